// Round 1
// baseline (3150.525 us; speedup 1.0000x reference)
//
#include <hip/hip_runtime.h>
#include <cstdint>
#include <cstddef>

#define HD 128              // hidden channels
#define GD 50               // gaussians
static constexpr float PI_F   = 3.14159265358979323846f;
static constexpr float CUTF   = 6.0f;
static constexpr float SHIFTF = 0.69314718055994530942f; // ln(2)

__device__ __forceinline__ float ssp(float x) {
    // softplus(x) - ln2, numerically stable
    return fmaxf(x, 0.0f) + log1pf(expf(-fabsf(x))) - SHIFTF;
}

// ---------------------------------------------------------------------------
// Wtab[bin][h] = (ssp(demb(bin) @ m0_w + m0_b) @ m2_w + m2_b), bin = 0..6
// One block per bin, 128 threads.
// ---------------------------------------------------------------------------
__global__ __launch_bounds__(HD) void k_wtab(const float* __restrict__ m0w,
                                             const float* __restrict__ m0b,
                                             const float* __restrict__ m2w,
                                             const float* __restrict__ m2b,
                                             float* __restrict__ wtab) {
    const int bin = blockIdx.x;       // 0..6
    const int t   = threadIdx.x;      // 0..127
    __shared__ float hbuf[HD];

    const float spacing = CUTF / (GD - 1);
    const float coeff   = -0.5f / (spacing * spacing);

    float acc = m0b[t];
    #pragma unroll 5
    for (int g = 0; g < GD; ++g) {
        float d = (float)bin - (float)g * spacing;
        acc = fmaf(expf(coeff * d * d), m0w[g * HD + t], acc);
    }
    hbuf[t] = ssp(acc);
    __syncthreads();

    float acc2 = m2b[t];
    #pragma unroll 8
    for (int k = 0; k < HD; ++k)
        acc2 = fmaf(hbuf[k], m2w[k * HD + t], acc2);
    wtab[bin * HD + t] = acc2;
}

// ---------------------------------------------------------------------------
// v = z @ init_w + init_b        z:[N,3]  init_w:[3,128]
// ---------------------------------------------------------------------------
__global__ __launch_bounds__(256) void k_init(const float* __restrict__ z,
                                              const float* __restrict__ w,
                                              const float* __restrict__ b,
                                              float* __restrict__ v, int n) {
    int idx = blockIdx.x * blockDim.x + threadIdx.x;
    int node = idx >> 7;
    int h    = idx & (HD - 1);
    if (node >= n) return;
    float z0 = z[node * 3 + 0], z1 = z[node * 3 + 1], z2 = z[node * 3 + 2];
    float r = fmaf(z0, w[0 * HD + h],
              fmaf(z1, w[1 * HD + h],
              fmaf(z2, w[2 * HD + h], b[h])));
    v[(size_t)node * HD + h] = r;
}

// ---------------------------------------------------------------------------
// Tiled fp32 matmul:  C = [res +] act(A @ B + bias)
// A:[nrows,128]  B:[128,128] row-major  tile: 64 rows x 128 cols, 256 thr
// Each thread: 8 rows x 4 cols register tile; A tile staged in LDS.
// ---------------------------------------------------------------------------
template <int ACT_SSP, int ADD_RES>
__global__ __launch_bounds__(256) void k_mm(const float* __restrict__ A,
                                            const float* __restrict__ Bm,
                                            const float* __restrict__ bias,
                                            float* __restrict__ C,
                                            const float* __restrict__ res,
                                            int nrows) {
    __shared__ float As[64 * HD];
    const int tid = threadIdx.x;
    const int rb  = blockIdx.x * 64;

    // stage A tile (64x128 f32 = 32 KB), coalesced float4
    #pragma unroll
    for (int it = 0; it < 8; ++it) {
        int f   = tid + 256 * it;      // float4 index in tile
        int row = f >> 5;              // 32 float4 per row
        int c4  = f & 31;
        float4 val = make_float4(0.f, 0.f, 0.f, 0.f);
        if (rb + row < nrows)
            val = ((const float4*)(A + (size_t)(rb + row) * HD))[c4];
        ((float4*)As)[f] = val;
    }
    __syncthreads();

    const int cg = tid & 31;   // cols 4*cg .. 4*cg+3
    const int tr = tid >> 5;   // 0..7 -> rows tr*8 .. tr*8+7

    float acc[8][4];
    #pragma unroll
    for (int i = 0; i < 8; ++i)
        #pragma unroll
        for (int c = 0; c < 4; ++c) acc[i][c] = 0.f;

    #pragma unroll 4
    for (int k = 0; k < HD; k += 4) {
        float4 b0 = ((const float4*)(Bm + (size_t)(k + 0) * HD))[cg];
        float4 b1 = ((const float4*)(Bm + (size_t)(k + 1) * HD))[cg];
        float4 b2 = ((const float4*)(Bm + (size_t)(k + 2) * HD))[cg];
        float4 b3 = ((const float4*)(Bm + (size_t)(k + 3) * HD))[cg];
        #pragma unroll
        for (int ri = 0; ri < 8; ++ri) {
            float4 av = ((const float4*)(As + (tr * 8 + ri) * HD))[k >> 2];
            acc[ri][0] = fmaf(av.x, b0.x, fmaf(av.y, b1.x, fmaf(av.z, b2.x, fmaf(av.w, b3.x, acc[ri][0]))));
            acc[ri][1] = fmaf(av.x, b0.y, fmaf(av.y, b1.y, fmaf(av.z, b2.y, fmaf(av.w, b3.y, acc[ri][1]))));
            acc[ri][2] = fmaf(av.x, b0.z, fmaf(av.y, b1.z, fmaf(av.z, b2.z, fmaf(av.w, b3.z, acc[ri][2]))));
            acc[ri][3] = fmaf(av.x, b0.w, fmaf(av.y, b1.w, fmaf(av.z, b2.w, fmaf(av.w, b3.w, acc[ri][3]))));
        }
    }

    float bs0 = 0.f, bs1 = 0.f, bs2 = 0.f, bs3 = 0.f;
    if (bias) {
        float4 bb = ((const float4*)bias)[cg];
        bs0 = bb.x; bs1 = bb.y; bs2 = bb.z; bs3 = bb.w;
    }
    #pragma unroll
    for (int ri = 0; ri < 8; ++ri) {
        int row = rb + tr * 8 + ri;
        if (row >= nrows) continue;
        float4 o;
        o.x = acc[ri][0] + bs0;
        o.y = acc[ri][1] + bs1;
        o.z = acc[ri][2] + bs2;
        o.w = acc[ri][3] + bs3;
        if (ACT_SSP) { o.x = ssp(o.x); o.y = ssp(o.y); o.z = ssp(o.z); o.w = ssp(o.w); }
        if (ADD_RES) {
            float4 r = ((const float4*)(res + (size_t)row * HD))[cg];
            o.x += r.x; o.y += r.y; o.z += r.z; o.w += r.w;
        }
        ((float4*)(C + (size_t)row * HD))[cg] = o;
    }
}

// ---------------------------------------------------------------------------
// Edge kernel: agg[i[e]] += vlin[j[e]] * Wtab[(int)dist[e]] * C(dist[e])
// 32 threads per edge, 4 channels (float4) each.
// ---------------------------------------------------------------------------
__global__ __launch_bounds__(256) void k_edge(const int* __restrict__ ei,
                                              const float* __restrict__ dist,
                                              const float* __restrict__ vlin,
                                              const float* __restrict__ wtab,
                                              float* __restrict__ agg,
                                              int nedges) {
    int tid    = blockIdx.x * blockDim.x + threadIdx.x;
    int lane4  = tid & 31;                         // channel group
    int e      = tid >> 5;
    int stride = (gridDim.x * blockDim.x) >> 5;
    for (; e < nedges; e += stride) {
        int   jsrc = ei[e];
        int   idst = ei[nedges + e];
        float d    = dist[e];
        int   bin  = min((int)d, 6);
        float Cg   = 0.5f * (cosf(d * (PI_F / CUTF)) + 1.0f);

        float4 w4 = ((const float4*)(wtab + bin * HD))[lane4];
        float4 x  = ((const float4*)(vlin + (size_t)jsrc * HD))[lane4];
        float* dst = agg + (size_t)idst * HD + lane4 * 4;
        unsafeAtomicAdd(dst + 0, x.x * w4.x * Cg);
        unsafeAtomicAdd(dst + 1, x.y * w4.y * Cg);
        unsafeAtomicAdd(dst + 2, x.z * w4.z * Cg);
        unsafeAtomicAdd(dst + 3, x.w * w4.w * Cg);
    }
}

// ---------------------------------------------------------------------------
// out[n, 0..2] = tmp[n,:] @ u_l2_w + u_l2_b     (u_l2_w: [128,3])
// ---------------------------------------------------------------------------
__global__ __launch_bounds__(256) void k_out3(const float* __restrict__ tmp,
                                              const float* __restrict__ w,
                                              const float* __restrict__ b,
                                              float* __restrict__ out, int n) {
    int node = blockIdx.x * blockDim.x + threadIdx.x;
    if (node >= n) return;
    float a0 = 0.f, a1 = 0.f, a2 = 0.f;
    const float4* row = (const float4*)(tmp + (size_t)node * HD);
    #pragma unroll 8
    for (int k4 = 0; k4 < 32; ++k4) {
        float4 v = row[k4];
        int kb = k4 * 4;
        a0 = fmaf(v.x, w[(kb + 0) * 3 + 0], a0);
        a1 = fmaf(v.x, w[(kb + 0) * 3 + 1], a1);
        a2 = fmaf(v.x, w[(kb + 0) * 3 + 2], a2);
        a0 = fmaf(v.y, w[(kb + 1) * 3 + 0], a0);
        a1 = fmaf(v.y, w[(kb + 1) * 3 + 1], a1);
        a2 = fmaf(v.y, w[(kb + 1) * 3 + 2], a2);
        a0 = fmaf(v.z, w[(kb + 2) * 3 + 0], a0);
        a1 = fmaf(v.z, w[(kb + 2) * 3 + 1], a1);
        a2 = fmaf(v.z, w[(kb + 2) * 3 + 2], a2);
        a0 = fmaf(v.w, w[(kb + 3) * 3 + 0], a0);
        a1 = fmaf(v.w, w[(kb + 3) * 3 + 1], a1);
        a2 = fmaf(v.w, w[(kb + 3) * 3 + 2], a2);
    }
    out[(size_t)node * 3 + 0] = a0 + b[0];
    out[(size_t)node * 3 + 1] = a1 + b[1];
    out[(size_t)node * 3 + 2] = a2 + b[2];
}

// ---------------------------------------------------------------------------
extern "C" void kernel_launch(void* const* d_in, const int* in_sizes, int n_in,
                              void* d_out, int out_size, void* d_ws, size_t ws_size,
                              hipStream_t stream) {
    const float* z      = (const float*)d_in[0];
    const float* dist   = (const float*)d_in[1];
    const int*   ei     = (const int*)d_in[2];
    const float* init_w = (const float*)d_in[3];
    const float* init_b = (const float*)d_in[4];

    // per-layer weights: lin_w, m0_w, m0_b, m2_w, m2_b, l1_w, l1_b, l2_w, l2_b
    const float* L[2][9];
    for (int l = 0; l < 2; ++l)
        for (int p = 0; p < 9; ++p)
            L[l][p] = (const float*)d_in[5 + l * 9 + p];

    const float* u_l1_w = (const float*)d_in[23];
    const float* u_l1_b = (const float*)d_in[24];
    const float* u_l2_w = (const float*)d_in[25];
    const float* u_l2_b = (const float*)d_in[26];
    float* out = (float*)d_out;

    const int N = in_sizes[0] / 3;
    const int E = in_sizes[1];

    // workspace layout (floats)
    float* wtab = (float*)d_ws;                    // 2 * 1024 (7x128 used)
    float* v    = wtab + 2048;                     // N*H
    float* vlin = v + (size_t)N * HD;              // N*H (doubles as tmp)
    float* agg  = vlin + (size_t)N * HD;           // N*H

    const int mmGrid = (N + 63) / 64;
    const int edgeGrid = (E * 32 + 255) / 256;

    // filter tables for both layers (m0_w, m0_b, m2_w, m2_b)
    k_wtab<<<7, HD, 0, stream>>>(L[0][1], L[0][2], L[0][3], L[0][4], wtab);
    k_wtab<<<7, HD, 0, stream>>>(L[1][1], L[1][2], L[1][3], L[1][4], wtab + 1024);

    // v = z @ init_w + init_b
    k_init<<<((size_t)N * HD + 255) / 256, 256, 0, stream>>>(z, init_w, init_b, v, N);

    for (int l = 0; l < 2; ++l) {
        // vlin = v @ lin_w
        k_mm<0, 0><<<mmGrid, 256, 0, stream>>>(v, L[l][0], nullptr, vlin, nullptr, N);
        // agg = 0
        hipMemsetAsync(agg, 0, (size_t)N * HD * sizeof(float), stream);
        // scatter
        k_edge<<<edgeGrid, 256, 0, stream>>>(ei, dist, vlin, wtab + l * 1024, agg, E);
        // tmp = ssp(agg @ l1_w + l1_b)   (reuse vlin buffer)
        k_mm<1, 0><<<mmGrid, 256, 0, stream>>>(agg, L[l][5], L[l][6], vlin, nullptr, N);
        // v = v + tmp @ l2_w + l2_b
        k_mm<0, 1><<<mmGrid, 256, 0, stream>>>(vlin, L[l][7], L[l][8], v, v, N);
    }

    // readout
    k_mm<1, 0><<<mmGrid, 256, 0, stream>>>(v, u_l1_w, u_l1_b, vlin, nullptr, N);
    k_out3<<<(N + 255) / 256, 256, 0, stream>>>(vlin, u_l2_w, u_l2_b, out, N);
}

// Round 2
// 719.070 us; speedup vs baseline: 4.3814x; 4.3814x over previous
//
#include <hip/hip_runtime.h>
#include <cstdint>
#include <cstddef>

#define HD 128              // hidden channels
#define GD 50               // gaussians
static constexpr float PI_F   = 3.14159265358979323846f;
static constexpr float CUTF   = 6.0f;
static constexpr float SHIFTF = 0.69314718055994530942f; // ln(2)

__device__ __forceinline__ float ssp(float x) {
    return fmaxf(x, 0.0f) + log1pf(expf(-fabsf(x))) - SHIFTF;
}

// ---------------------------------------------------------------------------
// Wtab[bin][h] for bin = 0..6 (trunc(dist) values), one block per bin.
// ---------------------------------------------------------------------------
__global__ __launch_bounds__(HD) void k_wtab(const float* __restrict__ m0w,
                                             const float* __restrict__ m0b,
                                             const float* __restrict__ m2w,
                                             const float* __restrict__ m2b,
                                             float* __restrict__ wtab) {
    const int bin = blockIdx.x;
    const int t   = threadIdx.x;
    __shared__ float hbuf[HD];

    const float spacing = CUTF / (GD - 1);
    const float coeff   = -0.5f / (spacing * spacing);

    float acc = m0b[t];
    #pragma unroll 5
    for (int g = 0; g < GD; ++g) {
        float d = (float)bin - (float)g * spacing;
        acc = fmaf(expf(coeff * d * d), m0w[g * HD + t], acc);
    }
    hbuf[t] = ssp(acc);
    __syncthreads();

    float acc2 = m2b[t];
    #pragma unroll 8
    for (int k = 0; k < HD; ++k)
        acc2 = fmaf(hbuf[k], m2w[k * HD + t], acc2);
    wtab[bin * HD + t] = acc2;
}

// ---------------------------------------------------------------------------
// v = z @ init_w + init_b
// ---------------------------------------------------------------------------
__global__ __launch_bounds__(256) void k_init(const float* __restrict__ z,
                                              const float* __restrict__ w,
                                              const float* __restrict__ b,
                                              float* __restrict__ v, int n) {
    int idx = blockIdx.x * blockDim.x + threadIdx.x;
    int node = idx >> 7;
    int h    = idx & (HD - 1);
    if (node >= n) return;
    float z0 = z[node * 3 + 0], z1 = z[node * 3 + 1], z2 = z[node * 3 + 2];
    float r = fmaf(z0, w[0 * HD + h],
              fmaf(z1, w[1 * HD + h],
              fmaf(z2, w[2 * HD + h], b[h])));
    v[(size_t)node * HD + h] = r;
}

// ---------------------------------------------------------------------------
// Tiled fp32 matmul:  C = [res +] act(A @ B + bias)
// ---------------------------------------------------------------------------
template <int ACT_SSP, int ADD_RES>
__global__ __launch_bounds__(256) void k_mm(const float* __restrict__ A,
                                            const float* __restrict__ Bm,
                                            const float* __restrict__ bias,
                                            float* __restrict__ C,
                                            const float* __restrict__ res,
                                            int nrows) {
    __shared__ float As[64 * HD];
    const int tid = threadIdx.x;
    const int rb  = blockIdx.x * 64;

    #pragma unroll
    for (int it = 0; it < 8; ++it) {
        int f   = tid + 256 * it;
        int row = f >> 5;
        int c4  = f & 31;
        float4 val = make_float4(0.f, 0.f, 0.f, 0.f);
        if (rb + row < nrows)
            val = ((const float4*)(A + (size_t)(rb + row) * HD))[c4];
        ((float4*)As)[f] = val;
    }
    __syncthreads();

    const int cg = tid & 31;
    const int tr = tid >> 5;

    float acc[8][4];
    #pragma unroll
    for (int i = 0; i < 8; ++i)
        #pragma unroll
        for (int c = 0; c < 4; ++c) acc[i][c] = 0.f;

    #pragma unroll 4
    for (int k = 0; k < HD; k += 4) {
        float4 b0 = ((const float4*)(Bm + (size_t)(k + 0) * HD))[cg];
        float4 b1 = ((const float4*)(Bm + (size_t)(k + 1) * HD))[cg];
        float4 b2 = ((const float4*)(Bm + (size_t)(k + 2) * HD))[cg];
        float4 b3 = ((const float4*)(Bm + (size_t)(k + 3) * HD))[cg];
        #pragma unroll
        for (int ri = 0; ri < 8; ++ri) {
            float4 av = ((const float4*)(As + (tr * 8 + ri) * HD))[k >> 2];
            acc[ri][0] = fmaf(av.x, b0.x, fmaf(av.y, b1.x, fmaf(av.z, b2.x, fmaf(av.w, b3.x, acc[ri][0]))));
            acc[ri][1] = fmaf(av.x, b0.y, fmaf(av.y, b1.y, fmaf(av.z, b2.y, fmaf(av.w, b3.y, acc[ri][1]))));
            acc[ri][2] = fmaf(av.x, b0.z, fmaf(av.y, b1.z, fmaf(av.z, b2.z, fmaf(av.w, b3.z, acc[ri][2]))));
            acc[ri][3] = fmaf(av.x, b0.w, fmaf(av.y, b1.w, fmaf(av.z, b2.w, fmaf(av.w, b3.w, acc[ri][3]))));
        }
    }

    float bs0 = 0.f, bs1 = 0.f, bs2 = 0.f, bs3 = 0.f;
    if (bias) {
        float4 bb = ((const float4*)bias)[cg];
        bs0 = bb.x; bs1 = bb.y; bs2 = bb.z; bs3 = bb.w;
    }
    #pragma unroll
    for (int ri = 0; ri < 8; ++ri) {
        int row = rb + tr * 8 + ri;
        if (row >= nrows) continue;
        float4 o;
        o.x = acc[ri][0] + bs0;
        o.y = acc[ri][1] + bs1;
        o.z = acc[ri][2] + bs2;
        o.w = acc[ri][3] + bs3;
        if (ACT_SSP) { o.x = ssp(o.x); o.y = ssp(o.y); o.z = ssp(o.z); o.w = ssp(o.w); }
        if (ADD_RES) {
            float4 r = ((const float4*)(res + (size_t)row * HD))[cg];
            o.x += r.x; o.y += r.y; o.z += r.z; o.w += r.w;
        }
        ((float4*)(C + (size_t)row * HD))[cg] = o;
    }
}

// ---------------------------------------------------------------------------
// CSR build: degree histogram -> 3-kernel exclusive scan -> placement scatter
// ---------------------------------------------------------------------------
__global__ __launch_bounds__(256) void k_deg(const int* __restrict__ ei,
                                             int* __restrict__ deg, int nedges) {
    int e = blockIdx.x * 256 + threadIdx.x;
    if (e < nedges) atomicAdd(&deg[ei[nedges + e]], 1);
}

// block-local exclusive scan over chunks of 1024 (covers m = n+1 elements)
__global__ __launch_bounds__(1024) void k_scan1(const int* __restrict__ deg,
                                                int* __restrict__ rowstart,
                                                int* __restrict__ blocksum,
                                                int n /*deg has n entries; scan n+1*/) {
    __shared__ int wsum[16];
    int tid  = threadIdx.x;
    int lane = tid & 63, wid = tid >> 6;
    int i = blockIdx.x * 1024 + tid;
    int val = (i < n) ? deg[i] : 0;
    int x = val;
    #pragma unroll
    for (int off = 1; off < 64; off <<= 1) {
        int y = __shfl_up(x, off, 64);
        if (lane >= off) x += y;
    }
    if (lane == 63) wsum[wid] = x;
    __syncthreads();
    if (wid == 0) {
        int s = (lane < 16) ? wsum[lane] : 0;
        #pragma unroll
        for (int off = 1; off < 16; off <<= 1) {
            int y = __shfl_up(s, off, 64);
            if (lane >= off) s += y;
        }
        if (lane < 16) wsum[lane] = s;
    }
    __syncthreads();
    int wbase = (wid > 0) ? wsum[wid - 1] : 0;
    if (i <= n) rowstart[i] = wbase + x - val;     // local exclusive
    if (tid == 1023) blocksum[blockIdx.x] = wsum[15];
}

__global__ __launch_bounds__(64) void k_scan2(int* __restrict__ blocksum, int nb) {
    int lane = threadIdx.x;
    int v = (lane < nb) ? blocksum[lane] : 0;
    int x = v;
    #pragma unroll
    for (int off = 1; off < 64; off <<= 1) {
        int y = __shfl_up(x, off, 64);
        if (lane >= off) x += y;
    }
    if (lane < nb) blocksum[lane] = x - v;          // exclusive
}

__global__ __launch_bounds__(1024) void k_scan3(int* __restrict__ rowstart,
                                                int* __restrict__ cursor,
                                                const int* __restrict__ blocksum,
                                                int n) {
    int i = blockIdx.x * 1024 + threadIdx.x;
    if (i <= n) {
        int rs = rowstart[i] + blocksum[blockIdx.x];
        rowstart[i] = rs;
        if (i < n) cursor[i] = rs;
    }
}

__global__ __launch_bounds__(256) void k_escatter(const int* __restrict__ ei,
                                                  const float* __restrict__ dist,
                                                  int* __restrict__ cursor,
                                                  int* __restrict__ packed,
                                                  float* __restrict__ cgarr,
                                                  int nedges) {
    int e = blockIdx.x * 256 + threadIdx.x;
    if (e >= nedges) return;
    int   j = ei[e];
    int   i = ei[nedges + e];
    float d = dist[e];
    int bin = min((int)d, 6);
    float Cg = 0.5f * (cosf(d * (PI_F / CUTF)) + 1.0f);
    int pos = atomicAdd(&cursor[i], 1);
    packed[pos] = j | (bin << 25);
    cgarr[pos]  = Cg;
}

// ---------------------------------------------------------------------------
// agg[node] = sum_{e in CSR row} vlin[j_e] * Wtab[bin_e] * Cg_e
// One wave per node, float2 per lane, accumulators in registers. No atomics.
// ---------------------------------------------------------------------------
__global__ __launch_bounds__(256) void k_agg(const int* __restrict__ rowstart,
                                             const int* __restrict__ packed,
                                             const float* __restrict__ cgarr,
                                             const float* __restrict__ vlin,
                                             const float* __restrict__ wtab,
                                             float* __restrict__ agg, int n) {
    __shared__ float lwt[7 * HD];
    int tid = threadIdx.x;
    if (tid < 224) ((float4*)lwt)[tid] = ((const float4*)wtab)[tid];
    __syncthreads();

    int node = blockIdx.x * 4 + (tid >> 6);
    if (node >= n) return;
    int lane = tid & 63;
    int beg = rowstart[node], end = rowstart[node + 1];

    float accx = 0.f, accy = 0.f;
    const float* lwt2 = lwt + 2 * lane;
    for (int e = beg; e < end; ++e) {
        int   p   = packed[e];
        float cgv = cgarr[e];
        int j = p & 0x01FFFFFF;
        int b = p >> 25;
        float2 x = *(const float2*)(vlin + (size_t)j * HD + 2 * lane);
        float2 w = *(const float2*)(lwt2 + b * HD);
        accx = fmaf(x.x, w.x * cgv, accx);
        accy = fmaf(x.y, w.y * cgv, accy);
    }
    *(float2*)(agg + (size_t)node * HD + 2 * lane) = make_float2(accx, accy);
}

// ---------------------------------------------------------------------------
// out = tmp @ u_l2_w + u_l2_b   (u_l2_w: [128,3])
// ---------------------------------------------------------------------------
__global__ __launch_bounds__(256) void k_out3(const float* __restrict__ tmp,
                                              const float* __restrict__ w,
                                              const float* __restrict__ b,
                                              float* __restrict__ out, int n) {
    int node = blockIdx.x * blockDim.x + threadIdx.x;
    if (node >= n) return;
    float a0 = 0.f, a1 = 0.f, a2 = 0.f;
    const float4* row = (const float4*)(tmp + (size_t)node * HD);
    #pragma unroll 8
    for (int k4 = 0; k4 < 32; ++k4) {
        float4 v = row[k4];
        int kb = k4 * 4;
        a0 = fmaf(v.x, w[(kb + 0) * 3 + 0], a0);
        a1 = fmaf(v.x, w[(kb + 0) * 3 + 1], a1);
        a2 = fmaf(v.x, w[(kb + 0) * 3 + 2], a2);
        a0 = fmaf(v.y, w[(kb + 1) * 3 + 0], a0);
        a1 = fmaf(v.y, w[(kb + 1) * 3 + 1], a1);
        a2 = fmaf(v.y, w[(kb + 1) * 3 + 2], a2);
        a0 = fmaf(v.z, w[(kb + 2) * 3 + 0], a0);
        a1 = fmaf(v.z, w[(kb + 2) * 3 + 1], a1);
        a2 = fmaf(v.z, w[(kb + 2) * 3 + 2], a2);
        a0 = fmaf(v.w, w[(kb + 3) * 3 + 0], a0);
        a1 = fmaf(v.w, w[(kb + 3) * 3 + 1], a1);
        a2 = fmaf(v.w, w[(kb + 3) * 3 + 2], a2);
    }
    out[(size_t)node * 3 + 0] = a0 + b[0];
    out[(size_t)node * 3 + 1] = a1 + b[1];
    out[(size_t)node * 3 + 2] = a2 + b[2];
}

// ---------------------------------------------------------------------------
extern "C" void kernel_launch(void* const* d_in, const int* in_sizes, int n_in,
                              void* d_out, int out_size, void* d_ws, size_t ws_size,
                              hipStream_t stream) {
    const float* z      = (const float*)d_in[0];
    const float* dist   = (const float*)d_in[1];
    const int*   ei     = (const int*)d_in[2];
    const float* init_w = (const float*)d_in[3];
    const float* init_b = (const float*)d_in[4];

    const float* L[2][9];
    for (int l = 0; l < 2; ++l)
        for (int p = 0; p < 9; ++p)
            L[l][p] = (const float*)d_in[5 + l * 9 + p];

    const float* u_l1_w = (const float*)d_in[23];
    const float* u_l1_b = (const float*)d_in[24];
    const float* u_l2_w = (const float*)d_in[25];
    const float* u_l2_b = (const float*)d_in[26];
    float* out = (float*)d_out;

    const int N = in_sizes[0] / 3;
    const int E = in_sizes[1];

    // workspace layout
    float* wtab    = (float*)d_ws;                 // 2048
    float* v       = wtab + 2048;                  // N*HD
    float* vlin    = v + (size_t)N * HD;           // N*HD
    float* agg     = vlin + (size_t)N * HD;        // N*HD
    int* deg       = (int*)(agg + (size_t)N * HD); // N
    int* rowstart  = deg + N;                      // N+1
    int* cursor    = rowstart + N + 1;             // N
    int* blocksum  = cursor + N;                   // 64
    int* packed    = blocksum + 64;                // E
    float* cgarr   = (float*)(packed + E);         // E

    const int mmGrid   = (N + 63) / 64;
    const int edgeGrid = (E + 255) / 256;
    const int scanB    = (N + 1 + 1023) / 1024;    // 49 for N=50000
    const int aggGrid  = (N + 3) / 4;

    // filter tables
    k_wtab<<<7, HD, 0, stream>>>(L[0][1], L[0][2], L[0][3], L[0][4], wtab);
    k_wtab<<<7, HD, 0, stream>>>(L[1][1], L[1][2], L[1][3], L[1][4], wtab + 1024);

    // v = z @ init_w + init_b
    k_init<<<((size_t)N * HD + 255) / 256, 256, 0, stream>>>(z, init_w, init_b, v, N);

    // CSR build (once; edge_index identical for both layers)
    hipMemsetAsync(deg, 0, (size_t)N * sizeof(int), stream);
    k_deg<<<edgeGrid, 256, 0, stream>>>(ei, deg, E);
    k_scan1<<<scanB, 1024, 0, stream>>>(deg, rowstart, blocksum, N);
    k_scan2<<<1, 64, 0, stream>>>(blocksum, scanB);
    k_scan3<<<scanB, 1024, 0, stream>>>(rowstart, cursor, blocksum, N);
    k_escatter<<<edgeGrid, 256, 0, stream>>>(ei, dist, cursor, packed, cgarr, E);

    for (int l = 0; l < 2; ++l) {
        k_mm<0, 0><<<mmGrid, 256, 0, stream>>>(v, L[l][0], nullptr, vlin, nullptr, N);
        k_agg<<<aggGrid, 256, 0, stream>>>(rowstart, packed, cgarr, vlin, wtab + l * 1024, agg, N);
        k_mm<1, 0><<<mmGrid, 256, 0, stream>>>(agg, L[l][5], L[l][6], vlin, nullptr, N);
        k_mm<0, 1><<<mmGrid, 256, 0, stream>>>(vlin, L[l][7], L[l][8], v, v, N);
    }

    k_mm<1, 0><<<mmGrid, 256, 0, stream>>>(v, u_l1_w, u_l1_b, vlin, nullptr, N);
    k_out3<<<(N + 255) / 256, 256, 0, stream>>>(vlin, u_l2_w, u_l2_b, out, N);
}

// Round 3
// 553.190 us; speedup vs baseline: 5.6952x; 1.2999x over previous
//
#include <hip/hip_runtime.h>
#include <cstdint>
#include <cstddef>

#define HD 128              // hidden channels
#define GD 50               // gaussians
static constexpr float PI_F   = 3.14159265358979323846f;
static constexpr float CUTF   = 6.0f;
static constexpr float SHIFTF = 0.69314718055994530942f; // ln(2)

typedef _Float16 f16x8 __attribute__((ext_vector_type(8)));
typedef _Float16 f16x2 __attribute__((ext_vector_type(2)));
typedef float    f32x4 __attribute__((ext_vector_type(4)));

__device__ __forceinline__ float ssp(float x) {
    return fmaxf(x, 0.0f) + log1pf(expf(-fabsf(x))) - SHIFTF;
}

// ---------------------------------------------------------------------------
// Wtab[bin][h] for bin = 0..6, one block per bin.
// ---------------------------------------------------------------------------
__global__ __launch_bounds__(HD) void k_wtab(const float* __restrict__ m0w,
                                             const float* __restrict__ m0b,
                                             const float* __restrict__ m2w,
                                             const float* __restrict__ m2b,
                                             float* __restrict__ wtab) {
    const int bin = blockIdx.x;
    const int t   = threadIdx.x;
    __shared__ float hbuf[HD];

    const float spacing = CUTF / (GD - 1);
    const float coeff   = -0.5f / (spacing * spacing);

    float acc = m0b[t];
    #pragma unroll 5
    for (int g = 0; g < GD; ++g) {
        float d = (float)bin - (float)g * spacing;
        acc = fmaf(expf(coeff * d * d), m0w[g * HD + t], acc);
    }
    hbuf[t] = ssp(acc);
    __syncthreads();

    float acc2 = m2b[t];
    #pragma unroll 8
    for (int k = 0; k < HD; ++k)
        acc2 = fmaf(hbuf[k], m2w[k * HD + t], acc2);
    wtab[bin * HD + t] = acc2;
}

// ---------------------------------------------------------------------------
// v = z @ init_w + init_b
// ---------------------------------------------------------------------------
__global__ __launch_bounds__(256) void k_init(const float* __restrict__ z,
                                              const float* __restrict__ w,
                                              const float* __restrict__ b,
                                              float* __restrict__ v, int n) {
    int idx = blockIdx.x * blockDim.x + threadIdx.x;
    int node = idx >> 7;
    int h    = idx & (HD - 1);
    if (node >= n) return;
    float z0 = z[node * 3 + 0], z1 = z[node * 3 + 1], z2 = z[node * 3 + 2];
    float r = fmaf(z0, w[0 * HD + h],
              fmaf(z1, w[1 * HD + h],
              fmaf(z2, w[2 * HD + h], b[h])));
    v[(size_t)node * HD + h] = r;
}

// ---------------------------------------------------------------------------
// Pre-pack a [128,128] fp32 weight (row-major [k][col]) into fp16 MFMA
// B-fragment order: Bf[((ct*4+ks)*64 + lane)*8 + j] =
//                   W[ks*32 + (lane>>4)*8 + j][ct*16 + (lane&15)]
// ---------------------------------------------------------------------------
__global__ __launch_bounds__(256) void k_prepB(const float* __restrict__ W,
                                               _Float16* __restrict__ Bf) {
    int idx = blockIdx.x * 256 + threadIdx.x;   // 0..4095
    int l  = idx & 63;
    int f  = idx >> 6;        // ct*4+ks
    int ks = f & 3, ct = f >> 2;
    int col = ct * 16 + (l & 15);
    int k0  = ks * 32 + ((l >> 4) << 3);
    f16x8 o;
    #pragma unroll
    for (int j = 0; j < 8; ++j) o[j] = (_Float16)W[(size_t)(k0 + j) * HD + col];
    ((f16x8*)Bf)[idx] = o;
}

// ---------------------------------------------------------------------------
// MFMA matmul: C = [res +] act(A @ B + bias).  A:[nrows,128] fp32,
// B pre-packed fp16 frags. Block = 4 waves x 16 rows; wave tile 16x128.
// No LDS, no barriers. C/D layout: col=lane&15, row=(lane>>4)*4+reg (m89).
// ---------------------------------------------------------------------------
template <int ACT_SSP, int ADD_RES, int OUT_HALF>
__global__ __launch_bounds__(256) void k_mm_mfma(const float* __restrict__ A,
                                                 const _Float16* __restrict__ Bf,
                                                 const float* __restrict__ bias,
                                                 float* __restrict__ C,
                                                 _Float16* __restrict__ Ch,
                                                 const float* __restrict__ res,
                                                 int nrows) {
    const int tid  = threadIdx.x;
    const int lane = tid & 63;
    const int wid  = tid >> 6;
    const int rowbase = blockIdx.x * 64 + wid * 16;
    const int arow = rowbase + (lane & 15);
    const int arow_c = min(arow, nrows - 1);
    const int kgrp = (lane >> 4) << 3;      // 0,8,16,24

    f32x4 acc[8];
    #pragma unroll
    for (int i = 0; i < 8; ++i) acc[i] = (f32x4){0.f, 0.f, 0.f, 0.f};

    #pragma unroll
    for (int ks = 0; ks < 4; ++ks) {
        const float* ap = A + (size_t)arow_c * HD + ks * 32 + kgrp;
        float4 a0 = *(const float4*)ap;
        float4 a1 = *(const float4*)(ap + 4);
        f16x8 af;
        af[0] = (_Float16)a0.x; af[1] = (_Float16)a0.y;
        af[2] = (_Float16)a0.z; af[3] = (_Float16)a0.w;
        af[4] = (_Float16)a1.x; af[5] = (_Float16)a1.y;
        af[6] = (_Float16)a1.z; af[7] = (_Float16)a1.w;
        #pragma unroll
        for (int ct = 0; ct < 8; ++ct) {
            f16x8 bf = ((const f16x8*)Bf)[(ct * 4 + ks) * 64 + lane];
            acc[ct] = __builtin_amdgcn_mfma_f32_16x16x32_f16(af, bf, acc[ct], 0, 0, 0);
        }
    }

    const int crow0 = rowbase + ((lane >> 4) << 2);
    const int col   = lane & 15;
    #pragma unroll
    for (int ct = 0; ct < 8; ++ct) {
        int c = ct * 16 + col;
        float bs = bias ? bias[c] : 0.f;
        #pragma unroll
        for (int r = 0; r < 4; ++r) {
            int row = crow0 + r;
            if (row >= nrows) continue;
            float o = acc[ct][r] + bs;
            if (ACT_SSP) o = ssp(o);
            if (ADD_RES) o += res[(size_t)row * HD + c];
            if (OUT_HALF) Ch[(size_t)row * HD + c] = (_Float16)o;
            else          C[(size_t)row * HD + c] = o;
        }
    }
}

// ---------------------------------------------------------------------------
// CSR build: degree histogram -> 3-kernel exclusive scan -> placement scatter
// ---------------------------------------------------------------------------
__global__ __launch_bounds__(256) void k_deg(const int* __restrict__ ei,
                                             int* __restrict__ deg, int nedges) {
    int e = blockIdx.x * 256 + threadIdx.x;
    if (e < nedges) atomicAdd(&deg[ei[nedges + e]], 1);
}

__global__ __launch_bounds__(1024) void k_scan1(const int* __restrict__ deg,
                                                int* __restrict__ rowstart,
                                                int* __restrict__ blocksum,
                                                int n) {
    __shared__ int wsum[16];
    int tid  = threadIdx.x;
    int lane = tid & 63, wid = tid >> 6;
    int i = blockIdx.x * 1024 + tid;
    int val = (i < n) ? deg[i] : 0;
    int x = val;
    #pragma unroll
    for (int off = 1; off < 64; off <<= 1) {
        int y = __shfl_up(x, off, 64);
        if (lane >= off) x += y;
    }
    if (lane == 63) wsum[wid] = x;
    __syncthreads();
    if (wid == 0) {
        int s = (lane < 16) ? wsum[lane] : 0;
        #pragma unroll
        for (int off = 1; off < 16; off <<= 1) {
            int y = __shfl_up(s, off, 64);
            if (lane >= off) s += y;
        }
        if (lane < 16) wsum[lane] = s;
    }
    __syncthreads();
    int wbase = (wid > 0) ? wsum[wid - 1] : 0;
    if (i <= n) rowstart[i] = wbase + x - val;
    if (tid == 1023) blocksum[blockIdx.x] = wsum[15];
}

__global__ __launch_bounds__(64) void k_scan2(int* __restrict__ blocksum, int nb) {
    int lane = threadIdx.x;
    int v = (lane < nb) ? blocksum[lane] : 0;
    int x = v;
    #pragma unroll
    for (int off = 1; off < 64; off <<= 1) {
        int y = __shfl_up(x, off, 64);
        if (lane >= off) x += y;
    }
    if (lane < nb) blocksum[lane] = x - v;
}

__global__ __launch_bounds__(1024) void k_scan3(int* __restrict__ rowstart,
                                                int* __restrict__ cursor,
                                                const int* __restrict__ blocksum,
                                                int n) {
    int i = blockIdx.x * 1024 + threadIdx.x;
    if (i <= n) {
        int rs = rowstart[i] + blocksum[blockIdx.x];
        rowstart[i] = rs;
        if (i < n) cursor[i] = rs;
    }
}

__global__ __launch_bounds__(256) void k_escatter(const int* __restrict__ ei,
                                                  const float* __restrict__ dist,
                                                  int* __restrict__ cursor,
                                                  int* __restrict__ packed,
                                                  float* __restrict__ cgarr,
                                                  int nedges) {
    int e = blockIdx.x * 256 + threadIdx.x;
    if (e >= nedges) return;
    int   j = ei[e];
    int   i = ei[nedges + e];
    float d = dist[e];
    int bin = min((int)d, 6);
    float Cg = 0.5f * (cosf(d * (PI_F / CUTF)) + 1.0f);
    int pos = atomicAdd(&cursor[i], 1);
    packed[pos] = j | (bin << 25);
    cgarr[pos]  = Cg;
}

// ---------------------------------------------------------------------------
// agg[node] = sum_e vlin_h[j_e] * Wtab[bin_e] * Cg_e   (fp16 gather, fp32 acc)
// One wave per node, 2 channels/lane, 2-edge unroll. No atomics.
// ---------------------------------------------------------------------------
__global__ __launch_bounds__(256) void k_agg(const int* __restrict__ rowstart,
                                             const int* __restrict__ packed,
                                             const float* __restrict__ cgarr,
                                             const _Float16* __restrict__ vlin_h,
                                             const float* __restrict__ wtab,
                                             float* __restrict__ agg, int n) {
    __shared__ float lwt[7 * HD];
    int tid = threadIdx.x;
    if (tid < 224) ((float4*)lwt)[tid] = ((const float4*)wtab)[tid];
    __syncthreads();

    int node = blockIdx.x * 4 + (tid >> 6);
    if (node >= n) return;
    int lane = tid & 63;
    int beg = rowstart[node], end = rowstart[node + 1];

    float accx = 0.f, accy = 0.f;
    const float* lwt2 = lwt + 2 * lane;
    int e = beg;
    for (; e + 1 < end; e += 2) {
        int   p0 = packed[e],     p1 = packed[e + 1];
        float c0 = cgarr[e],      c1 = cgarr[e + 1];
        int j0 = p0 & 0x01FFFFFF, b0 = p0 >> 25;
        int j1 = p1 & 0x01FFFFFF, b1 = p1 >> 25;
        f16x2 h0 = *(const f16x2*)(vlin_h + (size_t)j0 * HD + 2 * lane);
        f16x2 h1 = *(const f16x2*)(vlin_h + (size_t)j1 * HD + 2 * lane);
        float2 w0 = *(const float2*)(lwt2 + b0 * HD);
        float2 w1 = *(const float2*)(lwt2 + b1 * HD);
        accx = fmaf((float)h0[0], w0.x * c0, accx);
        accy = fmaf((float)h0[1], w0.y * c0, accy);
        accx = fmaf((float)h1[0], w1.x * c1, accx);
        accy = fmaf((float)h1[1], w1.y * c1, accy);
    }
    if (e < end) {
        int   p0 = packed[e];
        float c0 = cgarr[e];
        int j0 = p0 & 0x01FFFFFF, b0 = p0 >> 25;
        f16x2 h0 = *(const f16x2*)(vlin_h + (size_t)j0 * HD + 2 * lane);
        float2 w0 = *(const float2*)(lwt2 + b0 * HD);
        accx = fmaf((float)h0[0], w0.x * c0, accx);
        accy = fmaf((float)h0[1], w0.y * c0, accy);
    }
    *(float2*)(agg + (size_t)node * HD + 2 * lane) = make_float2(accx, accy);
}

// ---------------------------------------------------------------------------
// out = tmp @ u_l2_w + u_l2_b   (u_l2_w: [128,3])
// ---------------------------------------------------------------------------
__global__ __launch_bounds__(256) void k_out3(const float* __restrict__ tmp,
                                              const float* __restrict__ w,
                                              const float* __restrict__ b,
                                              float* __restrict__ out, int n) {
    int node = blockIdx.x * blockDim.x + threadIdx.x;
    if (node >= n) return;
    float a0 = 0.f, a1 = 0.f, a2 = 0.f;
    const float4* row = (const float4*)(tmp + (size_t)node * HD);
    #pragma unroll 8
    for (int k4 = 0; k4 < 32; ++k4) {
        float4 v = row[k4];
        int kb = k4 * 4;
        a0 = fmaf(v.x, w[(kb + 0) * 3 + 0], a0);
        a1 = fmaf(v.x, w[(kb + 0) * 3 + 1], a1);
        a2 = fmaf(v.x, w[(kb + 0) * 3 + 2], a2);
        a0 = fmaf(v.y, w[(kb + 1) * 3 + 0], a0);
        a1 = fmaf(v.y, w[(kb + 1) * 3 + 1], a1);
        a2 = fmaf(v.y, w[(kb + 1) * 3 + 2], a2);
        a0 = fmaf(v.z, w[(kb + 2) * 3 + 0], a0);
        a1 = fmaf(v.z, w[(kb + 2) * 3 + 1], a1);
        a2 = fmaf(v.z, w[(kb + 2) * 3 + 2], a2);
        a0 = fmaf(v.w, w[(kb + 3) * 3 + 0], a0);
        a1 = fmaf(v.w, w[(kb + 3) * 3 + 1], a1);
        a2 = fmaf(v.w, w[(kb + 3) * 3 + 2], a2);
    }
    out[(size_t)node * 3 + 0] = a0 + b[0];
    out[(size_t)node * 3 + 1] = a1 + b[1];
    out[(size_t)node * 3 + 2] = a2 + b[2];
}

// ---------------------------------------------------------------------------
extern "C" void kernel_launch(void* const* d_in, const int* in_sizes, int n_in,
                              void* d_out, int out_size, void* d_ws, size_t ws_size,
                              hipStream_t stream) {
    const float* z      = (const float*)d_in[0];
    const float* dist   = (const float*)d_in[1];
    const int*   ei     = (const int*)d_in[2];
    const float* init_w = (const float*)d_in[3];
    const float* init_b = (const float*)d_in[4];

    const float* L[2][9];
    for (int l = 0; l < 2; ++l)
        for (int p = 0; p < 9; ++p)
            L[l][p] = (const float*)d_in[5 + l * 9 + p];

    const float* u_l1_w = (const float*)d_in[23];
    const float* u_l1_b = (const float*)d_in[24];
    const float* u_l2_w = (const float*)d_in[25];
    const float* u_l2_b = (const float*)d_in[26];
    float* out = (float*)d_out;

    const int N = in_sizes[0] / 3;
    const int E = in_sizes[1];

    // workspace layout (floats)
    float* wtab   = (float*)d_ws;                   // 2048
    float* v      = wtab + 2048;                    // N*HD
    float* tmp    = v + (size_t)N * HD;             // N*HD (vlin_h aliases this)
    float* agg    = tmp + (size_t)N * HD;           // N*HD
    float* bfbase = agg + (size_t)N * HD;           // 7*16384 halves = 57344 floats
    int* deg      = (int*)(bfbase + 57344);         // N
    int* rowstart = deg + N;                        // N+1
    int* cursor   = rowstart + N + 1;               // N
    int* blocksum = cursor + N;                     // 64
    int* packed   = blocksum + 64;                  // E
    float* cgarr  = (float*)(packed + E);           // E

    _Float16* vlin_h = (_Float16*)tmp;
    _Float16* Bf     = (_Float16*)bfbase;
    // packed-weight slots: 0,1,2 = layer0 lin,l1,l2 ; 3,4,5 = layer1 ; 6 = u_l1
    _Float16* BfW[7];
    for (int i = 0; i < 7; ++i) BfW[i] = Bf + (size_t)i * 16384;

    const int mmGrid   = (N + 63) / 64;
    const int edgeGrid = (E + 255) / 256;
    const int scanB    = (N + 1 + 1023) / 1024;
    const int aggGrid  = (N + 3) / 4;

    // filter tables + packed weights
    k_wtab<<<7, HD, 0, stream>>>(L[0][1], L[0][2], L[0][3], L[0][4], wtab);
    k_wtab<<<7, HD, 0, stream>>>(L[1][1], L[1][2], L[1][3], L[1][4], wtab + 1024);
    k_prepB<<<16, 256, 0, stream>>>(L[0][0], BfW[0]);
    k_prepB<<<16, 256, 0, stream>>>(L[0][5], BfW[1]);
    k_prepB<<<16, 256, 0, stream>>>(L[0][7], BfW[2]);
    k_prepB<<<16, 256, 0, stream>>>(L[1][0], BfW[3]);
    k_prepB<<<16, 256, 0, stream>>>(L[1][5], BfW[4]);
    k_prepB<<<16, 256, 0, stream>>>(L[1][7], BfW[5]);
    k_prepB<<<16, 256, 0, stream>>>(u_l1_w,  BfW[6]);

    // v = z @ init_w + init_b
    k_init<<<((size_t)N * HD + 255) / 256, 256, 0, stream>>>(z, init_w, init_b, v, N);

    // CSR build (edge_index identical for both layers)
    hipMemsetAsync(deg, 0, (size_t)N * sizeof(int), stream);
    k_deg<<<edgeGrid, 256, 0, stream>>>(ei, deg, E);
    k_scan1<<<scanB, 1024, 0, stream>>>(deg, rowstart, blocksum, N);
    k_scan2<<<1, 64, 0, stream>>>(blocksum, scanB);
    k_scan3<<<scanB, 1024, 0, stream>>>(rowstart, cursor, blocksum, N);
    k_escatter<<<edgeGrid, 256, 0, stream>>>(ei, dist, cursor, packed, cgarr, E);

    for (int l = 0; l < 2; ++l) {
        // vlin_h = fp16(v @ lin_w)
        k_mm_mfma<0, 0, 1><<<mmGrid, 256, 0, stream>>>(v, BfW[l * 3 + 0], nullptr,
                                                       nullptr, vlin_h, nullptr, N);
        k_agg<<<aggGrid, 256, 0, stream>>>(rowstart, packed, cgarr, vlin_h,
                                           wtab + l * 1024, agg, N);
        // tmp = ssp(agg @ l1_w + l1_b)
        k_mm_mfma<1, 0, 0><<<mmGrid, 256, 0, stream>>>(agg, BfW[l * 3 + 1], L[l][6],
                                                       tmp, nullptr, nullptr, N);
        // v = v + tmp @ l2_w + l2_b
        k_mm_mfma<0, 1, 0><<<mmGrid, 256, 0, stream>>>(tmp, BfW[l * 3 + 2], L[l][8],
                                                       v, nullptr, v, N);
    }

    // readout
    k_mm_mfma<1, 0, 0><<<mmGrid, 256, 0, stream>>>(v, BfW[6], u_l1_b,
                                                   tmp, nullptr, nullptr, N);
    k_out3<<<(N + 255) / 256, 256, 0, stream>>>(tmp, u_l2_w, u_l2_b, out, N);
}

// Round 6
// 497.609 us; speedup vs baseline: 6.3313x; 1.1117x over previous
//
#include <hip/hip_runtime.h>
#include <cstdint>
#include <cstddef>

#define HD 128              // hidden channels
#define GD 50               // gaussians
static constexpr float PI_F   = 3.14159265358979323846f;
static constexpr float CUTF   = 6.0f;
static constexpr float SHIFTF = 0.69314718055994530942f; // ln(2)

typedef _Float16 f16x8 __attribute__((ext_vector_type(8)));
typedef _Float16 f16x2 __attribute__((ext_vector_type(2)));
typedef float    f32x4 __attribute__((ext_vector_type(4)));

struct Ptr8 { const float* p[8]; };

__device__ __forceinline__ float ssp(float x) {
    return fmaxf(x, 0.0f) + log1pf(expf(-fabsf(x))) - SHIFTF;
}

// ---------------------------------------------------------------------------
// Swizzled per-wave LDS tiles (16 rows). fp32 tile: 512 B/row; fp16: 256 B/row.
// XOR bits 4-6 of the byte offset with (row&7)<<4: bijective within a row,
// moves whole 16B blocks, consistent for 2/4/16 B accesses (G4).
// ---------------------------------------------------------------------------
__device__ __forceinline__ float* t32(float* base, int row, int byte) {
    return (float*)((char*)base + row * 512 + (byte ^ ((row & 7) << 4)));
}
__device__ __forceinline__ _Float16* t16(_Float16* base, int row, int byte) {
    return (_Float16*)((char*)base + row * 256 + (byte ^ ((row & 7) << 4)));
}

// 32 MFMAs: acc[ct] += A(af) * Bf[ct,ks]
__device__ __forceinline__ void mfma32(const f16x8 af[4],
                                       const _Float16* __restrict__ Bf,
                                       int lane, f32x4 acc[8]) {
    #pragma unroll
    for (int ks = 0; ks < 4; ++ks)
        #pragma unroll
        for (int ct = 0; ct < 8; ++ct)
            acc[ct] = __builtin_amdgcn_mfma_f32_16x16x32_f16(
                af[ks], ((const f16x8*)Bf)[(ct * 4 + ks) * 64 + lane], acc[ct], 0, 0, 0);
}

// C/D layout (m89): col = lane&15, row_local = (lane>>4)*4 + r
template <int ACT>
__device__ __forceinline__ void acc_to_t16(const f32x4 acc[8], const float* bias,
                                           int lane, _Float16* tile) {
    int col0 = lane & 15, r0 = (lane >> 4) * 4;
    #pragma unroll
    for (int ct = 0; ct < 8; ++ct) {
        int c = ct * 16 + col0;
        float bs = bias ? bias[c] : 0.f;
        #pragma unroll
        for (int r = 0; r < 4; ++r) {
            float o = acc[ct][r] + bs;
            if (ACT) o = ssp(o);
            *t16(tile, r0 + r, c * 2) = (_Float16)o;
        }
    }
}

__device__ __forceinline__ void acc_to_t32(const f32x4 acc[8], const float* bias,
                                           int lane, float* tile) {
    int col0 = lane & 15, r0 = (lane >> 4) * 4;
    #pragma unroll
    for (int ct = 0; ct < 8; ++ct) {
        int c = ct * 16 + col0;
        float bs = bias ? bias[c] : 0.f;
        #pragma unroll
        for (int r = 0; r < 4; ++r)
            *t32(tile, r0 + r, c * 4) = acc[ct][r] + bs;
    }
}

// A-fragments (lane: row = lane&15, k = (lane>>4)*8 + j per ks) from tiles
__device__ __forceinline__ void t16_to_af(_Float16* tile, int lane, f16x8 af[4]) {
    int row = lane & 15, kgB = (lane >> 4) * 16;
    #pragma unroll
    for (int ks = 0; ks < 4; ++ks)
        af[ks] = *(const f16x8*)t16(tile, row, ks * 64 + kgB);
}

__device__ __forceinline__ void t32_to_af(float* tile, int lane, f16x8 af[4]) {
    int row = lane & 15, kgB = (lane >> 4) * 32;
    #pragma unroll
    for (int ks = 0; ks < 4; ++ks) {
        f32x4 a = *(const f32x4*)t32(tile, row, ks * 128 + kgB);
        f32x4 b = *(const f32x4*)t32(tile, row, ks * 128 + kgB + 16);
        f16x8 h;
        h[0] = (_Float16)a[0]; h[1] = (_Float16)a[1];
        h[2] = (_Float16)a[2]; h[3] = (_Float16)a[3];
        h[4] = (_Float16)b[0]; h[5] = (_Float16)b[1];
        h[6] = (_Float16)b[2]; h[7] = (_Float16)b[3];
        af[ks] = h;
    }
}

// fp16 tile -> coalesced global f16x8 stores
__device__ __forceinline__ void t16_store(_Float16* tile, _Float16* g,
                                          int rowbase, int lane, int n) {
    #pragma unroll
    for (int it = 0; it < 4; ++it) {
        int f8 = it * 64 + lane;
        int row = f8 >> 4, g8 = f8 & 15;
        f16x8 h = *(const f16x8*)t16(tile, row, g8 * 16);
        if (rowbase + row < n) ((f16x8*)g)[(size_t)(rowbase + row) * 16 + g8] = h;
    }
}

// fp32 tile -> [optional += res load] -> [optional LDS writeback] -> [opt store]
template <int ADD_RES, int WB_LDS, int STORE_G>
__device__ __forceinline__ void t32_epilogue(float* tile, const float* res,
                                             float* g, int rowbase, int lane, int n) {
    #pragma unroll
    for (int it = 0; it < 8; ++it) {
        int f4 = it * 64 + lane;
        int row = f4 >> 5, c4 = f4 & 31;
        float* lp = t32(tile, row, c4 * 16);
        f32x4 val = *(f32x4*)lp;
        int grow = rowbase + row;
        int growc = min(grow, n - 1);
        if (ADD_RES) val += ((const f32x4*)res)[(size_t)growc * 32 + c4];
        if (WB_LDS) *(f32x4*)lp = val;
        if (STORE_G) { if (grow < n) ((f32x4*)g)[(size_t)grow * 32 + c4] = val; }
    }
}

// ---------------------------------------------------------------------------
// Wtab[layer][bin][h], grid (7 bins, 2 layers)
// ---------------------------------------------------------------------------
__global__ __launch_bounds__(HD) void k_wtab2(Ptr8 P, float* __restrict__ wtab) {
    const int bin = blockIdx.x, layer = blockIdx.y;
    const int t = threadIdx.x;
    const float* m0w = P.p[layer * 4 + 0];
    const float* m0b = P.p[layer * 4 + 1];
    const float* m2w = P.p[layer * 4 + 2];
    const float* m2b = P.p[layer * 4 + 3];
    __shared__ float hbuf[HD];

    const float spacing = CUTF / (GD - 1);
    const float coeff   = -0.5f / (spacing * spacing);

    float acc = m0b[t];
    #pragma unroll 5
    for (int g = 0; g < GD; ++g) {
        float d = (float)bin - (float)g * spacing;
        acc = fmaf(expf(coeff * d * d), m0w[g * HD + t], acc);
    }
    hbuf[t] = ssp(acc);
    __syncthreads();

    float acc2 = m2b[t];
    #pragma unroll 8
    for (int k = 0; k < HD; ++k)
        acc2 = fmaf(hbuf[k], m2w[k * HD + t], acc2);
    wtab[(layer * 7 + bin) * HD + t] = acc2;
}

// ---------------------------------------------------------------------------
// Pack 7 [128,128] fp32 weights into fp16 MFMA B-fragment order.
// EXACTLY 2048 f16x8 fragments per slot: grid must be dim3(8, 7).
// (Round 2-4 bug: 16 blocks -> idx 2048..4095 overran into the next slot;
//  concurrent slots in one launch then raced. Guard + correct grid.)
// ---------------------------------------------------------------------------
__global__ __launch_bounds__(256) void k_prepB7(Ptr8 P, _Float16* __restrict__ Bf) {
    int slot = blockIdx.y;
    const float* W = P.p[slot];
    int idx = blockIdx.x * 256 + threadIdx.x;   // 0..2047
    if (idx >= 2048) return;
    int l  = idx & 63;
    int f  = idx >> 6;        // 0..31 = ct*4+ks
    int ks = f & 3, ct = f >> 2;
    int col = ct * 16 + (l & 15);
    int k0  = ks * 32 + ((l >> 4) << 3);
    f16x8 o;
    #pragma unroll
    for (int j = 0; j < 8; ++j) o[j] = (_Float16)W[(size_t)(k0 + j) * HD + col];
    ((f16x8*)(Bf + (size_t)slot * 16384))[idx] = o;
}

// ---------------------------------------------------------------------------
// CSR build
// ---------------------------------------------------------------------------
__global__ __launch_bounds__(256) void k_deg(const int* __restrict__ ei,
                                             int* __restrict__ deg, int nedges) {
    int e = blockIdx.x * 256 + threadIdx.x;
    if (e < nedges) atomicAdd(&deg[ei[nedges + e]], 1);
}

__global__ __launch_bounds__(1024) void k_scan1(const int* __restrict__ deg,
                                                int* __restrict__ rowstart,
                                                int* __restrict__ blocksum, int n) {
    __shared__ int wsum[16];
    int tid  = threadIdx.x;
    int lane = tid & 63, wid = tid >> 6;
    int i = blockIdx.x * 1024 + tid;
    int val = (i < n) ? deg[i] : 0;
    int x = val;
    #pragma unroll
    for (int off = 1; off < 64; off <<= 1) {
        int y = __shfl_up(x, off, 64);
        if (lane >= off) x += y;
    }
    if (lane == 63) wsum[wid] = x;
    __syncthreads();
    if (wid == 0) {
        int s = (lane < 16) ? wsum[lane] : 0;
        #pragma unroll
        for (int off = 1; off < 16; off <<= 1) {
            int y = __shfl_up(s, off, 64);
            if (lane >= off) s += y;
        }
        if (lane < 16) wsum[lane] = s;
    }
    __syncthreads();
    int wbase = (wid > 0) ? wsum[wid - 1] : 0;
    if (i <= n) rowstart[i] = wbase + x - val;
    if (tid == 1023) blocksum[blockIdx.x] = wsum[15];
}

__global__ __launch_bounds__(64) void k_scan2(int* __restrict__ blocksum, int nb) {
    int lane = threadIdx.x;
    int v = (lane < nb) ? blocksum[lane] : 0;
    int x = v;
    #pragma unroll
    for (int off = 1; off < 64; off <<= 1) {
        int y = __shfl_up(x, off, 64);
        if (lane >= off) x += y;
    }
    if (lane < nb) blocksum[lane] = x - v;
}

__global__ __launch_bounds__(1024) void k_scan3(int* __restrict__ rowstart,
                                                int* __restrict__ cursor,
                                                const int* __restrict__ blocksum,
                                                int n) {
    int i = blockIdx.x * 1024 + threadIdx.x;
    if (i <= n) {
        int rs = rowstart[i] + blocksum[blockIdx.x];
        rowstart[i] = rs;
        if (i < n) cursor[i] = rs;
    }
}

// single int2 per edge -> one dirtied line per edge
__global__ __launch_bounds__(256) void k_escatter(const int* __restrict__ ei,
                                                  const float* __restrict__ dist,
                                                  int* __restrict__ cursor,
                                                  int2* __restrict__ ecomb,
                                                  int nedges) {
    int e = blockIdx.x * 256 + threadIdx.x;
    if (e >= nedges) return;
    int   j = ei[e];
    int   i = ei[nedges + e];
    float d = dist[e];
    int bin = min((int)d, 6);
    float Cg = 0.5f * (cosf(d * (PI_F / CUTF)) + 1.0f);
    int pos = atomicAdd(&cursor[i], 1);
    ecomb[pos] = make_int2(j | (bin << 25), __float_as_int(Cg));
}

// ---------------------------------------------------------------------------
// agg_h[node] = fp16( sum_e vlin_h[j_e] * Wtab[bin_e] * Cg_e )  (fp32 acc)
// ---------------------------------------------------------------------------
__global__ __launch_bounds__(256) void k_agg(const int* __restrict__ rowstart,
                                             const int2* __restrict__ ecomb,
                                             const _Float16* __restrict__ vlin_h,
                                             const float* __restrict__ wtab,
                                             _Float16* __restrict__ agg_h, int n) {
    __shared__ float lwt[7 * HD];
    int tid = threadIdx.x;
    if (tid < 224) ((float4*)lwt)[tid] = ((const float4*)wtab)[tid];
    __syncthreads();

    int node = blockIdx.x * 4 + (tid >> 6);
    if (node >= n) return;
    int lane = tid & 63;
    int beg = rowstart[node], end = rowstart[node + 1];

    float accx = 0.f, accy = 0.f;
    const float* lwt2 = lwt + 2 * lane;
    int e = beg;
    for (; e + 3 < end; e += 4) {
        int2 c0 = ecomb[e],     c1 = ecomb[e + 1];
        int2 c2 = ecomb[e + 2], c3 = ecomb[e + 3];
        f16x2 h0 = *(const f16x2*)(vlin_h + (size_t)(c0.x & 0x01FFFFFF) * HD + 2 * lane);
        f16x2 h1 = *(const f16x2*)(vlin_h + (size_t)(c1.x & 0x01FFFFFF) * HD + 2 * lane);
        f16x2 h2 = *(const f16x2*)(vlin_h + (size_t)(c2.x & 0x01FFFFFF) * HD + 2 * lane);
        f16x2 h3 = *(const f16x2*)(vlin_h + (size_t)(c3.x & 0x01FFFFFF) * HD + 2 * lane);
        float2 w0 = *(const float2*)(lwt2 + (c0.x >> 25) * HD);
        float2 w1 = *(const float2*)(lwt2 + (c1.x >> 25) * HD);
        float2 w2 = *(const float2*)(lwt2 + (c2.x >> 25) * HD);
        float2 w3 = *(const float2*)(lwt2 + (c3.x >> 25) * HD);
        float g0 = __int_as_float(c0.y), g1 = __int_as_float(c1.y);
        float g2 = __int_as_float(c2.y), g3 = __int_as_float(c3.y);
        accx = fmaf((float)h0[0], w0.x * g0, accx);
        accy = fmaf((float)h0[1], w0.y * g0, accy);
        accx = fmaf((float)h1[0], w1.x * g1, accx);
        accy = fmaf((float)h1[1], w1.y * g1, accy);
        accx = fmaf((float)h2[0], w2.x * g2, accx);
        accy = fmaf((float)h2[1], w2.y * g2, accy);
        accx = fmaf((float)h3[0], w3.x * g3, accx);
        accy = fmaf((float)h3[1], w3.y * g3, accy);
    }
    for (; e < end; ++e) {
        int2 c0 = ecomb[e];
        f16x2 h0 = *(const f16x2*)(vlin_h + (size_t)(c0.x & 0x01FFFFFF) * HD + 2 * lane);
        float2 w0 = *(const float2*)(lwt2 + (c0.x >> 25) * HD);
        float g0 = __int_as_float(c0.y);
        accx = fmaf((float)h0[0], w0.x * g0, accx);
        accy = fmaf((float)h0[1], w0.y * g0, accy);
    }
    f16x2 o; o[0] = (_Float16)accx; o[1] = (_Float16)accy;
    *(f16x2*)(agg_h + (size_t)node * HD + 2 * lane) = o;
}

// ---------------------------------------------------------------------------
// k_front: v = z@init_w + init_b (VALU); vlin0_h = f16(v @ lin0) (MFMA)
// ---------------------------------------------------------------------------
__global__ __launch_bounds__(256) void k_front(const float* __restrict__ z,
                                               const float* __restrict__ iw,
                                               const float* __restrict__ ib,
                                               const _Float16* __restrict__ BfL,
                                               float* __restrict__ v,
                                               _Float16* __restrict__ vlin_h, int n) {
    __shared__ __attribute__((aligned(16))) float    ldsf[4][2048];
    __shared__ __attribute__((aligned(16))) _Float16 ldsh[4][2048];
    int tid = threadIdx.x, lane = tid & 63, wid = tid >> 6;
    int rowbase = blockIdx.x * 64 + wid * 16;
    float*    tile   = ldsf[wid];
    _Float16* tile16 = ldsh[wid];

    int row16 = lane & 15;
    int arow = min(rowbase + row16, n - 1);
    float z0 = z[arow * 3 + 0], z1 = z[arow * 3 + 1], z2 = z[arow * 3 + 2];
    int kg = (lane >> 4) * 8;

    f16x8 af[4];
    #pragma unroll
    for (int ks = 0; ks < 4; ++ks) {
        f16x8 h;
        #pragma unroll
        for (int j = 0; j < 8; ++j) {
            int c = ks * 32 + kg + j;
            float vv = fmaf(z0, iw[c], fmaf(z1, iw[HD + c], fmaf(z2, iw[2 * HD + c], ib[c])));
            h[j] = (_Float16)vv;
            *t32(tile, row16, c * 4) = vv;
        }
        af[ks] = h;
    }
    __syncthreads();                                  // v tile written -> read
    t32_epilogue<0, 0, 1>(tile, nullptr, v, rowbase, lane, n);

    f32x4 acc[8];
    #pragma unroll
    for (int i = 0; i < 8; ++i) acc[i] = (f32x4){0.f, 0.f, 0.f, 0.f};
    mfma32(af, BfL, lane, acc);
    acc_to_t16<0>(acc, nullptr, lane, tile16);
    __syncthreads();                                  // vlin tile written -> read
    t16_store(tile16, vlin_h, rowbase, lane, n);
}

// ---------------------------------------------------------------------------
// k_mid: tmp=ssp(agg@l1+b1); vnew = v + tmp@l2 + b2 -> v; vlin_h = f16(vnew@lin)
// ---------------------------------------------------------------------------
__global__ __launch_bounds__(256) void k_mid(const _Float16* __restrict__ agg_h,
                                             const _Float16* __restrict__ Bf1,
                                             const float* __restrict__ b1,
                                             const _Float16* __restrict__ Bf2,
                                             const float* __restrict__ b2,
                                             const _Float16* __restrict__ BfL,
                                             float* __restrict__ v,
                                             _Float16* __restrict__ vlin_h, int n) {
    __shared__ __attribute__((aligned(16))) float    ldsf[4][2048];
    __shared__ __attribute__((aligned(16))) _Float16 ldsh[4][2048];
    int tid = threadIdx.x, lane = tid & 63, wid = tid >> 6;
    int rowbase = blockIdx.x * 64 + wid * 16;
    float*    tile   = ldsf[wid];
    _Float16* tile16 = ldsh[wid];

    int arow = min(rowbase + (lane & 15), n - 1);
    int kg = (lane >> 4) * 8;
    f16x8 af[4];
    #pragma unroll
    for (int ks = 0; ks < 4; ++ks)
        af[ks] = *(const f16x8*)(agg_h + (size_t)arow * HD + ks * 32 + kg);

    f32x4 acc[8];
    #pragma unroll
    for (int i = 0; i < 8; ++i) acc[i] = (f32x4){0.f, 0.f, 0.f, 0.f};
    mfma32(af, Bf1, lane, acc);
    acc_to_t16<1>(acc, b1, lane, tile16);             // tmp tile (fp16)
    __syncthreads();                                  // tmp written -> read
    t16_to_af(tile16, lane, af);

    #pragma unroll
    for (int i = 0; i < 8; ++i) acc[i] = (f32x4){0.f, 0.f, 0.f, 0.f};
    mfma32(af, Bf2, lane, acc);
    acc_to_t32(acc, b2, lane, tile);                  // tmp@l2 + b2 (fp32)
    __syncthreads();                                  // tile written -> epilogue
    t32_epilogue<1, 1, 1>(tile, v, v, rowbase, lane, n);   // += v, wb LDS, store v
    __syncthreads();                                  // writeback -> read
    t32_to_af(tile, lane, af);                        // vnew A-frags

    #pragma unroll
    for (int i = 0; i < 8; ++i) acc[i] = (f32x4){0.f, 0.f, 0.f, 0.f};
    mfma32(af, BfL, lane, acc);
    acc_to_t16<0>(acc, nullptr, lane, tile16);
    __syncthreads();                                  // vlin tile written -> read
    t16_store(tile16, vlin_h, rowbase, lane, n);
}

// ---------------------------------------------------------------------------
// k_back: tmp=ssp(agg@l1+b1); vnew = v + tmp@l2 + b2 (LDS only);
//         u = ssp(vnew@u1+ub1); out = u @ u_l2[128,3] + ub2   (shfl reduce)
// ---------------------------------------------------------------------------
__global__ __launch_bounds__(256) void k_back(const _Float16* __restrict__ agg_h,
                                              const _Float16* __restrict__ Bf1,
                                              const float* __restrict__ b1,
                                              const _Float16* __restrict__ Bf2,
                                              const float* __restrict__ b2,
                                              const _Float16* __restrict__ BfU,
                                              const float* __restrict__ ub1,
                                              const float* __restrict__ w2,
                                              const float* __restrict__ ub2,
                                              const float* __restrict__ v,
                                              float* __restrict__ out, int n) {
    __shared__ __attribute__((aligned(16))) float    ldsf[4][2048];
    __shared__ __attribute__((aligned(16))) _Float16 ldsh[4][2048];
    int tid = threadIdx.x, lane = tid & 63, wid = tid >> 6;
    int rowbase = blockIdx.x * 64 + wid * 16;
    float*    tile   = ldsf[wid];
    _Float16* tile16 = ldsh[wid];

    int arow = min(rowbase + (lane & 15), n - 1);
    int kg = (lane >> 4) * 8;
    f16x8 af[4];
    #pragma unroll
    for (int ks = 0; ks < 4; ++ks)
        af[ks] = *(const f16x8*)(agg_h + (size_t)arow * HD + ks * 32 + kg);

    f32x4 acc[8];
    #pragma unroll
    for (int i = 0; i < 8; ++i) acc[i] = (f32x4){0.f, 0.f, 0.f, 0.f};
    mfma32(af, Bf1, lane, acc);
    acc_to_t16<1>(acc, b1, lane, tile16);
    __syncthreads();                                  // tmp written -> read
    t16_to_af(tile16, lane, af);

    #pragma unroll
    for (int i = 0; i < 8; ++i) acc[i] = (f32x4){0.f, 0.f, 0.f, 0.f};
    mfma32(af, Bf2, lane, acc);
    acc_to_t32(acc, b2, lane, tile);
    __syncthreads();                                  // tile written -> epilogue
    t32_epilogue<1, 1, 0>(tile, v, nullptr, rowbase, lane, n);  // += v, wb LDS
    __syncthreads();                                  // writeback -> read
    t32_to_af(tile, lane, af);

    #pragma unroll
    for (int i = 0; i < 8; ++i) acc[i] = (f32x4){0.f, 0.f, 0.f, 0.f};
    mfma32(af, BfU, lane, acc);

    // readout: per-lane partials over its 8 cols, then 16-lane shfl reduce
    int col0 = lane & 15, r0 = (lane >> 4) * 4;
    float p0[4] = {0.f, 0.f, 0.f, 0.f};
    float p1[4] = {0.f, 0.f, 0.f, 0.f};
    float p2[4] = {0.f, 0.f, 0.f, 0.f};
    #pragma unroll
    for (int ct = 0; ct < 8; ++ct) {
        int c = ct * 16 + col0;
        float bu = ub1[c];
        float w20 = w2[c * 3 + 0], w21 = w2[c * 3 + 1], w22 = w2[c * 3 + 2];
        #pragma unroll
        for (int r = 0; r < 4; ++r) {
            float u = ssp(acc[ct][r] + bu);
            p0[r] = fmaf(u, w20, p0[r]);
            p1[r] = fmaf(u, w21, p1[r]);
            p2[r] = fmaf(u, w22, p2[r]);
        }
    }
    #pragma unroll
    for (int m = 1; m < 16; m <<= 1) {
        #pragma unroll
        for (int r = 0; r < 4; ++r) {
            p0[r] += __shfl_xor(p0[r], m, 64);
            p1[r] += __shfl_xor(p1[r], m, 64);
            p2[r] += __shfl_xor(p2[r], m, 64);
        }
    }
    if (col0 == 0) {
        #pragma unroll
        for (int r = 0; r < 4; ++r) {
            int row = rowbase + r0 + r;
            if (row < n) {
                out[(size_t)row * 3 + 0] = p0[r] + ub2[0];
                out[(size_t)row * 3 + 1] = p1[r] + ub2[1];
                out[(size_t)row * 3 + 2] = p2[r] + ub2[2];
            }
        }
    }
}

// ---------------------------------------------------------------------------
extern "C" void kernel_launch(void* const* d_in, const int* in_sizes, int n_in,
                              void* d_out, int out_size, void* d_ws, size_t ws_size,
                              hipStream_t stream) {
    const float* z      = (const float*)d_in[0];
    const float* dist   = (const float*)d_in[1];
    const int*   ei     = (const int*)d_in[2];
    const float* init_w = (const float*)d_in[3];
    const float* init_b = (const float*)d_in[4];

    const float* L[2][9];
    for (int l = 0; l < 2; ++l)
        for (int p = 0; p < 9; ++p)
            L[l][p] = (const float*)d_in[5 + l * 9 + p];

    const float* u_l1_w = (const float*)d_in[23];
    const float* u_l1_b = (const float*)d_in[24];
    const float* u_l2_w = (const float*)d_in[25];
    const float* u_l2_b = (const float*)d_in[26];
    float* out = (float*)d_out;

    const int N = in_sizes[0] / 3;
    const int E = in_sizes[1];

    // workspace layout (float units)
    float* wtab   = (float*)d_ws;                     // 2*7*128 = 1792 (pad 2048)
    float* bf     = wtab + 2048;                      // 7*16384 halves = 57344 f
    float* v      = bf + 57344;                       // N*128
    float* vh     = v + (size_t)N * HD;               // N*128 halves = N*64 f
    float* aggh   = vh + (size_t)N * 64;              // N*64 f
    int2*  ecomb  = (int2*)(aggh + (size_t)N * 64);   // E int2
    int*   deg    = (int*)(ecomb + E);                // N
    int*   rowstart = deg + N;                        // N+1
    int*   cursor = rowstart + N + 1;                 // N
    int*   blocksum = cursor + N;                     // 64

    _Float16* vlin_h = (_Float16*)vh;
    _Float16* agg_h  = (_Float16*)aggh;
    _Float16* Bf     = (_Float16*)bf;
    // slots: 0=lin0 1=l1_0 2=l2_0 3=lin1 4=l1_1 5=l2_1 6=u_l1
    _Float16* BfW[7];
    for (int i = 0; i < 7; ++i) BfW[i] = Bf + (size_t)i * 16384;

    const int mmGrid   = (N + 63) / 64;
    const int edgeGrid = (E + 255) / 256;
    const int scanB    = (N + 1 + 1023) / 1024;
    const int aggGrid  = (N + 3) / 4;

    Ptr8 wt; wt.p[0] = L[0][1]; wt.p[1] = L[0][2]; wt.p[2] = L[0][3]; wt.p[3] = L[0][4];
             wt.p[4] = L[1][1]; wt.p[5] = L[1][2]; wt.p[6] = L[1][3]; wt.p[7] = L[1][4];
    k_wtab2<<<dim3(7, 2), HD, 0, stream>>>(wt, wtab);

    Ptr8 pb; pb.p[0] = L[0][0]; pb.p[1] = L[0][5]; pb.p[2] = L[0][7];
             pb.p[3] = L[1][0]; pb.p[4] = L[1][5]; pb.p[5] = L[1][7];
             pb.p[6] = u_l1_w;  pb.p[7] = u_l1_w;
    k_prepB7<<<dim3(8, 7), 256, 0, stream>>>(pb, Bf);   // 2048 frags/slot exactly

    // CSR build
    hipMemsetAsync(deg, 0, (size_t)N * sizeof(int), stream);
    k_deg<<<edgeGrid, 256, 0, stream>>>(ei, deg, E);
    k_scan1<<<scanB, 1024, 0, stream>>>(deg, rowstart, blocksum, N);
    k_scan2<<<1, 64, 0, stream>>>(blocksum, scanB);
    k_scan3<<<scanB, 1024, 0, stream>>>(rowstart, cursor, blocksum, N);
    k_escatter<<<edgeGrid, 256, 0, stream>>>(ei, dist, cursor, ecomb, E);

    // layer 0
    k_front<<<mmGrid, 256, 0, stream>>>(z, init_w, init_b, BfW[0], v, vlin_h, N);
    k_agg<<<aggGrid, 256, 0, stream>>>(rowstart, ecomb, vlin_h, wtab, agg_h, N);
    // layer 0 update_v + layer 1 lin
    k_mid<<<mmGrid, 256, 0, stream>>>(agg_h, BfW[1], L[0][6], BfW[2], L[0][8],
                                      BfW[3], v, vlin_h, N);
    k_agg<<<aggGrid, 256, 0, stream>>>(rowstart, ecomb, vlin_h, wtab + 7 * HD, agg_h, N);
    // layer 1 update_v + readout
    k_back<<<mmGrid, 256, 0, stream>>>(agg_h, BfW[4], L[1][6], BfW[5], L[1][8],
                                       BfW[6], u_l1_b, u_l2_w, u_l2_b, v, out, N);
}

// Round 7
// 362.454 us; speedup vs baseline: 8.6922x; 1.3729x over previous
//
#include <hip/hip_runtime.h>
#include <cstdint>
#include <cstddef>

#define HD 128              // hidden channels
#define GD 50               // gaussians
static constexpr float PI_F   = 3.14159265358979323846f;
static constexpr float CUTF   = 6.0f;
static constexpr float SHIFTF = 0.69314718055994530942f; // ln(2)

typedef _Float16 f16x8 __attribute__((ext_vector_type(8)));
typedef _Float16 f16x2 __attribute__((ext_vector_type(2)));
typedef float    f32x4 __attribute__((ext_vector_type(4)));

struct Ptr8 { const float* p[8]; };

// fast ShiftedSoftplus: native v_exp_f32 / v_log_f32 (error ~1e-6 abs)
__device__ __forceinline__ float ssp(float x) {
    float e = __expf(-fabsf(x));
    return fmaxf(x, 0.0f) + __logf(1.0f + e) - SHIFTF;
}

// ---------------------------------------------------------------------------
// Swizzled per-wave fp16 LDS tile (16 rows x 128 cols, 256 B/row).
// XOR bits 4-6 of byte offset with (row&7)<<4 (G4 conflict fix).
// ---------------------------------------------------------------------------
__device__ __forceinline__ _Float16* t16(_Float16* base, int row, int byte) {
    return (_Float16*)((char*)base + row * 256 + (byte ^ ((row & 7) << 4)));
}

// 32 MFMAs: acc[ct] += A(af) * Bf[ct,ks]
__device__ __forceinline__ void mfma32(const f16x8 af[4],
                                       const _Float16* __restrict__ Bf,
                                       int lane, f32x4 acc[8]) {
    #pragma unroll
    for (int ks = 0; ks < 4; ++ks)
        #pragma unroll
        for (int ct = 0; ct < 8; ++ct)
            acc[ct] = __builtin_amdgcn_mfma_f32_16x16x32_f16(
                af[ks], ((const f16x8*)Bf)[(ct * 4 + ks) * 64 + lane], acc[ct], 0, 0, 0);
}

// C/D layout (m89): col = lane&15, row_local = (lane>>4)*4 + r
template <int ACT>
__device__ __forceinline__ void acc_to_t16(const f32x4 acc[8], const float* bias,
                                           int lane, _Float16* tile) {
    int col0 = lane & 15, r0 = (lane >> 4) * 4;
    #pragma unroll
    for (int ct = 0; ct < 8; ++ct) {
        int c = ct * 16 + col0;
        float bs = bias ? bias[c] : 0.f;
        #pragma unroll
        for (int r = 0; r < 4; ++r) {
            float o = acc[ct][r] + bs;
            if (ACT) o = ssp(o);
            *t16(tile, r0 + r, c * 2) = (_Float16)o;
        }
    }
}

// A-fragments (lane: row = lane&15, k = (lane>>4)*8 + j per ks) from fp16 tile
__device__ __forceinline__ void t16_to_af(_Float16* tile, int lane, f16x8 af[4]) {
    int row = lane & 15, kgB = (lane >> 4) * 16;
    #pragma unroll
    for (int ks = 0; ks < 4; ++ks)
        af[ks] = *(const f16x8*)t16(tile, row, ks * 64 + kgB);
}

// fp16 tile -> coalesced global f16x8 stores
__device__ __forceinline__ void t16_store(_Float16* tile, _Float16* g,
                                          int rowbase, int lane, int n) {
    #pragma unroll
    for (int it = 0; it < 4; ++it) {
        int f8 = it * 64 + lane;
        int row = f8 >> 4, g8 = f8 & 15;
        f16x8 h = *(const f16x8*)t16(tile, row, g8 * 16);
        if (rowbase + row < n) ((f16x8*)g)[(size_t)(rowbase + row) * 16 + g8] = h;
    }
}

// v(z) in accumulator layout: vz[ct][r] for rows rowbase+r0+r, col ct*16+col0
__device__ __forceinline__ void vz_acc(const float* __restrict__ z,
                                       const float* __restrict__ iw,
                                       const float* __restrict__ ib,
                                       int rowbase, int lane, int n,
                                       f32x4 vz[8]) {
    int col0 = lane & 15, r0 = (lane >> 4) * 4;
    float zr[4][3];
    #pragma unroll
    for (int r = 0; r < 4; ++r) {
        int row = min(rowbase + r0 + r, n - 1);
        zr[r][0] = z[row * 3 + 0];
        zr[r][1] = z[row * 3 + 1];
        zr[r][2] = z[row * 3 + 2];
    }
    #pragma unroll
    for (int ct = 0; ct < 8; ++ct) {
        int c = ct * 16 + col0;
        float w0 = iw[c], w1 = iw[HD + c], w2 = iw[2 * HD + c], bz = ib[c];
        #pragma unroll
        for (int r = 0; r < 4; ++r)
            vz[ct][r] = fmaf(zr[r][0], w0, fmaf(zr[r][1], w1, fmaf(zr[r][2], w2, bz)));
    }
}

// ---------------------------------------------------------------------------
// Wtab[layer][bin][h], grid (7 bins, 2 layers)
// ---------------------------------------------------------------------------
__global__ __launch_bounds__(HD) void k_wtab2(Ptr8 P, float* __restrict__ wtab) {
    const int bin = blockIdx.x, layer = blockIdx.y;
    const int t = threadIdx.x;
    const float* m0w = P.p[layer * 4 + 0];
    const float* m0b = P.p[layer * 4 + 1];
    const float* m2w = P.p[layer * 4 + 2];
    const float* m2b = P.p[layer * 4 + 3];
    __shared__ float hbuf[HD];

    const float spacing = CUTF / (GD - 1);
    const float coeff   = -0.5f / (spacing * spacing);

    float acc = m0b[t];
    #pragma unroll 5
    for (int g = 0; g < GD; ++g) {
        float d = (float)bin - (float)g * spacing;
        acc = fmaf(__expf(coeff * d * d), m0w[g * HD + t], acc);
    }
    hbuf[t] = ssp(acc);
    __syncthreads();

    float acc2 = m2b[t];
    #pragma unroll 8
    for (int k = 0; k < HD; ++k)
        acc2 = fmaf(hbuf[k], m2w[k * HD + t], acc2);
    wtab[(layer * 7 + bin) * HD + t] = acc2;
}

// ---------------------------------------------------------------------------
// Pack 7 [128,128] fp32 weights into fp16 MFMA B-fragment order.
// EXACTLY 2048 f16x8 fragments per slot: grid dim3(8, 7) + guard.
// ---------------------------------------------------------------------------
__global__ __launch_bounds__(256) void k_prepB7(Ptr8 P, _Float16* __restrict__ Bf) {
    int slot = blockIdx.y;
    const float* W = P.p[slot];
    int idx = blockIdx.x * 256 + threadIdx.x;   // 0..2047
    if (idx >= 2048) return;
    int l  = idx & 63;
    int f  = idx >> 6;        // 0..31 = ct*4+ks
    int ks = f & 3, ct = f >> 2;
    int col = ct * 16 + (l & 15);
    int k0  = ks * 32 + ((l >> 4) << 3);
    f16x8 o;
    #pragma unroll
    for (int j = 0; j < 8; ++j) o[j] = (_Float16)W[(size_t)(k0 + j) * HD + col];
    ((f16x8*)(Bf + (size_t)slot * 16384))[idx] = o;
}

// ---------------------------------------------------------------------------
// CSR build
// ---------------------------------------------------------------------------
__global__ __launch_bounds__(256) void k_deg(const int* __restrict__ ei,
                                             int* __restrict__ deg, int nedges) {
    int e = blockIdx.x * 256 + threadIdx.x;
    if (e < nedges) atomicAdd(&deg[ei[nedges + e]], 1);
}

__global__ __launch_bounds__(1024) void k_scan1(const int* __restrict__ deg,
                                                int* __restrict__ rowstart,
                                                int* __restrict__ blocksum, int n) {
    __shared__ int wsum[16];
    int tid  = threadIdx.x;
    int lane = tid & 63, wid = tid >> 6;
    int i = blockIdx.x * 1024 + tid;
    int val = (i < n) ? deg[i] : 0;
    int x = val;
    #pragma unroll
    for (int off = 1; off < 64; off <<= 1) {
        int y = __shfl_up(x, off, 64);
        if (lane >= off) x += y;
    }
    if (lane == 63) wsum[wid] = x;
    __syncthreads();
    if (wid == 0) {
        int s = (lane < 16) ? wsum[lane] : 0;
        #pragma unroll
        for (int off = 1; off < 16; off <<= 1) {
            int y = __shfl_up(s, off, 64);
            if (lane >= off) s += y;
        }
        if (lane < 16) wsum[lane] = s;
    }
    __syncthreads();
    int wbase = (wid > 0) ? wsum[wid - 1] : 0;
    if (i <= n) rowstart[i] = wbase + x - val;
    if (tid == 1023) blocksum[blockIdx.x] = wsum[15];
}

__global__ __launch_bounds__(64) void k_scan2(int* __restrict__ blocksum, int nb) {
    int lane = threadIdx.x;
    int v = (lane < nb) ? blocksum[lane] : 0;
    int x = v;
    #pragma unroll
    for (int off = 1; off < 64; off <<= 1) {
        int y = __shfl_up(x, off, 64);
        if (lane >= off) x += y;
    }
    if (lane < nb) blocksum[lane] = x - v;
}

__global__ __launch_bounds__(1024) void k_scan3(int* __restrict__ rowstart,
                                                int* __restrict__ cursor,
                                                const int* __restrict__ blocksum,
                                                int n) {
    int i = blockIdx.x * 1024 + threadIdx.x;
    if (i <= n) {
        int rs = rowstart[i] + blocksum[blockIdx.x];
        rowstart[i] = rs;
        if (i < n) cursor[i] = rs;
    }
}

// single int2 per edge -> one dirtied line per edge
__global__ __launch_bounds__(256) void k_escatter(const int* __restrict__ ei,
                                                  const float* __restrict__ dist,
                                                  int* __restrict__ cursor,
                                                  int2* __restrict__ ecomb,
                                                  int nedges) {
    int e = blockIdx.x * 256 + threadIdx.x;
    if (e >= nedges) return;
    int   j = ei[e];
    int   i = ei[nedges + e];
    float d = dist[e];
    int bin = min((int)d, 6);
    float Cg = 0.5f * (cosf(d * (PI_F / CUTF)) + 1.0f);
    int pos = atomicAdd(&cursor[i], 1);
    ecomb[pos] = make_int2(j | (bin << 25), __float_as_int(Cg));
}

// ---------------------------------------------------------------------------
// agg_h[node] = fp16( sum_e vlin_h[j_e] * Wtab[bin_e] * Cg_e )  (fp32 acc)
// ---------------------------------------------------------------------------
__global__ __launch_bounds__(256) void k_agg(const int* __restrict__ rowstart,
                                             const int2* __restrict__ ecomb,
                                             const _Float16* __restrict__ vlin_h,
                                             const float* __restrict__ wtab,
                                             _Float16* __restrict__ agg_h, int n) {
    __shared__ float lwt[7 * HD];
    int tid = threadIdx.x;
    if (tid < 224) ((float4*)lwt)[tid] = ((const float4*)wtab)[tid];
    __syncthreads();

    int node = blockIdx.x * 4 + (tid >> 6);
    if (node >= n) return;
    int lane = tid & 63;
    int beg = rowstart[node], end = rowstart[node + 1];

    float accx = 0.f, accy = 0.f;
    const float* lwt2 = lwt + 2 * lane;
    int e = beg;
    for (; e + 3 < end; e += 4) {
        int2 c0 = ecomb[e],     c1 = ecomb[e + 1];
        int2 c2 = ecomb[e + 2], c3 = ecomb[e + 3];
        f16x2 h0 = *(const f16x2*)(vlin_h + (size_t)(c0.x & 0x01FFFFFF) * HD + 2 * lane);
        f16x2 h1 = *(const f16x2*)(vlin_h + (size_t)(c1.x & 0x01FFFFFF) * HD + 2 * lane);
        f16x2 h2 = *(const f16x2*)(vlin_h + (size_t)(c2.x & 0x01FFFFFF) * HD + 2 * lane);
        f16x2 h3 = *(const f16x2*)(vlin_h + (size_t)(c3.x & 0x01FFFFFF) * HD + 2 * lane);
        float2 w0 = *(const float2*)(lwt2 + (c0.x >> 25) * HD);
        float2 w1 = *(const float2*)(lwt2 + (c1.x >> 25) * HD);
        float2 w2 = *(const float2*)(lwt2 + (c2.x >> 25) * HD);
        float2 w3 = *(const float2*)(lwt2 + (c3.x >> 25) * HD);
        float g0 = __int_as_float(c0.y), g1 = __int_as_float(c1.y);
        float g2 = __int_as_float(c2.y), g3 = __int_as_float(c3.y);
        accx = fmaf((float)h0[0], w0.x * g0, accx);
        accy = fmaf((float)h0[1], w0.y * g0, accy);
        accx = fmaf((float)h1[0], w1.x * g1, accx);
        accy = fmaf((float)h1[1], w1.y * g1, accy);
        accx = fmaf((float)h2[0], w2.x * g2, accx);
        accy = fmaf((float)h2[1], w2.y * g2, accy);
        accx = fmaf((float)h3[0], w3.x * g3, accx);
        accy = fmaf((float)h3[1], w3.y * g3, accy);
    }
    for (; e < end; ++e) {
        int2 c0 = ecomb[e];
        f16x2 h0 = *(const f16x2*)(vlin_h + (size_t)(c0.x & 0x01FFFFFF) * HD + 2 * lane);
        float2 w0 = *(const float2*)(lwt2 + (c0.x >> 25) * HD);
        float g0 = __int_as_float(c0.y);
        accx = fmaf((float)h0[0], w0.x * g0, accx);
        accy = fmaf((float)h0[1], w0.y * g0, accy);
    }
    f16x2 o; o[0] = (_Float16)accx; o[1] = (_Float16)accy;
    *(f16x2*)(agg_h + (size_t)node * HD + 2 * lane) = o;
}

// ---------------------------------------------------------------------------
// k_front: vlin0_h = f16( (z@init_w + init_b) @ lin0 ).   No v store.
// ---------------------------------------------------------------------------
__global__ __launch_bounds__(256) void k_front(const float* __restrict__ z,
                                               const float* __restrict__ iw,
                                               const float* __restrict__ ib,
                                               const _Float16* __restrict__ BfL,
                                               _Float16* __restrict__ vlin_h, int n) {
    __shared__ __attribute__((aligned(16))) _Float16 ldsh[4][2048];
    int tid = threadIdx.x, lane = tid & 63, wid = tid >> 6;
    int rowbase = blockIdx.x * 64 + wid * 16;
    _Float16* tile16 = ldsh[wid];

    int arow = min(rowbase + (lane & 15), n - 1);
    float z0 = z[arow * 3 + 0], z1 = z[arow * 3 + 1], z2 = z[arow * 3 + 2];
    int kg = (lane >> 4) * 8;

    f16x8 af[4];
    #pragma unroll
    for (int ks = 0; ks < 4; ++ks) {
        f16x8 h;
        #pragma unroll
        for (int j = 0; j < 8; ++j) {
            int c = ks * 32 + kg + j;
            h[j] = (_Float16)fmaf(z0, iw[c], fmaf(z1, iw[HD + c], fmaf(z2, iw[2 * HD + c], ib[c])));
        }
        af[ks] = h;
    }

    f32x4 acc[8];
    #pragma unroll
    for (int i = 0; i < 8; ++i) acc[i] = (f32x4){0.f, 0.f, 0.f, 0.f};
    mfma32(af, BfL, lane, acc);
    acc_to_t16<0>(acc, nullptr, lane, tile16);
    __syncthreads();
    t16_store(tile16, vlin_h, rowbase, lane, n);
}

// ---------------------------------------------------------------------------
// k_mid: tmp=ssp(agg@l1+b1); vnew = v(z) + tmp@l2 + b2 (acc layout, regs);
//        store vnew -> vres (acc-layout f32, coalesced); vlin_h = f16(vnew@lin1)
// ---------------------------------------------------------------------------
__global__ __launch_bounds__(256) void k_mid(const _Float16* __restrict__ agg_h,
                                             const _Float16* __restrict__ Bf1,
                                             const float* __restrict__ b1,
                                             const _Float16* __restrict__ Bf2,
                                             const float* __restrict__ b2,
                                             const _Float16* __restrict__ BfL,
                                             const float* __restrict__ z,
                                             const float* __restrict__ iw,
                                             const float* __restrict__ ib,
                                             f32x4* __restrict__ vres4,
                                             _Float16* __restrict__ vlin_h, int n) {
    __shared__ __attribute__((aligned(16))) _Float16 ldsh[4][2048];
    int tid = threadIdx.x, lane = tid & 63, wid = tid >> 6;
    int rowbase = blockIdx.x * 64 + wid * 16;
    _Float16* tile16 = ldsh[wid];

    int arow = min(rowbase + (lane & 15), n - 1);
    int kg = (lane >> 4) * 8;
    f16x8 af[4];
    #pragma unroll
    for (int ks = 0; ks < 4; ++ks)
        af[ks] = *(const f16x8*)(agg_h + (size_t)arow * HD + ks * 32 + kg);

    f32x4 acc[8];
    #pragma unroll
    for (int i = 0; i < 8; ++i) acc[i] = (f32x4){0.f, 0.f, 0.f, 0.f};
    mfma32(af, Bf1, lane, acc);
    acc_to_t16<1>(acc, b1, lane, tile16);             // tmp = ssp(..+b1)
    __syncthreads();
    t16_to_af(tile16, lane, af);

    #pragma unroll
    for (int i = 0; i < 8; ++i) acc[i] = (f32x4){0.f, 0.f, 0.f, 0.f};
    mfma32(af, Bf2, lane, acc);

    // vnew = v(z) + acc + b2  (accumulator layout, registers)
    f32x4 vz[8];
    vz_acc(z, iw, ib, rowbase, lane, n, vz);
    int col0 = lane & 15;
    #pragma unroll
    for (int ct = 0; ct < 8; ++ct) {
        float bs = b2[ct * 16 + col0];
        #pragma unroll
        for (int r = 0; r < 4; ++r) acc[ct][r] += bs + vz[ct][r];
        size_t g = ((size_t)(blockIdx.x * 4 + wid) * 8 + ct) * 64 + lane;
        vres4[g] = acc[ct];                           // coalesced 16B store
    }

    acc_to_t16<0>(acc, nullptr, lane, tile16);        // vnew -> fp16 tile
    __syncthreads();
    t16_to_af(tile16, lane, af);

    #pragma unroll
    for (int i = 0; i < 8; ++i) acc[i] = (f32x4){0.f, 0.f, 0.f, 0.f};
    mfma32(af, BfL, lane, acc);
    acc_to_t16<0>(acc, nullptr, lane, tile16);
    __syncthreads();
    t16_store(tile16, vlin_h, rowbase, lane, n);
}

// ---------------------------------------------------------------------------
// k_back: tmp=ssp(agg@l1+b1); vnew = vres + tmp@l2 + b2 (regs);
//         u = ssp(vnew@u1+ub1); out = u @ u_l2[128,3] + ub2   (shfl reduce)
// ---------------------------------------------------------------------------
__global__ __launch_bounds__(256) void k_back(const _Float16* __restrict__ agg_h,
                                              const _Float16* __restrict__ Bf1,
                                              const float* __restrict__ b1,
                                              const _Float16* __restrict__ Bf2,
                                              const float* __restrict__ b2,
                                              const _Float16* __restrict__ BfU,
                                              const float* __restrict__ ub1,
                                              const float* __restrict__ w2,
                                              const float* __restrict__ ub2,
                                              const f32x4* __restrict__ vres4,
                                              float* __restrict__ out, int n) {
    __shared__ __attribute__((aligned(16))) _Float16 ldsh[4][2048];
    int tid = threadIdx.x, lane = tid & 63, wid = tid >> 6;
    int rowbase = blockIdx.x * 64 + wid * 16;
    _Float16* tile16 = ldsh[wid];

    int arow = min(rowbase + (lane & 15), n - 1);
    int kg = (lane >> 4) * 8;
    f16x8 af[4];
    #pragma unroll
    for (int ks = 0; ks < 4; ++ks)
        af[ks] = *(const f16x8*)(agg_h + (size_t)arow * HD + ks * 32 + kg);

    f32x4 acc[8];
    #pragma unroll
    for (int i = 0; i < 8; ++i) acc[i] = (f32x4){0.f, 0.f, 0.f, 0.f};
    mfma32(af, Bf1, lane, acc);
    acc_to_t16<1>(acc, b1, lane, tile16);
    __syncthreads();
    t16_to_af(tile16, lane, af);

    #pragma unroll
    for (int i = 0; i < 8; ++i) acc[i] = (f32x4){0.f, 0.f, 0.f, 0.f};
    mfma32(af, Bf2, lane, acc);

    // vnew = vres + acc + b2  (registers, coalesced vres load)
    int col0 = lane & 15;
    #pragma unroll
    for (int ct = 0; ct < 8; ++ct) {
        float bs = b2[ct * 16 + col0];
        f32x4 rv = vres4[((size_t)(blockIdx.x * 4 + wid) * 8 + ct) * 64 + lane];
        #pragma unroll
        for (int r = 0; r < 4; ++r) acc[ct][r] += bs + rv[r];
    }

    acc_to_t16<0>(acc, nullptr, lane, tile16);
    __syncthreads();
    t16_to_af(tile16, lane, af);

    #pragma unroll
    for (int i = 0; i < 8; ++i) acc[i] = (f32x4){0.f, 0.f, 0.f, 0.f};
    mfma32(af, BfU, lane, acc);

    // readout: per-lane partials over its 8 cols, then 16-lane shfl reduce
    int r0 = (lane >> 4) * 4;
    float p0[4] = {0.f, 0.f, 0.f, 0.f};
    float p1[4] = {0.f, 0.f, 0.f, 0.f};
    float p2[4] = {0.f, 0.f, 0.f, 0.f};
    #pragma unroll
    for (int ct = 0; ct < 8; ++ct) {
        int c = ct * 16 + col0;
        float bu = ub1[c];
        float w20 = w2[c * 3 + 0], w21 = w2[c * 3 + 1], w22 = w2[c * 3 + 2];
        #pragma unroll
        for (int r = 0; r < 4; ++r) {
            float u = ssp(acc[ct][r] + bu);
            p0[r] = fmaf(u, w20, p0[r]);
            p1[r] = fmaf(u, w21, p1[r]);
            p2[r] = fmaf(u, w22, p2[r]);
        }
    }
    #pragma unroll
    for (int m = 1; m < 16; m <<= 1) {
        #pragma unroll
        for (int r = 0; r < 4; ++r) {
            p0[r] += __shfl_xor(p0[r], m, 64);
            p1[r] += __shfl_xor(p1[r], m, 64);
            p2[r] += __shfl_xor(p2[r], m, 64);
        }
    }
    if (col0 == 0) {
        #pragma unroll
        for (int r = 0; r < 4; ++r) {
            int row = rowbase + r0 + r;
            if (row < n) {
                out[(size_t)row * 3 + 0] = p0[r] + ub2[0];
                out[(size_t)row * 3 + 1] = p1[r] + ub2[1];
                out[(size_t)row * 3 + 2] = p2[r] + ub2[2];
            }
        }
    }
}

// ---------------------------------------------------------------------------
extern "C" void kernel_launch(void* const* d_in, const int* in_sizes, int n_in,
                              void* d_out, int out_size, void* d_ws, size_t ws_size,
                              hipStream_t stream) {
    const float* z      = (const float*)d_in[0];
    const float* dist   = (const float*)d_in[1];
    const int*   ei     = (const int*)d_in[2];
    const float* init_w = (const float*)d_in[3];
    const float* init_b = (const float*)d_in[4];

    const float* L[2][9];
    for (int l = 0; l < 2; ++l)
        for (int p = 0; p < 9; ++p)
            L[l][p] = (const float*)d_in[5 + l * 9 + p];

    const float* u_l1_w = (const float*)d_in[23];
    const float* u_l1_b = (const float*)d_in[24];
    const float* u_l2_w = (const float*)d_in[25];
    const float* u_l2_b = (const float*)d_in[26];
    float* out = (float*)d_out;

    const int N = in_sizes[0] / 3;
    const int E = in_sizes[1];

    const int mmGrid   = (N + 63) / 64;
    const int edgeGrid = (E + 255) / 256;
    const int scanB    = (N + 1 + 1023) / 1024;
    const int aggGrid  = (N + 3) / 4;

    // workspace layout (float units)
    float* wtab   = (float*)d_ws;                     // 2048
    float* bf     = wtab + 2048;                      // 57344
    float* vres   = bf + 57344;                       // mmGrid*8192 (acc layout)
    float* vh     = vres + (size_t)mmGrid * 8192;     // N*64
    float* aggh   = vh + (size_t)N * 64;              // N*64
    int2*  ecomb  = (int2*)(aggh + (size_t)N * 64);   // E int2
    int*   deg    = (int*)(ecomb + E);                // N
    int*   rowstart = deg + N;                        // N+1
    int*   cursor = rowstart + N + 1;                 // N
    int*   blocksum = cursor + N;                     // 64

    _Float16* vlin_h = (_Float16*)vh;
    _Float16* agg_h  = (_Float16*)aggh;
    f32x4*    vres4  = (f32x4*)vres;
    _Float16* Bf     = (_Float16*)bf;
    // slots: 0=lin0 1=l1_0 2=l2_0 3=lin1 4=l1_1 5=l2_1 6=u_l1
    _Float16* BfW[7];
    for (int i = 0; i < 7; ++i) BfW[i] = Bf + (size_t)i * 16384;

    Ptr8 wt; wt.p[0] = L[0][1]; wt.p[1] = L[0][2]; wt.p[2] = L[0][3]; wt.p[3] = L[0][4];
             wt.p[4] = L[1][1]; wt.p[5] = L[1][2]; wt.p[6] = L[1][3]; wt.p[7] = L[1][4];
    k_wtab2<<<dim3(7, 2), HD, 0, stream>>>(wt, wtab);

    Ptr8 pb; pb.p[0] = L[0][0]; pb.p[1] = L[0][5]; pb.p[2] = L[0][7];
             pb.p[3] = L[1][0]; pb.p[4] = L[1][5]; pb.p[5] = L[1][7];
             pb.p[6] = u_l1_w;  pb.p[7] = u_l1_w;
    k_prepB7<<<dim3(8, 7), 256, 0, stream>>>(pb, Bf);   // 2048 frags/slot exactly

    // CSR build
    hipMemsetAsync(deg, 0, (size_t)N * sizeof(int), stream);
    k_deg<<<edgeGrid, 256, 0, stream>>>(ei, deg, E);
    k_scan1<<<scanB, 1024, 0, stream>>>(deg, rowstart, blocksum, N);
    k_scan2<<<1, 64, 0, stream>>>(blocksum, scanB);
    k_scan3<<<scanB, 1024, 0, stream>>>(rowstart, cursor, blocksum, N);
    k_escatter<<<edgeGrid, 256, 0, stream>>>(ei, dist, cursor, ecomb, E);

    // layer 0
    k_front<<<mmGrid, 256, 0, stream>>>(z, init_w, init_b, BfW[0], vlin_h, N);
    k_agg<<<aggGrid, 256, 0, stream>>>(rowstart, ecomb, vlin_h, wtab, agg_h, N);
    // layer 0 update_v + layer 1 lin  (v recomputed from z; vnew -> vres)
    k_mid<<<mmGrid, 256, 0, stream>>>(agg_h, BfW[1], L[0][6], BfW[2], L[0][8],
                                      BfW[3], z, init_w, init_b, vres4, vlin_h, N);
    k_agg<<<aggGrid, 256, 0, stream>>>(rowstart, ecomb, vlin_h, wtab + 7 * HD, agg_h, N);
    // layer 1 update_v + readout
    k_back<<<mmGrid, 256, 0, stream>>>(agg_h, BfW[4], L[1][6], BfW[5], L[1][8],
                                       BfW[6], u_l1_b, u_l2_w, u_l2_b, vres4, out, N);
}

// Round 10
// 356.403 us; speedup vs baseline: 8.8398x; 1.0170x over previous
//
#include <hip/hip_runtime.h>
#include <cstdint>
#include <cstddef>

#define HD 128              // hidden channels
#define GD 50               // gaussians
static constexpr float PI_F   = 3.14159265358979323846f;
static constexpr float CUTF   = 6.0f;
static constexpr float SHIFTF = 0.69314718055994530942f; // ln(2)

typedef _Float16 f16x8 __attribute__((ext_vector_type(8)));
typedef _Float16 f16x2 __attribute__((ext_vector_type(2)));
typedef float    f32x4 __attribute__((ext_vector_type(4)));

struct Ptr8 { const float* p[8]; };

// fast ShiftedSoftplus: native v_exp_f32 / v_log_f32
__device__ __forceinline__ float ssp(float x) {
    float e = __expf(-fabsf(x));
    return fmaxf(x, 0.0f) + __logf(1.0f + e) - SHIFTF;
}

// ---------------------------------------------------------------------------
// Swizzled fp16 LDS tile (16 rows x 128 cols, 256 B/row), XOR G4 fix.
// ---------------------------------------------------------------------------
__device__ __forceinline__ _Float16* t16(_Float16* base, int row, int byte) {
    return (_Float16*)((char*)base + row * 256 + (byte ^ ((row & 7) << 4)));
}

// 8 MFMAs covering 2 column-tiles (ctb, ctb+1) x 4 k-slices
__device__ __forceinline__ void mfma_ct(const f16x8 af[4],
                                        const _Float16* __restrict__ Bf,
                                        int lane, f32x4 acc[2], int ctb) {
    #pragma unroll
    for (int ks = 0; ks < 4; ++ks)
        #pragma unroll
        for (int c = 0; c < 2; ++c)
            acc[c] = __builtin_amdgcn_mfma_f32_16x16x32_f16(
                af[ks], ((const f16x8*)Bf)[((ctb + c) * 4 + ks) * 64 + lane],
                acc[c], 0, 0, 0);
}

// C/D layout (m89): col = lane&15, row_local = (lane>>4)*4 + r
template <int ACT>
__device__ __forceinline__ void acc_to_t16_ct(const f32x4 acc[2], const float* bias,
                                              int lane, _Float16* tile, int ctb) {
    int col0 = lane & 15, r0 = (lane >> 4) * 4;
    #pragma unroll
    for (int c = 0; c < 2; ++c) {
        int cc = (ctb + c) * 16 + col0;
        float bs = bias ? bias[cc] : 0.f;
        #pragma unroll
        for (int r = 0; r < 4; ++r) {
            float o = acc[c][r] + bs;
            if (ACT) o = ssp(o);
            *t16(tile, r0 + r, cc * 2) = (_Float16)o;
        }
    }
}

// A-fragments (lane: row = lane&15, k = (lane>>4)*8 + j per ks) from fp16 tile
__device__ __forceinline__ void t16_to_af(_Float16* tile, int lane, f16x8 af[4]) {
    int row = lane & 15, kgB = (lane >> 4) * 16;
    #pragma unroll
    for (int ks = 0; ks < 4; ++ks)
        af[ks] = *(const f16x8*)t16(tile, row, ks * 64 + kgB);
}

// v(z) for 2 column-tiles in accumulator layout
__device__ __forceinline__ void vz_ct(const float* __restrict__ z,
                                      const float* __restrict__ iw,
                                      const float* __restrict__ ib,
                                      int rowbase, int lane, int n, int ctb,
                                      f32x4 vz[2]) {
    int col0 = lane & 15, r0 = (lane >> 4) * 4;
    float zr[4][3];
    #pragma unroll
    for (int r = 0; r < 4; ++r) {
        int row = min(rowbase + r0 + r, n - 1);
        zr[r][0] = z[row * 3 + 0];
        zr[r][1] = z[row * 3 + 1];
        zr[r][2] = z[row * 3 + 2];
    }
    #pragma unroll
    for (int c = 0; c < 2; ++c) {
        int cc = (ctb + c) * 16 + col0;
        float w0 = iw[cc], w1 = iw[HD + cc], w2 = iw[2 * HD + cc], bz = ib[cc];
        #pragma unroll
        for (int r = 0; r < 4; ++r)
            vz[c][r] = fmaf(zr[r][0], w0, fmaf(zr[r][1], w1, fmaf(zr[r][2], w2, bz)));
    }
}

// ---------------------------------------------------------------------------
// Wtab[layer][bin][h], grid (7 bins, 2 layers)
// ---------------------------------------------------------------------------
__global__ __launch_bounds__(HD) void k_wtab2(Ptr8 P, float* __restrict__ wtab) {
    const int bin = blockIdx.x, layer = blockIdx.y;
    const int t = threadIdx.x;
    const float* m0w = P.p[layer * 4 + 0];
    const float* m0b = P.p[layer * 4 + 1];
    const float* m2w = P.p[layer * 4 + 2];
    const float* m2b = P.p[layer * 4 + 3];
    __shared__ float hbuf[HD];

    const float spacing = CUTF / (GD - 1);
    const float coeff   = -0.5f / (spacing * spacing);

    float acc = m0b[t];
    #pragma unroll 5
    for (int g = 0; g < GD; ++g) {
        float d = (float)bin - (float)g * spacing;
        acc = fmaf(__expf(coeff * d * d), m0w[g * HD + t], acc);
    }
    hbuf[t] = ssp(acc);
    __syncthreads();

    float acc2 = m2b[t];
    #pragma unroll 8
    for (int k = 0; k < HD; ++k)
        acc2 = fmaf(hbuf[k], m2w[k * HD + t], acc2);
    wtab[(layer * 7 + bin) * HD + t] = acc2;
}

// ---------------------------------------------------------------------------
// Pack 7 [128,128] fp32 weights into fp16 MFMA B-fragment order (slots y=0..6,
// EXACTLY 2048 f16x8 frags each, grid x=8), and zero deg[] (slot y=7).
// ---------------------------------------------------------------------------
__global__ __launch_bounds__(256) void k_prepB7(Ptr8 P, _Float16* __restrict__ Bf,
                                                int* __restrict__ deg, int n) {
    int slot = blockIdx.y;
    int idx = blockIdx.x * 256 + threadIdx.x;   // 0..2047
    if (slot == 7) {
        for (int i = idx; i < n; i += 2048) deg[i] = 0;
        return;
    }
    if (idx >= 2048) return;
    const float* W = P.p[slot];
    int l  = idx & 63;
    int f  = idx >> 6;        // 0..31 = ct*4+ks
    int ks = f & 3, ct = f >> 2;
    int col = ct * 16 + (l & 15);
    int k0  = ks * 32 + ((l >> 4) << 3);
    f16x8 o;
    #pragma unroll
    for (int j = 0; j < 8; ++j) o[j] = (_Float16)W[(size_t)(k0 + j) * HD + col];
    ((f16x8*)(Bf + (size_t)slot * 16384))[idx] = o;
}

// ---------------------------------------------------------------------------
// CSR build
// ---------------------------------------------------------------------------
__global__ __launch_bounds__(256) void k_deg(const int* __restrict__ ei,
                                             int* __restrict__ deg, int nedges) {
    int e = blockIdx.x * 256 + threadIdx.x;
    if (e < nedges) atomicAdd(&deg[ei[nedges + e]], 1);
}

__global__ __launch_bounds__(1024) void k_scan1(const int* __restrict__ deg,
                                                int* __restrict__ rowstart,
                                                int* __restrict__ blocksum, int n) {
    __shared__ int wsum[16];
    int tid  = threadIdx.x;
    int lane = tid & 63, wid = tid >> 6;
    int i = blockIdx.x * 1024 + tid;
    int val = (i < n) ? deg[i] : 0;
    int x = val;
    #pragma unroll
    for (int off = 1; off < 64; off <<= 1) {
        int y = __shfl_up(x, off, 64);
        if (lane >= off) x += y;
    }
    if (lane == 63) wsum[wid] = x;
    __syncthreads();
    if (wid == 0) {
        int s = (lane < 16) ? wsum[lane] : 0;
        #pragma unroll
        for (int off = 1; off < 16; off <<= 1) {
            int y = __shfl_up(s, off, 64);
            if (lane >= off) s += y;
        }
        if (lane < 16) wsum[lane] = s;
    }
    __syncthreads();
    int wbase = (wid > 0) ? wsum[wid - 1] : 0;
    if (i <= n) rowstart[i] = wbase + x - val;
    if (tid == 1023) blocksum[blockIdx.x] = wsum[15];
}

__global__ __launch_bounds__(64) void k_scan2(int* __restrict__ blocksum, int nb) {
    int lane = threadIdx.x;
    int v = (lane < nb) ? blocksum[lane] : 0;
    int x = v;
    #pragma unroll
    for (int off = 1; off < 64; off <<= 1) {
        int y = __shfl_up(x, off, 64);
        if (lane >= off) x += y;
    }
    if (lane < nb) blocksum[lane] = x - v;
}

__global__ __launch_bounds__(1024) void k_scan3(int* __restrict__ rowstart,
                                                int* __restrict__ cursor,
                                                const int* __restrict__ blocksum,
                                                int n) {
    int i = blockIdx.x * 1024 + threadIdx.x;
    if (i <= n) {
        int rs = rowstart[i] + blocksum[blockIdx.x];
        rowstart[i] = rs;
        if (i < n) cursor[i] = rs;
    }
}

// ---------------------------------------------------------------------------
// Fused: escatter (4-edge ILP, blocks [0, escGrid)) + front (blocks after).
// front: vlin0_h = f16( (z@init_w + init_b) @ lin0 ), 16 rows/block.
// ---------------------------------------------------------------------------
__global__ __launch_bounds__(256) void k_fused_fe(const int* __restrict__ ei,
                                                  const float* __restrict__ dist,
                                                  int* __restrict__ cursor,
                                                  int2* __restrict__ ecomb,
                                                  int nedges, int escGrid,
                                                  const float* __restrict__ z,
                                                  const float* __restrict__ iw,
                                                  const float* __restrict__ ib,
                                                  const _Float16* __restrict__ BfL,
                                                  _Float16* __restrict__ vlin_h,
                                                  int n) {
    __shared__ __attribute__((aligned(16))) _Float16 tile16[2048];
    int bx = blockIdx.x;
    if (bx < escGrid) {
        // ---- edge scatter, 4 independent edges per thread ----
        int base = bx * 1024 + (int)threadIdx.x;
        #pragma unroll
        for (int k = 0; k < 4; ++k) {
            int e = base + k * 256;
            if (e < nedges) {
                int   j = ei[e];
                int   i = ei[nedges + e];
                float d = dist[e];
                int bin = min((int)d, 6);
                float Cg = 0.5f * (cosf(d * (PI_F / CUTF)) + 1.0f);
                int pos = atomicAdd(&cursor[i], 1);
                ecomb[pos] = make_int2(j | (bin << 25), __float_as_int(Cg));
            }
        }
        return;
    }
    // ---- front: 16 rows, 4 waves x 2 column-tiles ----
    int tid = threadIdx.x, lane = tid & 63, wid = tid >> 6;
    int rowbase = (bx - escGrid) * 16;
    int arow = min(rowbase + (lane & 15), n - 1);
    float z0 = z[arow * 3 + 0], z1 = z[arow * 3 + 1], z2 = z[arow * 3 + 2];
    int kg = (lane >> 4) * 8;

    f16x8 af[4];
    #pragma unroll
    for (int ks = 0; ks < 4; ++ks) {
        f16x8 h;
        #pragma unroll
        for (int j = 0; j < 8; ++j) {
            int c = ks * 32 + kg + j;
            h[j] = (_Float16)fmaf(z0, iw[c], fmaf(z1, iw[HD + c], fmaf(z2, iw[2 * HD + c], ib[c])));
        }
        af[ks] = h;
    }

    f32x4 acc[2];
    acc[0] = (f32x4){0.f, 0.f, 0.f, 0.f};
    acc[1] = (f32x4){0.f, 0.f, 0.f, 0.f};
    mfma_ct(af, BfL, lane, acc, wid * 2);
    acc_to_t16_ct<0>(acc, nullptr, lane, tile16, wid * 2);
    __syncthreads();
    int row = tid >> 4, g8 = tid & 15;
    if (rowbase + row < n)
        ((f16x8*)vlin_h)[(size_t)(rowbase + row) * 16 + g8] =
            *(const f16x8*)t16(tile16, row, g8 * 16);
}

// ---------------------------------------------------------------------------
// agg_h[node] = fp16( sum_e vlin_h[j_e] * Wtab[bin_e] * Cg_e )  (fp32 acc)
// ---------------------------------------------------------------------------
__global__ __launch_bounds__(256) void k_agg(const int* __restrict__ rowstart,
                                             const int2* __restrict__ ecomb,
                                             const _Float16* __restrict__ vlin_h,
                                             const float* __restrict__ wtab,
                                             _Float16* __restrict__ agg_h, int n) {
    __shared__ float lwt[7 * HD];
    int tid = threadIdx.x;
    if (tid < 224) ((float4*)lwt)[tid] = ((const float4*)wtab)[tid];
    __syncthreads();

    int node = blockIdx.x * 4 + (tid >> 6);
    if (node >= n) return;
    int lane = tid & 63;
    int beg = rowstart[node], end = rowstart[node + 1];

    float accx = 0.f, accy = 0.f;
    const float* lwt2 = lwt + 2 * lane;
    int e = beg;
    for (; e + 3 < end; e += 4) {
        int2 c0 = ecomb[e],     c1 = ecomb[e + 1];
        int2 c2 = ecomb[e + 2], c3 = ecomb[e + 3];
        f16x2 h0 = *(const f16x2*)(vlin_h + (size_t)(c0.x & 0x01FFFFFF) * HD + 2 * lane);
        f16x2 h1 = *(const f16x2*)(vlin_h + (size_t)(c1.x & 0x01FFFFFF) * HD + 2 * lane);
        f16x2 h2 = *(const f16x2*)(vlin_h + (size_t)(c2.x & 0x01FFFFFF) * HD + 2 * lane);
        f16x2 h3 = *(const f16x2*)(vlin_h + (size_t)(c3.x & 0x01FFFFFF) * HD + 2 * lane);
        float2 w0 = *(const float2*)(lwt2 + (c0.x >> 25) * HD);
        float2 w1 = *(const float2*)(lwt2 + (c1.x >> 25) * HD);
        float2 w2 = *(const float2*)(lwt2 + (c2.x >> 25) * HD);
        float2 w3 = *(const float2*)(lwt2 + (c3.x >> 25) * HD);
        float g0 = __int_as_float(c0.y), g1 = __int_as_float(c1.y);
        float g2 = __int_as_float(c2.y), g3 = __int_as_float(c3.y);
        accx = fmaf((float)h0[0], w0.x * g0, accx);
        accy = fmaf((float)h0[1], w0.y * g0, accy);
        accx = fmaf((float)h1[0], w1.x * g1, accx);
        accy = fmaf((float)h1[1], w1.y * g1, accy);
        accx = fmaf((float)h2[0], w2.x * g2, accx);
        accy = fmaf((float)h2[1], w2.y * g2, accy);
        accx = fmaf((float)h3[0], w3.x * g3, accx);
        accy = fmaf((float)h3[1], w3.y * g3, accy);
    }
    for (; e < end; ++e) {
        int2 c0 = ecomb[e];
        f16x2 h0 = *(const f16x2*)(vlin_h + (size_t)(c0.x & 0x01FFFFFF) * HD + 2 * lane);
        float2 w0 = *(const float2*)(lwt2 + (c0.x >> 25) * HD);
        float g0 = __int_as_float(c0.y);
        accx = fmaf((float)h0[0], w0.x * g0, accx);
        accy = fmaf((float)h0[1], w0.y * g0, accy);
    }
    f16x2 o; o[0] = (_Float16)accx; o[1] = (_Float16)accy;
    *(f16x2*)(agg_h + (size_t)node * HD + 2 * lane) = o;
}

// ---------------------------------------------------------------------------
// k_mid: 16 rows/block, 4 waves x 2 ct. tmp=ssp(agg@l1+b1);
// vnew = v(z) + tmp@l2 + b2 -> vres (acc layout); vlin_h = f16(vnew@lin1)
// ---------------------------------------------------------------------------
__global__ __launch_bounds__(256) void k_mid(const _Float16* __restrict__ agg_h,
                                             const _Float16* __restrict__ Bf1,
                                             const float* __restrict__ b1,
                                             const _Float16* __restrict__ Bf2,
                                             const float* __restrict__ b2,
                                             const _Float16* __restrict__ BfL,
                                             const float* __restrict__ z,
                                             const float* __restrict__ iw,
                                             const float* __restrict__ ib,
                                             f32x4* __restrict__ vres4,
                                             _Float16* __restrict__ vlin_h, int n) {
    __shared__ __attribute__((aligned(16))) _Float16 tile16[2048];
    int tid = threadIdx.x, lane = tid & 63, wid = tid >> 6;
    int rowbase = blockIdx.x * 16;
    int ctb = wid * 2;

    int arow = min(rowbase + (lane & 15), n - 1);
    int kg = (lane >> 4) * 8;
    f16x8 af[4];
    #pragma unroll
    for (int ks = 0; ks < 4; ++ks)
        af[ks] = *(const f16x8*)(agg_h + (size_t)arow * HD + ks * 32 + kg);

    f32x4 acc[2];
    acc[0] = (f32x4){0.f, 0.f, 0.f, 0.f};
    acc[1] = (f32x4){0.f, 0.f, 0.f, 0.f};
    mfma_ct(af, Bf1, lane, acc, ctb);
    acc_to_t16_ct<1>(acc, b1, lane, tile16, ctb);     // tmp cols
    __syncthreads();                                  // tmp complete
    t16_to_af(tile16, lane, af);
    __syncthreads();                                  // all reads done

    acc[0] = (f32x4){0.f, 0.f, 0.f, 0.f};
    acc[1] = (f32x4){0.f, 0.f, 0.f, 0.f};
    mfma_ct(af, Bf2, lane, acc, ctb);

    f32x4 vz[2];
    vz_ct(z, iw, ib, rowbase, lane, n, ctb, vz);
    int col0 = lane & 15;
    #pragma unroll
    for (int c = 0; c < 2; ++c) {
        float bs = b2[(ctb + c) * 16 + col0];
        #pragma unroll
        for (int r = 0; r < 4; ++r) acc[c][r] += bs + vz[c][r];
        vres4[((size_t)blockIdx.x * 8 + ctb + c) * 64 + lane] = acc[c];
    }

    acc_to_t16_ct<0>(acc, nullptr, lane, tile16, ctb);  // vnew cols
    __syncthreads();                                    // vnew complete
    t16_to_af(tile16, lane, af);
    __syncthreads();                                    // reads done

    acc[0] = (f32x4){0.f, 0.f, 0.f, 0.f};
    acc[1] = (f32x4){0.f, 0.f, 0.f, 0.f};
    mfma_ct(af, BfL, lane, acc, ctb);
    acc_to_t16_ct<0>(acc, nullptr, lane, tile16, ctb);
    __syncthreads();                                    // vlin tile complete
    int row = tid >> 4, g8 = tid & 15;
    if (rowbase + row < n)
        ((f16x8*)vlin_h)[(size_t)(rowbase + row) * 16 + g8] =
            *(const f16x8*)t16(tile16, row, g8 * 16);
}

// ---------------------------------------------------------------------------
// k_back: 16 rows/block. tmp=ssp(agg@l1+b1); vnew = vres + tmp@l2 + b2;
// u = ssp(vnew@u1+ub1); out = u @ u_l2[128,3] + ub2 (shfl + LDS reduce)
// ---------------------------------------------------------------------------
__global__ __launch_bounds__(256) void k_back(const _Float16* __restrict__ agg_h,
                                              const _Float16* __restrict__ Bf1,
                                              const float* __restrict__ b1,
                                              const _Float16* __restrict__ Bf2,
                                              const float* __restrict__ b2,
                                              const _Float16* __restrict__ BfU,
                                              const float* __restrict__ ub1,
                                              const float* __restrict__ w2,
                                              const float* __restrict__ ub2,
                                              const f32x4* __restrict__ vres4,
                                              float* __restrict__ out, int n) {
    __shared__ __attribute__((aligned(16))) _Float16 tile16[2048];
    __shared__ float red[4][16][3];
    int tid = threadIdx.x, lane = tid & 63, wid = tid >> 6;
    int rowbase = blockIdx.x * 16;
    int ctb = wid * 2;

    int arow = min(rowbase + (lane & 15), n - 1);
    int kg = (lane >> 4) * 8;
    f16x8 af[4];
    #pragma unroll
    for (int ks = 0; ks < 4; ++ks)
        af[ks] = *(const f16x8*)(agg_h + (size_t)arow * HD + ks * 32 + kg);

    f32x4 acc[2];
    acc[0] = (f32x4){0.f, 0.f, 0.f, 0.f};
    acc[1] = (f32x4){0.f, 0.f, 0.f, 0.f};
    mfma_ct(af, Bf1, lane, acc, ctb);
    acc_to_t16_ct<1>(acc, b1, lane, tile16, ctb);
    __syncthreads();
    t16_to_af(tile16, lane, af);
    __syncthreads();

    acc[0] = (f32x4){0.f, 0.f, 0.f, 0.f};
    acc[1] = (f32x4){0.f, 0.f, 0.f, 0.f};
    mfma_ct(af, Bf2, lane, acc, ctb);

    int col0 = lane & 15;
    #pragma unroll
    for (int c = 0; c < 2; ++c) {
        float bs = b2[(ctb + c) * 16 + col0];
        f32x4 rv = vres4[((size_t)blockIdx.x * 8 + ctb + c) * 64 + lane];
        #pragma unroll
        for (int r = 0; r < 4; ++r) acc[c][r] += bs + rv[r];
    }

    acc_to_t16_ct<0>(acc, nullptr, lane, tile16, ctb);
    __syncthreads();
    t16_to_af(tile16, lane, af);
    // tile is not written again — no further barrier needed before MFMA

    acc[0] = (f32x4){0.f, 0.f, 0.f, 0.f};
    acc[1] = (f32x4){0.f, 0.f, 0.f, 0.f};
    mfma_ct(af, BfU, lane, acc, ctb);

    // readout partials over this wave's 32 cols
    int r0 = (lane >> 4) * 4;
    float p0[4] = {0.f, 0.f, 0.f, 0.f};
    float p1[4] = {0.f, 0.f, 0.f, 0.f};
    float p2[4] = {0.f, 0.f, 0.f, 0.f};
    #pragma unroll
    for (int c = 0; c < 2; ++c) {
        int cc = (ctb + c) * 16 + col0;
        float bu = ub1[cc];
        float w20 = w2[cc * 3 + 0], w21 = w2[cc * 3 + 1], w22 = w2[cc * 3 + 2];
        #pragma unroll
        for (int r = 0; r < 4; ++r) {
            float u = ssp(acc[c][r] + bu);
            p0[r] = fmaf(u, w20, p0[r]);
            p1[r] = fmaf(u, w21, p1[r]);
            p2[r] = fmaf(u, w22, p2[r]);
        }
    }
    #pragma unroll
    for (int m = 1; m < 16; m <<= 1) {
        #pragma unroll
        for (int r = 0; r < 4; ++r) {
            p0[r] += __shfl_xor(p0[r], m, 64);
            p1[r] += __shfl_xor(p1[r], m, 64);
            p2[r] += __shfl_xor(p2[r], m, 64);
        }
    }
    if (col0 == 0) {
        #pragma unroll
        for (int r = 0; r < 4; ++r) {
            red[wid][r0 + r][0] = p0[r];
            red[wid][r0 + r][1] = p1[r];
            red[wid][r0 + r][2] = p2[r];
        }
    }
    __syncthreads();
    if (tid < 48) {
        int row = tid / 3, c = tid % 3;
        float s = red[0][row][c] + red[1][row][c] + red[2][row][c] + red[3][row][c];
        if (rowbase + row < n)
            out[(size_t)(rowbase + row) * 3 + c] = s + ub2[c];
    }
}

// ---------------------------------------------------------------------------
extern "C" void kernel_launch(void* const* d_in, const int* in_sizes, int n_in,
                              void* d_out, int out_size, void* d_ws, size_t ws_size,
                              hipStream_t stream) {
    const float* z      = (const float*)d_in[0];
    const float* dist   = (const float*)d_in[1];
    const int*   ei     = (const int*)d_in[2];
    const float* init_w = (const float*)d_in[3];
    const float* init_b = (const float*)d_in[4];

    const float* L[2][9];
    for (int l = 0; l < 2; ++l)
        for (int p = 0; p < 9; ++p)
            L[l][p] = (const float*)d_in[5 + l * 9 + p];

    const float* u_l1_w = (const float*)d_in[23];
    const float* u_l1_b = (const float*)d_in[24];
    const float* u_l2_w = (const float*)d_in[25];
    const float* u_l2_b = (const float*)d_in[26];
    float* out = (float*)d_out;

    const int N = in_sizes[0] / 3;
    const int E = in_sizes[1];

    const int nb16     = (N + 15) / 16;           // 16-row blocks
    const int escGrid  = (E + 1023) / 1024;       // 4 edges/thread
    const int edgeGrid = (E + 255) / 256;
    const int scanB    = (N + 1 + 1023) / 1024;
    const int aggGrid  = (N + 3) / 4;

    // workspace layout (float units)
    float* wtab   = (float*)d_ws;                     // 2048
    float* bf     = wtab + 2048;                      // 57344
    float* vres   = bf + 57344;                       // nb16*2048 (acc layout)
    float* vh     = vres + (size_t)nb16 * 2048;       // N*64
    float* aggh   = vh + (size_t)N * 64;              // N*64
    int2*  ecomb  = (int2*)(aggh + (size_t)N * 64);   // E int2
    int*   deg    = (int*)(ecomb + E);                // N
    int*   rowstart = deg + N;                        // N+1
    int*   cursor = rowstart + N + 1;                 // N
    int*   blocksum = cursor + N;                     // 64

    _Float16* vlin_h = (_Float16*)vh;
    _Float16* agg_h  = (_Float16*)aggh;
    f32x4*    vres4  = (f32x4*)vres;
    _Float16* Bf     = (_Float16*)bf;
    _Float16* BfW[7];
    for (int i = 0; i < 7; ++i) BfW[i] = Bf + (size_t)i * 16384;

    Ptr8 wt; wt.p[0] = L[0][1]; wt.p[1] = L[0][2]; wt.p[2] = L[0][3]; wt.p[3] = L[0][4];
             wt.p[4] = L[1][1]; wt.p[5] = L[1][2]; wt.p[6] = L[1][3]; wt.p[7] = L[1][4];
    k_wtab2<<<dim3(7, 2), HD, 0, stream>>>(wt, wtab);

    Ptr8 pb; pb.p[0] = L[0][0]; pb.p[1] = L[0][5]; pb.p[2] = L[0][7];
             pb.p[3] = L[1][0]; pb.p[4] = L[1][5]; pb.p[5] = L[1][7];
             pb.p[6] = u_l1_w;  pb.p[7] = u_l1_w;
    k_prepB7<<<dim3(8, 8), 256, 0, stream>>>(pb, Bf, deg, N);  // pack + zero deg

    // CSR build
    k_deg<<<edgeGrid, 256, 0, stream>>>(ei, deg, E);
    k_scan1<<<scanB, 1024, 0, stream>>>(deg, rowstart, blocksum, N);
    k_scan2<<<1, 64, 0, stream>>>(blocksum, scanB);
    k_scan3<<<scanB, 1024, 0, stream>>>(rowstart, cursor, blocksum, N);

    // escatter (long pole, blocks first) fused with layer-0 front
    k_fused_fe<<<escGrid + nb16, 256, 0, stream>>>(ei, dist, cursor, ecomb, E, escGrid,
                                                   z, init_w, init_b, BfW[0], vlin_h, N);

    k_agg<<<aggGrid, 256, 0, stream>>>(rowstart, ecomb, vlin_h, wtab, agg_h, N);
    k_mid<<<nb16, 256, 0, stream>>>(agg_h, BfW[1], L[0][6], BfW[2], L[0][8],
                                    BfW[3], z, init_w, init_b, vres4, vlin_h, N);
    k_agg<<<aggGrid, 256, 0, stream>>>(rowstart, ecomb, vlin_h, wtab + 7 * HD, agg_h, N);
    k_back<<<nb16, 256, 0, stream>>>(agg_h, BfW[4], L[1][6], BfW[5], L[1][8],
                                     BfW[6], u_l1_b, u_l2_w, u_l2_b, vres4, out, N);
}

// Round 11
// 350.347 us; speedup vs baseline: 8.9926x; 1.0173x over previous
//
#include <hip/hip_runtime.h>
#include <cstdint>
#include <cstddef>

#define HD 128              // hidden channels
#define GD 50               // gaussians
static constexpr float PI_F   = 3.14159265358979323846f;
static constexpr float CUTF   = 6.0f;
static constexpr float SHIFTF = 0.69314718055994530942f; // ln(2)

typedef _Float16 f16x8 __attribute__((ext_vector_type(8)));
typedef _Float16 f16x2 __attribute__((ext_vector_type(2)));
typedef float    f32x4 __attribute__((ext_vector_type(4)));

struct Ptr8 { const float* p[8]; };

// fast ShiftedSoftplus: native v_exp_f32 / v_log_f32
__device__ __forceinline__ float ssp(float x) {
    float e = __expf(-fabsf(x));
    return fmaxf(x, 0.0f) + __logf(1.0f + e) - SHIFTF;
}

// ---------------------------------------------------------------------------
// Swizzled fp16 LDS tile (16 rows x 128 cols, 256 B/row), XOR G4 fix.
// ---------------------------------------------------------------------------
__device__ __forceinline__ _Float16* t16(_Float16* base, int row, int byte) {
    return (_Float16*)((char*)base + row * 256 + (byte ^ ((row & 7) << 4)));
}

// 8 MFMAs covering 2 column-tiles (ctb, ctb+1) x 4 k-slices
__device__ __forceinline__ void mfma_ct(const f16x8 af[4],
                                        const _Float16* __restrict__ Bf,
                                        int lane, f32x4 acc[2], int ctb) {
    #pragma unroll
    for (int ks = 0; ks < 4; ++ks)
        #pragma unroll
        for (int c = 0; c < 2; ++c)
            acc[c] = __builtin_amdgcn_mfma_f32_16x16x32_f16(
                af[ks], ((const f16x8*)Bf)[((ctb + c) * 4 + ks) * 64 + lane],
                acc[c], 0, 0, 0);
}

// C/D layout (m89): col = lane&15, row_local = (lane>>4)*4 + r
template <int ACT>
__device__ __forceinline__ void acc_to_t16_ct(const f32x4 acc[2], const float* bias,
                                              int lane, _Float16* tile, int ctb) {
    int col0 = lane & 15, r0 = (lane >> 4) * 4;
    #pragma unroll
    for (int c = 0; c < 2; ++c) {
        int cc = (ctb + c) * 16 + col0;
        float bs = bias ? bias[cc] : 0.f;
        #pragma unroll
        for (int r = 0; r < 4; ++r) {
            float o = acc[c][r] + bs;
            if (ACT) o = ssp(o);
            *t16(tile, r0 + r, cc * 2) = (_Float16)o;
        }
    }
}

// A-fragments (lane: row = lane&15, k = (lane>>4)*8 + j per ks) from fp16 tile
__device__ __forceinline__ void t16_to_af(_Float16* tile, int lane, f16x8 af[4]) {
    int row = lane & 15, kgB = (lane >> 4) * 16;
    #pragma unroll
    for (int ks = 0; ks < 4; ++ks)
        af[ks] = *(const f16x8*)t16(tile, row, ks * 64 + kgB);
}

// v(z) for 2 column-tiles in accumulator layout
__device__ __forceinline__ void vz_ct(const float* __restrict__ z,
                                      const float* __restrict__ iw,
                                      const float* __restrict__ ib,
                                      int rowbase, int lane, int n, int ctb,
                                      f32x4 vz[2]) {
    int col0 = lane & 15, r0 = (lane >> 4) * 4;
    float zr[4][3];
    #pragma unroll
    for (int r = 0; r < 4; ++r) {
        int row = min(rowbase + r0 + r, n - 1);
        zr[r][0] = z[row * 3 + 0];
        zr[r][1] = z[row * 3 + 1];
        zr[r][2] = z[row * 3 + 2];
    }
    #pragma unroll
    for (int c = 0; c < 2; ++c) {
        int cc = (ctb + c) * 16 + col0;
        float w0 = iw[cc], w1 = iw[HD + cc], w2 = iw[2 * HD + cc], bz = ib[cc];
        #pragma unroll
        for (int r = 0; r < 4; ++r)
            vz[c][r] = fmaf(zr[r][0], w0, fmaf(zr[r][1], w1, fmaf(zr[r][2], w2, bz)));
    }
}

// ---------------------------------------------------------------------------
// Wtab[layer][bin][h], grid (7 bins, 2 layers)
// ---------------------------------------------------------------------------
__global__ __launch_bounds__(HD) void k_wtab2(Ptr8 P, float* __restrict__ wtab) {
    const int bin = blockIdx.x, layer = blockIdx.y;
    const int t = threadIdx.x;
    const float* m0w = P.p[layer * 4 + 0];
    const float* m0b = P.p[layer * 4 + 1];
    const float* m2w = P.p[layer * 4 + 2];
    const float* m2b = P.p[layer * 4 + 3];
    __shared__ float hbuf[HD];

    const float spacing = CUTF / (GD - 1);
    const float coeff   = -0.5f / (spacing * spacing);

    float acc = m0b[t];
    #pragma unroll 5
    for (int g = 0; g < GD; ++g) {
        float d = (float)bin - (float)g * spacing;
        acc = fmaf(__expf(coeff * d * d), m0w[g * HD + t], acc);
    }
    hbuf[t] = ssp(acc);
    __syncthreads();

    float acc2 = m2b[t];
    #pragma unroll 8
    for (int k = 0; k < HD; ++k)
        acc2 = fmaf(hbuf[k], m2w[k * HD + t], acc2);
    wtab[(layer * 7 + bin) * HD + t] = acc2;
}

// ---------------------------------------------------------------------------
// Pack 7 [128,128] fp32 weights into fp16 MFMA B-fragment order (slots y=0..6,
// EXACTLY 2048 f16x8 frags each, grid x=8), and zero deg[] (slot y=7).
// ---------------------------------------------------------------------------
__global__ __launch_bounds__(256) void k_prepB7(Ptr8 P, _Float16* __restrict__ Bf,
                                                int* __restrict__ deg, int n) {
    int slot = blockIdx.y;
    int idx = blockIdx.x * 256 + threadIdx.x;   // 0..2047
    if (slot == 7) {
        for (int i = idx; i < n; i += 2048) deg[i] = 0;
        return;
    }
    if (idx >= 2048) return;
    const float* W = P.p[slot];
    int l  = idx & 63;
    int f  = idx >> 6;        // 0..31 = ct*4+ks
    int ks = f & 3, ct = f >> 2;
    int col = ct * 16 + (l & 15);
    int k0  = ks * 32 + ((l >> 4) << 3);
    f16x8 o;
    #pragma unroll
    for (int j = 0; j < 8; ++j) o[j] = (_Float16)W[(size_t)(k0 + j) * HD + col];
    ((f16x8*)(Bf + (size_t)slot * 16384))[idx] = o;
}

// ---------------------------------------------------------------------------
// CSR build
// ---------------------------------------------------------------------------
__global__ __launch_bounds__(256) void k_deg(const int* __restrict__ ei,
                                             int* __restrict__ deg, int nedges) {
    int e = blockIdx.x * 256 + threadIdx.x;
    if (e < nedges) atomicAdd(&deg[ei[nedges + e]], 1);
}

__global__ __launch_bounds__(1024) void k_scan1(const int* __restrict__ deg,
                                                int* __restrict__ rowstart,
                                                int* __restrict__ blocksum, int n) {
    __shared__ int wsum[16];
    int tid  = threadIdx.x;
    int lane = tid & 63, wid = tid >> 6;
    int i = blockIdx.x * 1024 + tid;
    int val = (i < n) ? deg[i] : 0;
    int x = val;
    #pragma unroll
    for (int off = 1; off < 64; off <<= 1) {
        int y = __shfl_up(x, off, 64);
        if (lane >= off) x += y;
    }
    if (lane == 63) wsum[wid] = x;
    __syncthreads();
    if (wid == 0) {
        int s = (lane < 16) ? wsum[lane] : 0;
        #pragma unroll
        for (int off = 1; off < 16; off <<= 1) {
            int y = __shfl_up(s, off, 64);
            if (lane >= off) s += y;
        }
        if (lane < 16) wsum[lane] = s;
    }
    __syncthreads();
    int wbase = (wid > 0) ? wsum[wid - 1] : 0;
    if (i <= n) rowstart[i] = wbase + x - val;
    if (tid == 1023) blocksum[blockIdx.x] = wsum[15];
}

__global__ __launch_bounds__(64) void k_scan2(int* __restrict__ blocksum, int nb) {
    int lane = threadIdx.x;
    int v = (lane < nb) ? blocksum[lane] : 0;
    int x = v;
    #pragma unroll
    for (int off = 1; off < 64; off <<= 1) {
        int y = __shfl_up(x, off, 64);
        if (lane >= off) x += y;
    }
    if (lane < nb) blocksum[lane] = x - v;
}

__global__ __launch_bounds__(1024) void k_scan3(int* __restrict__ rowstart,
                                                int* __restrict__ cursor,
                                                const int* __restrict__ blocksum,
                                                int n) {
    int i = blockIdx.x * 1024 + threadIdx.x;
    if (i <= n) {
        int rs = rowstart[i] + blocksum[blockIdx.x];
        rowstart[i] = rs;
        if (i < n) cursor[i] = rs;
    }
}

// ---------------------------------------------------------------------------
// k_epos: pos[e] = atomicAdd(cursor[dest], 1).  8 edges/thread; all 8 atomics
// issued before any dependent use -> 8 in flight. pos written coalesced.
// ---------------------------------------------------------------------------
__global__ __launch_bounds__(256) void k_epos(const int* __restrict__ ei,
                                              int* __restrict__ cursor,
                                              int* __restrict__ pos,
                                              int nedges) {
    int base = blockIdx.x * 2048 + threadIdx.x;
    int p[8];
    #pragma unroll
    for (int k = 0; k < 8; ++k) {
        int e = base + k * 256;
        if (e < nedges) p[k] = atomicAdd(&cursor[ei[nedges + e]], 1);
    }
    #pragma unroll
    for (int k = 0; k < 8; ++k) {
        int e = base + k * 256;
        if (e < nedges) pos[e] = p[k];
    }
}

// ---------------------------------------------------------------------------
// k_ewrite: ecomb[pos[e]] = {j|bin<<25, Cg}.  No atomics; 8 independent
// fire-and-forget random stores per thread.
// ---------------------------------------------------------------------------
__global__ __launch_bounds__(256) void k_ewrite(const int* __restrict__ ei,
                                                const float* __restrict__ dist,
                                                const int* __restrict__ pos,
                                                int2* __restrict__ ecomb,
                                                int nedges) {
    int base = blockIdx.x * 2048 + threadIdx.x;
    #pragma unroll
    for (int k = 0; k < 8; ++k) {
        int e = base + k * 256;
        if (e < nedges) {
            int   j = ei[e];
            float d = dist[e];
            int bin = min((int)d, 6);
            float Cg = 0.5f * (cosf(d * (PI_F / CUTF)) + 1.0f);
            ecomb[pos[e]] = make_int2(j | (bin << 25), __float_as_int(Cg));
        }
    }
}

// ---------------------------------------------------------------------------
// k_front: vlin0_h = f16( (z@init_w + init_b) @ lin0 ), 16 rows/block.
// ---------------------------------------------------------------------------
__global__ __launch_bounds__(256) void k_front(const float* __restrict__ z,
                                               const float* __restrict__ iw,
                                               const float* __restrict__ ib,
                                               const _Float16* __restrict__ BfL,
                                               _Float16* __restrict__ vlin_h, int n) {
    __shared__ __attribute__((aligned(16))) _Float16 tile16[2048];
    int tid = threadIdx.x, lane = tid & 63, wid = tid >> 6;
    int rowbase = blockIdx.x * 16;
    int arow = min(rowbase + (lane & 15), n - 1);
    float z0 = z[arow * 3 + 0], z1 = z[arow * 3 + 1], z2 = z[arow * 3 + 2];
    int kg = (lane >> 4) * 8;

    f16x8 af[4];
    #pragma unroll
    for (int ks = 0; ks < 4; ++ks) {
        f16x8 h;
        #pragma unroll
        for (int j = 0; j < 8; ++j) {
            int c = ks * 32 + kg + j;
            h[j] = (_Float16)fmaf(z0, iw[c], fmaf(z1, iw[HD + c], fmaf(z2, iw[2 * HD + c], ib[c])));
        }
        af[ks] = h;
    }

    f32x4 acc[2];
    acc[0] = (f32x4){0.f, 0.f, 0.f, 0.f};
    acc[1] = (f32x4){0.f, 0.f, 0.f, 0.f};
    mfma_ct(af, BfL, lane, acc, wid * 2);
    acc_to_t16_ct<0>(acc, nullptr, lane, tile16, wid * 2);
    __syncthreads();
    int row = tid >> 4, g8 = tid & 15;
    if (rowbase + row < n)
        ((f16x8*)vlin_h)[(size_t)(rowbase + row) * 16 + g8] =
            *(const f16x8*)t16(tile16, row, g8 * 16);
}

// ---------------------------------------------------------------------------
// agg_h[node] = fp16( sum_e vlin_h[j_e] * Wtab[bin_e] * Cg_e )  (fp32 acc)
// One wave per node, 2 ch/lane, 8-edge unroll for gather ILP.
// ---------------------------------------------------------------------------
__global__ __launch_bounds__(256) void k_agg(const int* __restrict__ rowstart,
                                             const int2* __restrict__ ecomb,
                                             const _Float16* __restrict__ vlin_h,
                                             const float* __restrict__ wtab,
                                             _Float16* __restrict__ agg_h, int n) {
    __shared__ float lwt[7 * HD];
    int tid = threadIdx.x;
    if (tid < 224) ((float4*)lwt)[tid] = ((const float4*)wtab)[tid];
    __syncthreads();

    int node = blockIdx.x * 4 + (tid >> 6);
    if (node >= n) return;
    int lane = tid & 63;
    int beg = rowstart[node], end = rowstart[node + 1];

    float accx = 0.f, accy = 0.f;
    const float* lwt2 = lwt + 2 * lane;
    int e = beg;
    for (; e + 7 < end; e += 8) {
        int2 cc[8];
        #pragma unroll
        for (int k = 0; k < 8; ++k) cc[k] = ecomb[e + k];
        f16x2 hh[8];
        #pragma unroll
        for (int k = 0; k < 8; ++k)
            hh[k] = *(const f16x2*)(vlin_h + (size_t)(cc[k].x & 0x01FFFFFF) * HD + 2 * lane);
        float2 ww[8];
        #pragma unroll
        for (int k = 0; k < 8; ++k)
            ww[k] = *(const float2*)(lwt2 + (cc[k].x >> 25) * HD);
        #pragma unroll
        for (int k = 0; k < 8; ++k) {
            float g = __int_as_float(cc[k].y);
            accx = fmaf((float)hh[k][0], ww[k].x * g, accx);
            accy = fmaf((float)hh[k][1], ww[k].y * g, accy);
        }
    }
    for (; e + 3 < end; e += 4) {
        int2 cc[4];
        #pragma unroll
        for (int k = 0; k < 4; ++k) cc[k] = ecomb[e + k];
        #pragma unroll
        for (int k = 0; k < 4; ++k) {
            f16x2 h = *(const f16x2*)(vlin_h + (size_t)(cc[k].x & 0x01FFFFFF) * HD + 2 * lane);
            float2 w = *(const float2*)(lwt2 + (cc[k].x >> 25) * HD);
            float g = __int_as_float(cc[k].y);
            accx = fmaf((float)h[0], w.x * g, accx);
            accy = fmaf((float)h[1], w.y * g, accy);
        }
    }
    for (; e < end; ++e) {
        int2 c0 = ecomb[e];
        f16x2 h0 = *(const f16x2*)(vlin_h + (size_t)(c0.x & 0x01FFFFFF) * HD + 2 * lane);
        float2 w0 = *(const float2*)(lwt2 + (c0.x >> 25) * HD);
        float g0 = __int_as_float(c0.y);
        accx = fmaf((float)h0[0], w0.x * g0, accx);
        accy = fmaf((float)h0[1], w0.y * g0, accy);
    }
    f16x2 o; o[0] = (_Float16)accx; o[1] = (_Float16)accy;
    *(f16x2*)(agg_h + (size_t)node * HD + 2 * lane) = o;
}

// ---------------------------------------------------------------------------
// k_mid: 16 rows/block, 4 waves x 2 ct. tmp=ssp(agg@l1+b1);
// vnew = v(z) + tmp@l2 + b2 -> vres (acc layout); vlin_h = f16(vnew@lin1)
// ---------------------------------------------------------------------------
__global__ __launch_bounds__(256) void k_mid(const _Float16* __restrict__ agg_h,
                                             const _Float16* __restrict__ Bf1,
                                             const float* __restrict__ b1,
                                             const _Float16* __restrict__ Bf2,
                                             const float* __restrict__ b2,
                                             const _Float16* __restrict__ BfL,
                                             const float* __restrict__ z,
                                             const float* __restrict__ iw,
                                             const float* __restrict__ ib,
                                             f32x4* __restrict__ vres4,
                                             _Float16* __restrict__ vlin_h, int n) {
    __shared__ __attribute__((aligned(16))) _Float16 tile16[2048];
    int tid = threadIdx.x, lane = tid & 63, wid = tid >> 6;
    int rowbase = blockIdx.x * 16;
    int ctb = wid * 2;

    int arow = min(rowbase + (lane & 15), n - 1);
    int kg = (lane >> 4) * 8;
    f16x8 af[4];
    #pragma unroll
    for (int ks = 0; ks < 4; ++ks)
        af[ks] = *(const f16x8*)(agg_h + (size_t)arow * HD + ks * 32 + kg);

    f32x4 acc[2];
    acc[0] = (f32x4){0.f, 0.f, 0.f, 0.f};
    acc[1] = (f32x4){0.f, 0.f, 0.f, 0.f};
    mfma_ct(af, Bf1, lane, acc, ctb);
    acc_to_t16_ct<1>(acc, b1, lane, tile16, ctb);     // tmp cols
    __syncthreads();                                  // tmp complete
    t16_to_af(tile16, lane, af);
    __syncthreads();                                  // all reads done

    acc[0] = (f32x4){0.f, 0.f, 0.f, 0.f};
    acc[1] = (f32x4){0.f, 0.f, 0.f, 0.f};
    mfma_ct(af, Bf2, lane, acc, ctb);

    f32x4 vz[2];
    vz_ct(z, iw, ib, rowbase, lane, n, ctb, vz);
    int col0 = lane & 15;
    #pragma unroll
    for (int c = 0; c < 2; ++c) {
        float bs = b2[(ctb + c) * 16 + col0];
        #pragma unroll
        for (int r = 0; r < 4; ++r) acc[c][r] += bs + vz[c][r];
        vres4[((size_t)blockIdx.x * 8 + ctb + c) * 64 + lane] = acc[c];
    }

    acc_to_t16_ct<0>(acc, nullptr, lane, tile16, ctb);  // vnew cols
    __syncthreads();                                    // vnew complete
    t16_to_af(tile16, lane, af);
    __syncthreads();                                    // reads done

    acc[0] = (f32x4){0.f, 0.f, 0.f, 0.f};
    acc[1] = (f32x4){0.f, 0.f, 0.f, 0.f};
    mfma_ct(af, BfL, lane, acc, ctb);
    acc_to_t16_ct<0>(acc, nullptr, lane, tile16, ctb);
    __syncthreads();                                    // vlin tile complete
    int row = tid >> 4, g8 = tid & 15;
    if (rowbase + row < n)
        ((f16x8*)vlin_h)[(size_t)(rowbase + row) * 16 + g8] =
            *(const f16x8*)t16(tile16, row, g8 * 16);
}

// ---------------------------------------------------------------------------
// k_back: 16 rows/block. tmp=ssp(agg@l1+b1); vnew = vres + tmp@l2 + b2;
// u = ssp(vnew@u1+ub1); out = u @ u_l2[128,3] + ub2 (shfl + LDS reduce)
// ---------------------------------------------------------------------------
__global__ __launch_bounds__(256) void k_back(const _Float16* __restrict__ agg_h,
                                              const _Float16* __restrict__ Bf1,
                                              const float* __restrict__ b1,
                                              const _Float16* __restrict__ Bf2,
                                              const float* __restrict__ b2,
                                              const _Float16* __restrict__ BfU,
                                              const float* __restrict__ ub1,
                                              const float* __restrict__ w2,
                                              const float* __restrict__ ub2,
                                              const f32x4* __restrict__ vres4,
                                              float* __restrict__ out, int n) {
    __shared__ __attribute__((aligned(16))) _Float16 tile16[2048];
    __shared__ float red[4][16][3];
    int tid = threadIdx.x, lane = tid & 63, wid = tid >> 6;
    int rowbase = blockIdx.x * 16;
    int ctb = wid * 2;

    int arow = min(rowbase + (lane & 15), n - 1);
    int kg = (lane >> 4) * 8;
    f16x8 af[4];
    #pragma unroll
    for (int ks = 0; ks < 4; ++ks)
        af[ks] = *(const f16x8*)(agg_h + (size_t)arow * HD + ks * 32 + kg);

    f32x4 acc[2];
    acc[0] = (f32x4){0.f, 0.f, 0.f, 0.f};
    acc[1] = (f32x4){0.f, 0.f, 0.f, 0.f};
    mfma_ct(af, Bf1, lane, acc, ctb);
    acc_to_t16_ct<1>(acc, b1, lane, tile16, ctb);
    __syncthreads();
    t16_to_af(tile16, lane, af);
    __syncthreads();

    acc[0] = (f32x4){0.f, 0.f, 0.f, 0.f};
    acc[1] = (f32x4){0.f, 0.f, 0.f, 0.f};
    mfma_ct(af, Bf2, lane, acc, ctb);

    int col0 = lane & 15;
    #pragma unroll
    for (int c = 0; c < 2; ++c) {
        float bs = b2[(ctb + c) * 16 + col0];
        f32x4 rv = vres4[((size_t)blockIdx.x * 8 + ctb + c) * 64 + lane];
        #pragma unroll
        for (int r = 0; r < 4; ++r) acc[c][r] += bs + rv[r];
    }

    acc_to_t16_ct<0>(acc, nullptr, lane, tile16, ctb);
    __syncthreads();
    t16_to_af(tile16, lane, af);
    // tile is not written again — no further barrier needed before MFMA

    acc[0] = (f32x4){0.f, 0.f, 0.f, 0.f};
    acc[1] = (f32x4){0.f, 0.f, 0.f, 0.f};
    mfma_ct(af, BfU, lane, acc, ctb);

    // readout partials over this wave's 32 cols
    int r0 = (lane >> 4) * 4;
    float p0[4] = {0.f, 0.f, 0.f, 0.f};
    float p1[4] = {0.f, 0.f, 0.f, 0.f};
    float p2[4] = {0.f, 0.f, 0.f, 0.f};
    #pragma unroll
    for (int c = 0; c < 2; ++c) {
        int cc = (ctb + c) * 16 + col0;
        float bu = ub1[cc];
        float w20 = w2[cc * 3 + 0], w21 = w2[cc * 3 + 1], w22 = w2[cc * 3 + 2];
        #pragma unroll
        for (int r = 0; r < 4; ++r) {
            float u = ssp(acc[c][r] + bu);
            p0[r] = fmaf(u, w20, p0[r]);
            p1[r] = fmaf(u, w21, p1[r]);
            p2[r] = fmaf(u, w22, p2[r]);
        }
    }
    #pragma unroll
    for (int m = 1; m < 16; m <<= 1) {
        #pragma unroll
        for (int r = 0; r < 4; ++r) {
            p0[r] += __shfl_xor(p0[r], m, 64);
            p1[r] += __shfl_xor(p1[r], m, 64);
            p2[r] += __shfl_xor(p2[r], m, 64);
        }
    }
    if (col0 == 0) {
        #pragma unroll
        for (int r = 0; r < 4; ++r) {
            red[wid][r0 + r][0] = p0[r];
            red[wid][r0 + r][1] = p1[r];
            red[wid][r0 + r][2] = p2[r];
        }
    }
    __syncthreads();
    if (tid < 48) {
        int row = tid / 3, c = tid % 3;
        float s = red[0][row][c] + red[1][row][c] + red[2][row][c] + red[3][row][c];
        if (rowbase + row < n)
            out[(size_t)(rowbase + row) * 3 + c] = s + ub2[c];
    }
}

// ---------------------------------------------------------------------------
extern "C" void kernel_launch(void* const* d_in, const int* in_sizes, int n_in,
                              void* d_out, int out_size, void* d_ws, size_t ws_size,
                              hipStream_t stream) {
    const float* z      = (const float*)d_in[0];
    const float* dist   = (const float*)d_in[1];
    const int*   ei     = (const int*)d_in[2];
    const float* init_w = (const float*)d_in[3];
    const float* init_b = (const float*)d_in[4];

    const float* L[2][9];
    for (int l = 0; l < 2; ++l)
        for (int p = 0; p < 9; ++p)
            L[l][p] = (const float*)d_in[5 + l * 9 + p];

    const float* u_l1_w = (const float*)d_in[23];
    const float* u_l1_b = (const float*)d_in[24];
    const float* u_l2_w = (const float*)d_in[25];
    const float* u_l2_b = (const float*)d_in[26];
    float* out = (float*)d_out;

    const int N = in_sizes[0] / 3;
    const int E = in_sizes[1];

    const int nb16     = (N + 15) / 16;           // 16-row blocks
    const int e8Grid   = (E + 2047) / 2048;       // 8 edges/thread
    const int edgeGrid = (E + 255) / 256;
    const int scanB    = (N + 1 + 1023) / 1024;
    const int aggGrid  = (N + 3) / 4;

    // workspace layout (float units)
    float* wtab   = (float*)d_ws;                     // 2048
    float* bf     = wtab + 2048;                      // 57344
    float* vres   = bf + 57344;                       // nb16*2048 (acc layout)
    float* vh     = vres + (size_t)nb16 * 2048;       // N*64
    float* aggh   = vh + (size_t)N * 64;              // N*64
    int2*  ecomb  = (int2*)(aggh + (size_t)N * 64);   // E int2
    int*   pos    = (int*)(ecomb + E);                // E
    int*   deg    = pos + E;                          // N
    int*   rowstart = deg + N;                        // N+1
    int*   cursor = rowstart + N + 1;                 // N
    int*   blocksum = cursor + N;                     // 64

    _Float16* vlin_h = (_Float16*)vh;
    _Float16* agg_h  = (_Float16*)aggh;
    f32x4*    vres4  = (f32x4*)vres;
    _Float16* Bf     = (_Float16*)bf;
    _Float16* BfW[7];
    for (int i = 0; i < 7; ++i) BfW[i] = Bf + (size_t)i * 16384;

    Ptr8 wt; wt.p[0] = L[0][1]; wt.p[1] = L[0][2]; wt.p[2] = L[0][3]; wt.p[3] = L[0][4];
             wt.p[4] = L[1][1]; wt.p[5] = L[1][2]; wt.p[6] = L[1][3]; wt.p[7] = L[1][4];
    k_wtab2<<<dim3(7, 2), HD, 0, stream>>>(wt, wtab);

    Ptr8 pb; pb.p[0] = L[0][0]; pb.p[1] = L[0][5]; pb.p[2] = L[0][7];
             pb.p[3] = L[1][0]; pb.p[4] = L[1][5]; pb.p[5] = L[1][7];
             pb.p[6] = u_l1_w;  pb.p[7] = u_l1_w;
    k_prepB7<<<dim3(8, 8), 256, 0, stream>>>(pb, Bf, deg, N);  // pack + zero deg

    // CSR build
    k_deg<<<edgeGrid, 256, 0, stream>>>(ei, deg, E);
    k_scan1<<<scanB, 1024, 0, stream>>>(deg, rowstart, blocksum, N);
    k_scan2<<<1, 64, 0, stream>>>(blocksum, scanB);
    k_scan3<<<scanB, 1024, 0, stream>>>(rowstart, cursor, blocksum, N);
    k_epos<<<e8Grid, 256, 0, stream>>>(ei, cursor, pos, E);
    k_ewrite<<<e8Grid, 256, 0, stream>>>(ei, dist, pos, ecomb, E);

    // layer 0
    k_front<<<nb16, 256, 0, stream>>>(z, init_w, init_b, BfW[0], vlin_h, N);
    k_agg<<<aggGrid, 256, 0, stream>>>(rowstart, ecomb, vlin_h, wtab, agg_h, N);
    k_mid<<<nb16, 256, 0, stream>>>(agg_h, BfW[1], L[0][6], BfW[2], L[0][8],
                                    BfW[3], z, init_w, init_b, vres4, vlin_h, N);
    k_agg<<<aggGrid, 256, 0, stream>>>(rowstart, ecomb, vlin_h, wtab + 7 * HD, agg_h, N);
    k_back<<<nb16, 256, 0, stream>>>(agg_h, BfW[4], L[1][6], BfW[5], L[1][8],
                                     BfW[6], u_l1_b, u_l2_w, u_l2_b, vres4, out, N);
}

// Round 12
// 316.107 us; speedup vs baseline: 9.9666x; 1.1083x over previous
//
#include <hip/hip_runtime.h>
#include <cstdint>
#include <cstddef>

#define HD 128              // hidden channels
#define GD 50               // gaussians
static constexpr float PI_F   = 3.14159265358979323846f;
static constexpr float CUTF   = 6.0f;
static constexpr float SHIFTF = 0.69314718055994530942f; // ln(2)

typedef _Float16 f16x8 __attribute__((ext_vector_type(8)));
typedef _Float16 f16x2 __attribute__((ext_vector_type(2)));
typedef float    f32x4 __attribute__((ext_vector_type(4)));

struct Ptr8 { const float* p[8]; };

// fast ShiftedSoftplus: native v_exp_f32 / v_log_f32
__device__ __forceinline__ float ssp(float x) {
    float e = __expf(-fabsf(x));
    return fmaxf(x, 0.0f) + __logf(1.0f + e) - SHIFTF;
}

// ---------------------------------------------------------------------------
// Swizzled fp16 LDS tile (16 rows x 128 cols, 256 B/row), XOR G4 fix.
// ---------------------------------------------------------------------------
__device__ __forceinline__ _Float16* t16(_Float16* base, int row, int byte) {
    return (_Float16*)((char*)base + row * 256 + (byte ^ ((row & 7) << 4)));
}

// 8 MFMAs covering 2 column-tiles (ctb, ctb+1) x 4 k-slices
__device__ __forceinline__ void mfma_ct(const f16x8 af[4],
                                        const _Float16* __restrict__ Bf,
                                        int lane, f32x4 acc[2], int ctb) {
    #pragma unroll
    for (int ks = 0; ks < 4; ++ks)
        #pragma unroll
        for (int c = 0; c < 2; ++c)
            acc[c] = __builtin_amdgcn_mfma_f32_16x16x32_f16(
                af[ks], ((const f16x8*)Bf)[((ctb + c) * 4 + ks) * 64 + lane],
                acc[c], 0, 0, 0);
}

// C/D layout (m89): col = lane&15, row_local = (lane>>4)*4 + r
template <int ACT>
__device__ __forceinline__ void acc_to_t16_ct(const f32x4 acc[2], const float* bias,
                                              int lane, _Float16* tile, int ctb) {
    int col0 = lane & 15, r0 = (lane >> 4) * 4;
    #pragma unroll
    for (int c = 0; c < 2; ++c) {
        int cc = (ctb + c) * 16 + col0;
        float bs = bias ? bias[cc] : 0.f;
        #pragma unroll
        for (int r = 0; r < 4; ++r) {
            float o = acc[c][r] + bs;
            if (ACT) o = ssp(o);
            *t16(tile, r0 + r, cc * 2) = (_Float16)o;
        }
    }
}

// A-fragments (lane: row = lane&15, k = (lane>>4)*8 + j per ks) from fp16 tile
__device__ __forceinline__ void t16_to_af(_Float16* tile, int lane, f16x8 af[4]) {
    int row = lane & 15, kgB = (lane >> 4) * 16;
    #pragma unroll
    for (int ks = 0; ks < 4; ++ks)
        af[ks] = *(const f16x8*)t16(tile, row, ks * 64 + kgB);
}

// v(z) for 2 column-tiles in accumulator layout
__device__ __forceinline__ void vz_ct(const float* __restrict__ z,
                                      const float* __restrict__ iw,
                                      const float* __restrict__ ib,
                                      int rowbase, int lane, int n, int ctb,
                                      f32x4 vz[2]) {
    int col0 = lane & 15, r0 = (lane >> 4) * 4;
    float zr[4][3];
    #pragma unroll
    for (int r = 0; r < 4; ++r) {
        int row = min(rowbase + r0 + r, n - 1);
        zr[r][0] = z[row * 3 + 0];
        zr[r][1] = z[row * 3 + 1];
        zr[r][2] = z[row * 3 + 2];
    }
    #pragma unroll
    for (int c = 0; c < 2; ++c) {
        int cc = (ctb + c) * 16 + col0;
        float w0 = iw[cc], w1 = iw[HD + cc], w2 = iw[2 * HD + cc], bz = ib[cc];
        #pragma unroll
        for (int r = 0; r < 4; ++r)
            vz[c][r] = fmaf(zr[r][0], w0, fmaf(zr[r][1], w1, fmaf(zr[r][2], w2, bz)));
    }
}

// ---------------------------------------------------------------------------
// Merged prep kernel, grid (8, 9), 256 threads:
//   y = 0..6 : pack weight slot y into fp16 MFMA B-frag order (2048 frags)
//   y = 7    : zero deg[]
//   y = 8, x<7: Wtab for bin=x, both layers (threads 0-127 = L0, 128-255 = L1)
// ---------------------------------------------------------------------------
__global__ __launch_bounds__(256) void k_wtab_prep(Ptr8 WT, Ptr8 PB,
                                                   float* __restrict__ wtab,
                                                   _Float16* __restrict__ Bf,
                                                   int* __restrict__ deg, int n) {
    int y = blockIdx.y;
    if (y < 7) {
        int idx = blockIdx.x * 256 + threadIdx.x;   // 0..2047
        if (idx >= 2048) return;
        const float* W = PB.p[y];
        int l  = idx & 63;
        int f  = idx >> 6;        // 0..31 = ct*4+ks
        int ks = f & 3, ct = f >> 2;
        int col = ct * 16 + (l & 15);
        int k0  = ks * 32 + ((l >> 4) << 3);
        f16x8 o;
        #pragma unroll
        for (int j = 0; j < 8; ++j) o[j] = (_Float16)W[(size_t)(k0 + j) * HD + col];
        ((f16x8*)(Bf + (size_t)y * 16384))[idx] = o;
        return;
    }
    if (y == 7) {
        int idx = blockIdx.x * 256 + threadIdx.x;
        for (int i = idx; i < n; i += 2048) deg[i] = 0;
        return;
    }
    // y == 8: Wtab
    if (blockIdx.x >= 7) return;
    int bin   = blockIdx.x;
    int layer = threadIdx.x >> 7;     // 0 / 1
    int t     = threadIdx.x & 127;
    const float* m0w = WT.p[layer * 4 + 0];
    const float* m0b = WT.p[layer * 4 + 1];
    const float* m2w = WT.p[layer * 4 + 2];
    const float* m2b = WT.p[layer * 4 + 3];
    __shared__ float hbuf[2][HD];

    const float spacing = CUTF / (GD - 1);
    const float coeff   = -0.5f / (spacing * spacing);

    float acc = m0b[t];
    #pragma unroll 5
    for (int g = 0; g < GD; ++g) {
        float d = (float)bin - (float)g * spacing;
        acc = fmaf(__expf(coeff * d * d), m0w[g * HD + t], acc);
    }
    hbuf[layer][t] = ssp(acc);
    __syncthreads();

    float acc2 = m2b[t];
    #pragma unroll 8
    for (int k = 0; k < HD; ++k)
        acc2 = fmaf(hbuf[layer][k], m2w[k * HD + t], acc2);
    wtab[(layer * 7 + bin) * HD + t] = acc2;
}

// ---------------------------------------------------------------------------
// k_degpos: deg histogram; the atomic's return value IS the local slot ->
// pos[e]. 8 edges/thread, atomics batched before dependent stores.
// ---------------------------------------------------------------------------
__global__ __launch_bounds__(256) void k_degpos(const int* __restrict__ ei,
                                                int* __restrict__ deg,
                                                int* __restrict__ pos,
                                                int nedges) {
    int base = blockIdx.x * 2048 + threadIdx.x;
    int p[8];
    #pragma unroll
    for (int k = 0; k < 8; ++k) {
        int e = base + k * 256;
        if (e < nedges) p[k] = atomicAdd(&deg[ei[nedges + e]], 1);
    }
    #pragma unroll
    for (int k = 0; k < 8; ++k) {
        int e = base + k * 256;
        if (e < nedges) pos[e] = p[k];
    }
}

// ---------------------------------------------------------------------------
// scan1: block-local exclusive scan of deg (n+1 elems) + per-block totals
// ---------------------------------------------------------------------------
__global__ __launch_bounds__(1024) void k_scan1(const int* __restrict__ deg,
                                                int* __restrict__ rowstart,
                                                int* __restrict__ blocksum, int n) {
    __shared__ int wsum[16];
    int tid  = threadIdx.x;
    int lane = tid & 63, wid = tid >> 6;
    int i = blockIdx.x * 1024 + tid;
    int val = (i < n) ? deg[i] : 0;
    int x = val;
    #pragma unroll
    for (int off = 1; off < 64; off <<= 1) {
        int y = __shfl_up(x, off, 64);
        if (lane >= off) x += y;
    }
    if (lane == 63) wsum[wid] = x;
    __syncthreads();
    if (wid == 0) {
        int s = (lane < 16) ? wsum[lane] : 0;
        #pragma unroll
        for (int off = 1; off < 16; off <<= 1) {
            int y = __shfl_up(s, off, 64);
            if (lane >= off) s += y;
        }
        if (lane < 16) wsum[lane] = s;
    }
    __syncthreads();
    int wbase = (wid > 0) ? wsum[wid - 1] : 0;
    if (i <= n) rowstart[i] = wbase + x - val;
    if (tid == 1023) blocksum[blockIdx.x] = wsum[15];
}

// ---------------------------------------------------------------------------
// scan3e: folds the tiny inter-block scan (<=64 blocksums) into each block,
// then adds the global base to rowstart.
// ---------------------------------------------------------------------------
__global__ __launch_bounds__(1024) void k_scan3e(int* __restrict__ rowstart,
                                                 const int* __restrict__ blocksum,
                                                 int nb, int n) {
    __shared__ int sbase[64];
    int tid = threadIdx.x;
    if (tid < 64) {
        int v = (tid < nb) ? blocksum[tid] : 0;
        int x = v;
        #pragma unroll
        for (int off = 1; off < 64; off <<= 1) {
            int y = __shfl_up(x, off, 64);
            if (tid >= off) x += y;
        }
        sbase[tid] = x;                    // inclusive scan
    }
    __syncthreads();
    int bx = blockIdx.x;
    int base = (bx > 0) ? sbase[bx - 1] : 0;
    int i = bx * 1024 + tid;
    if (i <= n) rowstart[i] += base;
}

// ---------------------------------------------------------------------------
// k_ewrite: ecomb[rowstart[i]+pos[e]] = {j|bin<<25, Cg}.  No atomics;
// 8 independent random stores per thread.
// ---------------------------------------------------------------------------
__global__ __launch_bounds__(256) void k_ewrite(const int* __restrict__ ei,
                                                const float* __restrict__ dist,
                                                const int* __restrict__ pos,
                                                const int* __restrict__ rowstart,
                                                int2* __restrict__ ecomb,
                                                int nedges) {
    int base = blockIdx.x * 2048 + threadIdx.x;
    #pragma unroll
    for (int k = 0; k < 8; ++k) {
        int e = base + k * 256;
        if (e < nedges) {
            int   i = ei[nedges + e];
            int   j = ei[e];
            float d = dist[e];
            int bin = min((int)d, 6);
            float Cg = 0.5f * (cosf(d * (PI_F / CUTF)) + 1.0f);
            ecomb[rowstart[i] + pos[e]] = make_int2(j | (bin << 25), __float_as_int(Cg));
        }
    }
}

// ---------------------------------------------------------------------------
// k_front: vlin0_h = f16( (z@init_w + init_b) @ lin0 ), 16 rows/block.
// ---------------------------------------------------------------------------
__global__ __launch_bounds__(256) void k_front(const float* __restrict__ z,
                                               const float* __restrict__ iw,
                                               const float* __restrict__ ib,
                                               const _Float16* __restrict__ BfL,
                                               _Float16* __restrict__ vlin_h, int n) {
    __shared__ __attribute__((aligned(16))) _Float16 tile16[2048];
    int tid = threadIdx.x, lane = tid & 63, wid = tid >> 6;
    int rowbase = blockIdx.x * 16;
    int arow = min(rowbase + (lane & 15), n - 1);
    float z0 = z[arow * 3 + 0], z1 = z[arow * 3 + 1], z2 = z[arow * 3 + 2];
    int kg = (lane >> 4) * 8;

    f16x8 af[4];
    #pragma unroll
    for (int ks = 0; ks < 4; ++ks) {
        f16x8 h;
        #pragma unroll
        for (int j = 0; j < 8; ++j) {
            int c = ks * 32 + kg + j;
            h[j] = (_Float16)fmaf(z0, iw[c], fmaf(z1, iw[HD + c], fmaf(z2, iw[2 * HD + c], ib[c])));
        }
        af[ks] = h;
    }

    f32x4 acc[2];
    acc[0] = (f32x4){0.f, 0.f, 0.f, 0.f};
    acc[1] = (f32x4){0.f, 0.f, 0.f, 0.f};
    mfma_ct(af, BfL, lane, acc, wid * 2);
    acc_to_t16_ct<0>(acc, nullptr, lane, tile16, wid * 2);
    __syncthreads();
    int row = tid >> 4, g8 = tid & 15;
    if (rowbase + row < n)
        ((f16x8*)vlin_h)[(size_t)(rowbase + row) * 16 + g8] =
            *(const f16x8*)t16(tile16, row, g8 * 16);
}

// ---------------------------------------------------------------------------
// agg_h[node] = fp16( sum_e vlin_h[j_e] * Wtab[bin_e] * Cg_e )  (fp32 acc)
// One wave per node, 2 ch/lane, 8-edge unroll for gather ILP.
// ---------------------------------------------------------------------------
__global__ __launch_bounds__(256) void k_agg(const int* __restrict__ rowstart,
                                             const int2* __restrict__ ecomb,
                                             const _Float16* __restrict__ vlin_h,
                                             const float* __restrict__ wtab,
                                             _Float16* __restrict__ agg_h, int n) {
    __shared__ float lwt[7 * HD];
    int tid = threadIdx.x;
    if (tid < 224) ((float4*)lwt)[tid] = ((const float4*)wtab)[tid];
    __syncthreads();

    int node = blockIdx.x * 4 + (tid >> 6);
    if (node >= n) return;
    int lane = tid & 63;
    int beg = rowstart[node], end = rowstart[node + 1];

    float accx = 0.f, accy = 0.f;
    const float* lwt2 = lwt + 2 * lane;
    int e = beg;
    for (; e + 7 < end; e += 8) {
        int2 cc[8];
        #pragma unroll
        for (int k = 0; k < 8; ++k) cc[k] = ecomb[e + k];
        f16x2 hh[8];
        #pragma unroll
        for (int k = 0; k < 8; ++k)
            hh[k] = *(const f16x2*)(vlin_h + (size_t)(cc[k].x & 0x01FFFFFF) * HD + 2 * lane);
        float2 ww[8];
        #pragma unroll
        for (int k = 0; k < 8; ++k)
            ww[k] = *(const float2*)(lwt2 + (cc[k].x >> 25) * HD);
        #pragma unroll
        for (int k = 0; k < 8; ++k) {
            float g = __int_as_float(cc[k].y);
            accx = fmaf((float)hh[k][0], ww[k].x * g, accx);
            accy = fmaf((float)hh[k][1], ww[k].y * g, accy);
        }
    }
    for (; e + 3 < end; e += 4) {
        int2 cc[4];
        #pragma unroll
        for (int k = 0; k < 4; ++k) cc[k] = ecomb[e + k];
        #pragma unroll
        for (int k = 0; k < 4; ++k) {
            f16x2 h = *(const f16x2*)(vlin_h + (size_t)(cc[k].x & 0x01FFFFFF) * HD + 2 * lane);
            float2 w = *(const float2*)(lwt2 + (cc[k].x >> 25) * HD);
            float g = __int_as_float(cc[k].y);
            accx = fmaf((float)h[0], w.x * g, accx);
            accy = fmaf((float)h[1], w.y * g, accy);
        }
    }
    for (; e < end; ++e) {
        int2 c0 = ecomb[e];
        f16x2 h0 = *(const f16x2*)(vlin_h + (size_t)(c0.x & 0x01FFFFFF) * HD + 2 * lane);
        float2 w0 = *(const float2*)(lwt2 + (c0.x >> 25) * HD);
        float g0 = __int_as_float(c0.y);
        accx = fmaf((float)h0[0], w0.x * g0, accx);
        accy = fmaf((float)h0[1], w0.y * g0, accy);
    }
    f16x2 o; o[0] = (_Float16)accx; o[1] = (_Float16)accy;
    *(f16x2*)(agg_h + (size_t)node * HD + 2 * lane) = o;
}

// ---------------------------------------------------------------------------
// k_mid: 16 rows/block, 4 waves x 2 ct. tmp=ssp(agg@l1+b1);
// vnew = v(z) + tmp@l2 + b2 -> vres (acc layout); vlin_h = f16(vnew@lin1)
// ---------------------------------------------------------------------------
__global__ __launch_bounds__(256) void k_mid(const _Float16* __restrict__ agg_h,
                                             const _Float16* __restrict__ Bf1,
                                             const float* __restrict__ b1,
                                             const _Float16* __restrict__ Bf2,
                                             const float* __restrict__ b2,
                                             const _Float16* __restrict__ BfL,
                                             const float* __restrict__ z,
                                             const float* __restrict__ iw,
                                             const float* __restrict__ ib,
                                             f32x4* __restrict__ vres4,
                                             _Float16* __restrict__ vlin_h, int n) {
    __shared__ __attribute__((aligned(16))) _Float16 tile16[2048];
    int tid = threadIdx.x, lane = tid & 63, wid = tid >> 6;
    int rowbase = blockIdx.x * 16;
    int ctb = wid * 2;

    int arow = min(rowbase + (lane & 15), n - 1);
    int kg = (lane >> 4) * 8;
    f16x8 af[4];
    #pragma unroll
    for (int ks = 0; ks < 4; ++ks)
        af[ks] = *(const f16x8*)(agg_h + (size_t)arow * HD + ks * 32 + kg);

    f32x4 acc[2];
    acc[0] = (f32x4){0.f, 0.f, 0.f, 0.f};
    acc[1] = (f32x4){0.f, 0.f, 0.f, 0.f};
    mfma_ct(af, Bf1, lane, acc, ctb);
    acc_to_t16_ct<1>(acc, b1, lane, tile16, ctb);     // tmp cols
    __syncthreads();                                  // tmp complete
    t16_to_af(tile16, lane, af);
    __syncthreads();                                  // all reads done

    acc[0] = (f32x4){0.f, 0.f, 0.f, 0.f};
    acc[1] = (f32x4){0.f, 0.f, 0.f, 0.f};
    mfma_ct(af, Bf2, lane, acc, ctb);

    f32x4 vz[2];
    vz_ct(z, iw, ib, rowbase, lane, n, ctb, vz);
    int col0 = lane & 15;
    #pragma unroll
    for (int c = 0; c < 2; ++c) {
        float bs = b2[(ctb + c) * 16 + col0];
        #pragma unroll
        for (int r = 0; r < 4; ++r) acc[c][r] += bs + vz[c][r];
        vres4[((size_t)blockIdx.x * 8 + ctb + c) * 64 + lane] = acc[c];
    }

    acc_to_t16_ct<0>(acc, nullptr, lane, tile16, ctb);  // vnew cols
    __syncthreads();                                    // vnew complete
    t16_to_af(tile16, lane, af);
    __syncthreads();                                    // reads done

    acc[0] = (f32x4){0.f, 0.f, 0.f, 0.f};
    acc[1] = (f32x4){0.f, 0.f, 0.f, 0.f};
    mfma_ct(af, BfL, lane, acc, ctb);
    acc_to_t16_ct<0>(acc, nullptr, lane, tile16, ctb);
    __syncthreads();                                    // vlin tile complete
    int row = tid >> 4, g8 = tid & 15;
    if (rowbase + row < n)
        ((f16x8*)vlin_h)[(size_t)(rowbase + row) * 16 + g8] =
            *(const f16x8*)t16(tile16, row, g8 * 16);
}

// ---------------------------------------------------------------------------
// k_back: 16 rows/block. tmp=ssp(agg@l1+b1); vnew = vres + tmp@l2 + b2;
// u = ssp(vnew@u1+ub1); out = u @ u_l2[128,3] + ub2 (shfl + LDS reduce)
// ---------------------------------------------------------------------------
__global__ __launch_bounds__(256) void k_back(const _Float16* __restrict__ agg_h,
                                              const _Float16* __restrict__ Bf1,
                                              const float* __restrict__ b1,
                                              const _Float16* __restrict__ Bf2,
                                              const float* __restrict__ b2,
                                              const _Float16* __restrict__ BfU,
                                              const float* __restrict__ ub1,
                                              const float* __restrict__ w2,
                                              const float* __restrict__ ub2,
                                              const f32x4* __restrict__ vres4,
                                              float* __restrict__ out, int n) {
    __shared__ __attribute__((aligned(16))) _Float16 tile16[2048];
    __shared__ float red[4][16][3];
    int tid = threadIdx.x, lane = tid & 63, wid = tid >> 6;
    int rowbase = blockIdx.x * 16;
    int ctb = wid * 2;

    int arow = min(rowbase + (lane & 15), n - 1);
    int kg = (lane >> 4) * 8;
    f16x8 af[4];
    #pragma unroll
    for (int ks = 0; ks < 4; ++ks)
        af[ks] = *(const f16x8*)(agg_h + (size_t)arow * HD + ks * 32 + kg);

    f32x4 acc[2];
    acc[0] = (f32x4){0.f, 0.f, 0.f, 0.f};
    acc[1] = (f32x4){0.f, 0.f, 0.f, 0.f};
    mfma_ct(af, Bf1, lane, acc, ctb);
    acc_to_t16_ct<1>(acc, b1, lane, tile16, ctb);
    __syncthreads();
    t16_to_af(tile16, lane, af);
    __syncthreads();

    acc[0] = (f32x4){0.f, 0.f, 0.f, 0.f};
    acc[1] = (f32x4){0.f, 0.f, 0.f, 0.f};
    mfma_ct(af, Bf2, lane, acc, ctb);

    int col0 = lane & 15;
    #pragma unroll
    for (int c = 0; c < 2; ++c) {
        float bs = b2[(ctb + c) * 16 + col0];
        f32x4 rv = vres4[((size_t)blockIdx.x * 8 + ctb + c) * 64 + lane];
        #pragma unroll
        for (int r = 0; r < 4; ++r) acc[c][r] += bs + rv[r];
    }

    acc_to_t16_ct<0>(acc, nullptr, lane, tile16, ctb);
    __syncthreads();
    t16_to_af(tile16, lane, af);
    // tile is not written again — no further barrier needed before MFMA

    acc[0] = (f32x4){0.f, 0.f, 0.f, 0.f};
    acc[1] = (f32x4){0.f, 0.f, 0.f, 0.f};
    mfma_ct(af, BfU, lane, acc, ctb);

    // readout partials over this wave's 32 cols
    int r0 = (lane >> 4) * 4;
    float p0[4] = {0.f, 0.f, 0.f, 0.f};
    float p1[4] = {0.f, 0.f, 0.f, 0.f};
    float p2[4] = {0.f, 0.f, 0.f, 0.f};
    #pragma unroll
    for (int c = 0; c < 2; ++c) {
        int cc = (ctb + c) * 16 + col0;
        float bu = ub1[cc];
        float w20 = w2[cc * 3 + 0], w21 = w2[cc * 3 + 1], w22 = w2[cc * 3 + 2];
        #pragma unroll
        for (int r = 0; r < 4; ++r) {
            float u = ssp(acc[c][r] + bu);
            p0[r] = fmaf(u, w20, p0[r]);
            p1[r] = fmaf(u, w21, p1[r]);
            p2[r] = fmaf(u, w22, p2[r]);
        }
    }
    #pragma unroll
    for (int m = 1; m < 16; m <<= 1) {
        #pragma unroll
        for (int r = 0; r < 4; ++r) {
            p0[r] += __shfl_xor(p0[r], m, 64);
            p1[r] += __shfl_xor(p1[r], m, 64);
            p2[r] += __shfl_xor(p2[r], m, 64);
        }
    }
    if (col0 == 0) {
        #pragma unroll
        for (int r = 0; r < 4; ++r) {
            red[wid][r0 + r][0] = p0[r];
            red[wid][r0 + r][1] = p1[r];
            red[wid][r0 + r][2] = p2[r];
        }
    }
    __syncthreads();
    if (tid < 48) {
        int row = tid / 3, c = tid % 3;
        float s = red[0][row][c] + red[1][row][c] + red[2][row][c] + red[3][row][c];
        if (rowbase + row < n)
            out[(size_t)(rowbase + row) * 3 + c] = s + ub2[c];
    }
}

// ---------------------------------------------------------------------------
extern "C" void kernel_launch(void* const* d_in, const int* in_sizes, int n_in,
                              void* d_out, int out_size, void* d_ws, size_t ws_size,
                              hipStream_t stream) {
    const float* z      = (const float*)d_in[0];
    const float* dist   = (const float*)d_in[1];
    const int*   ei     = (const int*)d_in[2];
    const float* init_w = (const float*)d_in[3];
    const float* init_b = (const float*)d_in[4];

    const float* L[2][9];
    for (int l = 0; l < 2; ++l)
        for (int p = 0; p < 9; ++p)
            L[l][p] = (const float*)d_in[5 + l * 9 + p];

    const float* u_l1_w = (const float*)d_in[23];
    const float* u_l1_b = (const float*)d_in[24];
    const float* u_l2_w = (const float*)d_in[25];
    const float* u_l2_b = (const float*)d_in[26];
    float* out = (float*)d_out;

    const int N = in_sizes[0] / 3;
    const int E = in_sizes[1];

    const int nb16     = (N + 15) / 16;           // 16-row blocks
    const int e8Grid   = (E + 2047) / 2048;       // 8 edges/thread
    const int scanB    = (N + 1 + 1023) / 1024;
    const int aggGrid  = (N + 3) / 4;

    // workspace layout (float units)
    float* wtab   = (float*)d_ws;                     // 2048
    float* bf     = wtab + 2048;                      // 57344
    float* vres   = bf + 57344;                       // nb16*2048 (acc layout)
    float* vh     = vres + (size_t)nb16 * 2048;       // N*64
    float* aggh   = vh + (size_t)N * 64;              // N*64
    int2*  ecomb  = (int2*)(aggh + (size_t)N * 64);   // E int2
    int*   pos    = (int*)(ecomb + E);                // E
    int*   deg    = pos + E;                          // N
    int*   rowstart = deg + N;                        // N+1
    int*   blocksum = rowstart + N + 1;               // 64

    _Float16* vlin_h = (_Float16*)vh;
    _Float16* agg_h  = (_Float16*)aggh;
    f32x4*    vres4  = (f32x4*)vres;
    _Float16* Bf     = (_Float16*)bf;
    _Float16* BfW[7];
    for (int i = 0; i < 7; ++i) BfW[i] = Bf + (size_t)i * 16384;

    Ptr8 wt; wt.p[0] = L[0][1]; wt.p[1] = L[0][2]; wt.p[2] = L[0][3]; wt.p[3] = L[0][4];
             wt.p[4] = L[1][1]; wt.p[5] = L[1][2]; wt.p[6] = L[1][3]; wt.p[7] = L[1][4];
    Ptr8 pb; pb.p[0] = L[0][0]; pb.p[1] = L[0][5]; pb.p[2] = L[0][7];
             pb.p[3] = L[1][0]; pb.p[4] = L[1][5]; pb.p[5] = L[1][7];
             pb.p[6] = u_l1_w;  pb.p[7] = u_l1_w;

    // prep: pack 7 weights + zero deg + both layers' Wtab, one launch
    k_wtab_prep<<<dim3(8, 9), 256, 0, stream>>>(wt, pb, wtab, Bf, deg, N);

    // CSR build: ONE atomic pass (deg + local slot), scan, placement write
    k_degpos<<<e8Grid, 256, 0, stream>>>(ei, deg, pos, E);
    k_scan1<<<scanB, 1024, 0, stream>>>(deg, rowstart, blocksum, N);
    k_scan3e<<<scanB, 1024, 0, stream>>>(rowstart, blocksum, scanB, N);
    k_ewrite<<<e8Grid, 256, 0, stream>>>(ei, dist, pos, rowstart, ecomb, E);

    // layer 0
    k_front<<<nb16, 256, 0, stream>>>(z, init_w, init_b, BfW[0], vlin_h, N);
    k_agg<<<aggGrid, 256, 0, stream>>>(rowstart, ecomb, vlin_h, wtab, agg_h, N);
    k_mid<<<nb16, 256, 0, stream>>>(agg_h, BfW[1], L[0][6], BfW[2], L[0][8],
                                    BfW[3], z, init_w, init_b, vres4, vlin_h, N);
    k_agg<<<aggGrid, 256, 0, stream>>>(rowstart, ecomb, vlin_h, wtab + 7 * HD, agg_h, N);
    k_back<<<nb16, 256, 0, stream>>>(agg_h, BfW[4], L[1][6], BfW[5], L[1][8],
                                     BfW[6], u_l1_b, u_l2_w, u_l2_b, vres4, out, N);
}

// Round 13
// 316.049 us; speedup vs baseline: 9.9685x; 1.0002x over previous
//
#include <hip/hip_runtime.h>
#include <cstdint>
#include <cstddef>

#define HD 128              // hidden channels
#define GD 50               // gaussians
static constexpr float PI_F   = 3.14159265358979323846f;
static constexpr float CUTF   = 6.0f;
static constexpr float SHIFTF = 0.69314718055994530942f; // ln(2)

typedef _Float16 f16x8 __attribute__((ext_vector_type(8)));
typedef _Float16 f16x2 __attribute__((ext_vector_type(2)));
typedef float    f32x4 __attribute__((ext_vector_type(4)));

struct Ptr8 { const float* p[8]; };

// fast ShiftedSoftplus: native v_exp_f32 / v_log_f32
__device__ __forceinline__ float ssp(float x) {
    float e = __expf(-fabsf(x));
    return fmaxf(x, 0.0f) + __logf(1.0f + e) - SHIFTF;
}

// ---------------------------------------------------------------------------
// Swizzled fp16 LDS tile (16 rows x 128 cols, 256 B/row), XOR G4 fix.
// ---------------------------------------------------------------------------
__device__ __forceinline__ _Float16* t16(_Float16* base, int row, int byte) {
    return (_Float16*)((char*)base + row * 256 + (byte ^ ((row & 7) << 4)));
}

// 8 MFMAs covering 2 column-tiles (ctb, ctb+1) x 4 k-slices
__device__ __forceinline__ void mfma_ct(const f16x8 af[4],
                                        const _Float16* __restrict__ Bf,
                                        int lane, f32x4 acc[2], int ctb) {
    #pragma unroll
    for (int ks = 0; ks < 4; ++ks)
        #pragma unroll
        for (int c = 0; c < 2; ++c)
            acc[c] = __builtin_amdgcn_mfma_f32_16x16x32_f16(
                af[ks], ((const f16x8*)Bf)[((ctb + c) * 4 + ks) * 64 + lane],
                acc[c], 0, 0, 0);
}

// C/D layout (m89): col = lane&15, row_local = (lane>>4)*4 + r
template <int ACT>
__device__ __forceinline__ void acc_to_t16_ct(const f32x4 acc[2], const float* bias,
                                              int lane, _Float16* tile, int ctb) {
    int col0 = lane & 15, r0 = (lane >> 4) * 4;
    #pragma unroll
    for (int c = 0; c < 2; ++c) {
        int cc = (ctb + c) * 16 + col0;
        float bs = bias ? bias[cc] : 0.f;
        #pragma unroll
        for (int r = 0; r < 4; ++r) {
            float o = acc[c][r] + bs;
            if (ACT) o = ssp(o);
            *t16(tile, r0 + r, cc * 2) = (_Float16)o;
        }
    }
}

// A-fragments (lane: row = lane&15, k = (lane>>4)*8 + j per ks) from fp16 tile
__device__ __forceinline__ void t16_to_af(_Float16* tile, int lane, f16x8 af[4]) {
    int row = lane & 15, kgB = (lane >> 4) * 16;
    #pragma unroll
    for (int ks = 0; ks < 4; ++ks)
        af[ks] = *(const f16x8*)t16(tile, row, ks * 64 + kgB);
}

// v(z) for 2 column-tiles in accumulator layout
__device__ __forceinline__ void vz_ct(const float* __restrict__ z,
                                      const float* __restrict__ iw,
                                      const float* __restrict__ ib,
                                      int rowbase, int lane, int n, int ctb,
                                      f32x4 vz[2]) {
    int col0 = lane & 15, r0 = (lane >> 4) * 4;
    float zr[4][3];
    #pragma unroll
    for (int r = 0; r < 4; ++r) {
        int row = min(rowbase + r0 + r, n - 1);
        zr[r][0] = z[row * 3 + 0];
        zr[r][1] = z[row * 3 + 1];
        zr[r][2] = z[row * 3 + 2];
    }
    #pragma unroll
    for (int c = 0; c < 2; ++c) {
        int cc = (ctb + c) * 16 + col0;
        float w0 = iw[cc], w1 = iw[HD + cc], w2 = iw[2 * HD + cc], bz = ib[cc];
        #pragma unroll
        for (int r = 0; r < 4; ++r)
            vz[c][r] = fmaf(zr[r][0], w0, fmaf(zr[r][1], w1, fmaf(zr[r][2], w2, bz)));
    }
}

// ---------------------------------------------------------------------------
// Merged prep kernel, grid (8, 9), 256 threads:
//   y = 0..6 : pack weight slot y into fp16 MFMA B-frag order (2048 frags)
//   y = 7    : zero deg[]
//   y = 8, x<7: Wtab for bin=x, both layers (threads 0-127 = L0, 128-255 = L1)
// ---------------------------------------------------------------------------
__global__ __launch_bounds__(256) void k_wtab_prep(Ptr8 WT, Ptr8 PB,
                                                   float* __restrict__ wtab,
                                                   _Float16* __restrict__ Bf,
                                                   int* __restrict__ deg, int n) {
    int y = blockIdx.y;
    if (y < 7) {
        int idx = blockIdx.x * 256 + threadIdx.x;   // 0..2047
        if (idx >= 2048) return;
        const float* W = PB.p[y];
        int l  = idx & 63;
        int f  = idx >> 6;        // 0..31 = ct*4+ks
        int ks = f & 3, ct = f >> 2;
        int col = ct * 16 + (l & 15);
        int k0  = ks * 32 + ((l >> 4) << 3);
        f16x8 o;
        #pragma unroll
        for (int j = 0; j < 8; ++j) o[j] = (_Float16)W[(size_t)(k0 + j) * HD + col];
        ((f16x8*)(Bf + (size_t)y * 16384))[idx] = o;
        return;
    }
    if (y == 7) {
        int idx = blockIdx.x * 256 + threadIdx.x;
        for (int i = idx; i < n; i += 2048) deg[i] = 0;
        return;
    }
    // y == 8: Wtab
    if (blockIdx.x >= 7) return;
    int bin   = blockIdx.x;
    int layer = threadIdx.x >> 7;     // 0 / 1
    int t     = threadIdx.x & 127;
    const float* m0w = WT.p[layer * 4 + 0];
    const float* m0b = WT.p[layer * 4 + 1];
    const float* m2w = WT.p[layer * 4 + 2];
    const float* m2b = WT.p[layer * 4 + 3];
    __shared__ float hbuf[2][HD];

    const float spacing = CUTF / (GD - 1);
    const float coeff   = -0.5f / (spacing * spacing);

    float acc = m0b[t];
    #pragma unroll 5
    for (int g = 0; g < GD; ++g) {
        float d = (float)bin - (float)g * spacing;
        acc = fmaf(__expf(coeff * d * d), m0w[g * HD + t], acc);
    }
    hbuf[layer][t] = ssp(acc);
    __syncthreads();

    float acc2 = m2b[t];
    #pragma unroll 8
    for (int k = 0; k < HD; ++k)
        acc2 = fmaf(hbuf[layer][k], m2w[k * HD + t], acc2);
    wtab[(layer * 7 + bin) * HD + t] = acc2;
}

// ---------------------------------------------------------------------------
// k_degpos: deg histogram; the atomic's return value IS the local slot ->
// pos[e]. 8 edges/thread, atomics batched before dependent stores.
// ---------------------------------------------------------------------------
__global__ __launch_bounds__(256) void k_degpos(const int* __restrict__ ei,
                                                int* __restrict__ deg,
                                                int* __restrict__ pos,
                                                int nedges) {
    int base = blockIdx.x * 2048 + threadIdx.x;
    int p[8];
    #pragma unroll
    for (int k = 0; k < 8; ++k) {
        int e = base + k * 256;
        if (e < nedges) p[k] = atomicAdd(&deg[ei[nedges + e]], 1);
    }
    #pragma unroll
    for (int k = 0; k < 8; ++k) {
        int e = base + k * 256;
        if (e < nedges) pos[e] = p[k];
    }
}

// ---------------------------------------------------------------------------
// scan1: block-local exclusive scan of deg (n+1 elems) + per-block totals
// ---------------------------------------------------------------------------
__global__ __launch_bounds__(1024) void k_scan1(const int* __restrict__ deg,
                                                int* __restrict__ rowstart,
                                                int* __restrict__ blocksum, int n) {
    __shared__ int wsum[16];
    int tid  = threadIdx.x;
    int lane = tid & 63, wid = tid >> 6;
    int i = blockIdx.x * 1024 + tid;
    int val = (i < n) ? deg[i] : 0;
    int x = val;
    #pragma unroll
    for (int off = 1; off < 64; off <<= 1) {
        int y = __shfl_up(x, off, 64);
        if (lane >= off) x += y;
    }
    if (lane == 63) wsum[wid] = x;
    __syncthreads();
    if (wid == 0) {
        int s = (lane < 16) ? wsum[lane] : 0;
        #pragma unroll
        for (int off = 1; off < 16; off <<= 1) {
            int y = __shfl_up(s, off, 64);
            if (lane >= off) s += y;
        }
        if (lane < 16) wsum[lane] = s;
    }
    __syncthreads();
    int wbase = (wid > 0) ? wsum[wid - 1] : 0;
    if (i <= n) rowstart[i] = wbase + x - val;
    if (tid == 1023) blocksum[blockIdx.x] = wsum[15];
}

// ---------------------------------------------------------------------------
// scan3e: folds the tiny inter-block scan (<=64 blocksums) into each block,
// then adds the global base to rowstart.
// ---------------------------------------------------------------------------
__global__ __launch_bounds__(1024) void k_scan3e(int* __restrict__ rowstart,
                                                 const int* __restrict__ blocksum,
                                                 int nb, int n) {
    __shared__ int sbase[64];
    int tid = threadIdx.x;
    if (tid < 64) {
        int v = (tid < nb) ? blocksum[tid] : 0;
        int x = v;
        #pragma unroll
        for (int off = 1; off < 64; off <<= 1) {
            int y = __shfl_up(x, off, 64);
            if (tid >= off) x += y;
        }
        sbase[tid] = x;                    // inclusive scan
    }
    __syncthreads();
    int bx = blockIdx.x;
    int base = (bx > 0) ? sbase[bx - 1] : 0;
    int i = bx * 1024 + tid;
    if (i <= n) rowstart[i] += base;
}

// ---------------------------------------------------------------------------
// Fused: ewrite (blocks [0,e8Grid)) + front (blocks after).
//  ewrite: ecomb[rowstart[i]+pos[e]] = {j|bin<<25, Cg} via NON-TEMPORAL 8B
//          stores (no L2 dirty-line amplification). No atomics.
//  front : vlin0_h = f16( (z@init_w + init_b) @ lin0 ), 16 rows/block.
// Disjoint predecessors (scan3e vs prep), complementary resources.
// ---------------------------------------------------------------------------
__global__ __launch_bounds__(256) void k_ewf(const int* __restrict__ ei,
                                             const float* __restrict__ dist,
                                             const int* __restrict__ pos,
                                             const int* __restrict__ rowstart,
                                             int2* __restrict__ ecomb,
                                             int nedges, int e8Grid,
                                             const float* __restrict__ z,
                                             const float* __restrict__ iw,
                                             const float* __restrict__ ib,
                                             const _Float16* __restrict__ BfL,
                                             _Float16* __restrict__ vlin_h, int n) {
    __shared__ __attribute__((aligned(16))) _Float16 tile16[2048];
    int bx = blockIdx.x;
    if (bx < e8Grid) {
        int base = bx * 2048 + (int)threadIdx.x;
        #pragma unroll
        for (int k = 0; k < 8; ++k) {
            int e = base + k * 256;
            if (e < nedges) {
                int   i = ei[nedges + e];
                int   j = ei[e];
                float d = dist[e];
                int bin = min((int)d, 6);
                float Cg = 0.5f * (cosf(d * (PI_F / CUTF)) + 1.0f);
                unsigned long long payload =
                    (unsigned long long)(unsigned)(j | (bin << 25)) |
                    ((unsigned long long)(unsigned)__float_as_int(Cg) << 32);
                __builtin_nontemporal_store(
                    payload, (unsigned long long*)&ecomb[rowstart[i] + pos[e]]);
            }
        }
        return;
    }
    // ---- front ----
    int tid = threadIdx.x, lane = tid & 63, wid = tid >> 6;
    int rowbase = (bx - e8Grid) * 16;
    int arow = min(rowbase + (lane & 15), n - 1);
    float z0 = z[arow * 3 + 0], z1 = z[arow * 3 + 1], z2 = z[arow * 3 + 2];
    int kg = (lane >> 4) * 8;

    f16x8 af[4];
    #pragma unroll
    for (int ks = 0; ks < 4; ++ks) {
        f16x8 h;
        #pragma unroll
        for (int j = 0; j < 8; ++j) {
            int c = ks * 32 + kg + j;
            h[j] = (_Float16)fmaf(z0, iw[c], fmaf(z1, iw[HD + c], fmaf(z2, iw[2 * HD + c], ib[c])));
        }
        af[ks] = h;
    }

    f32x4 acc[2];
    acc[0] = (f32x4){0.f, 0.f, 0.f, 0.f};
    acc[1] = (f32x4){0.f, 0.f, 0.f, 0.f};
    mfma_ct(af, BfL, lane, acc, wid * 2);
    acc_to_t16_ct<0>(acc, nullptr, lane, tile16, wid * 2);
    __syncthreads();
    int row = tid >> 4, g8 = tid & 15;
    if (rowbase + row < n)
        ((f16x8*)vlin_h)[(size_t)(rowbase + row) * 16 + g8] =
            *(const f16x8*)t16(tile16, row, g8 * 16);
}

// ---------------------------------------------------------------------------
// agg_h[node] = fp16( sum_e vlin_h[j_e] * Wtab[bin_e] * Cg_e )  (fp32 acc)
// One wave per node, 2 ch/lane, 8-edge unroll for gather ILP.
// ---------------------------------------------------------------------------
__global__ __launch_bounds__(256) void k_agg(const int* __restrict__ rowstart,
                                             const int2* __restrict__ ecomb,
                                             const _Float16* __restrict__ vlin_h,
                                             const float* __restrict__ wtab,
                                             _Float16* __restrict__ agg_h, int n) {
    __shared__ float lwt[7 * HD];
    int tid = threadIdx.x;
    if (tid < 224) ((float4*)lwt)[tid] = ((const float4*)wtab)[tid];
    __syncthreads();

    int node = blockIdx.x * 4 + (tid >> 6);
    if (node >= n) return;
    int lane = tid & 63;
    int beg = rowstart[node], end = rowstart[node + 1];

    float accx = 0.f, accy = 0.f;
    const float* lwt2 = lwt + 2 * lane;
    int e = beg;
    for (; e + 7 < end; e += 8) {
        int2 cc[8];
        #pragma unroll
        for (int k = 0; k < 8; ++k) cc[k] = ecomb[e + k];
        f16x2 hh[8];
        #pragma unroll
        for (int k = 0; k < 8; ++k)
            hh[k] = *(const f16x2*)(vlin_h + (size_t)(cc[k].x & 0x01FFFFFF) * HD + 2 * lane);
        float2 ww[8];
        #pragma unroll
        for (int k = 0; k < 8; ++k)
            ww[k] = *(const float2*)(lwt2 + (cc[k].x >> 25) * HD);
        #pragma unroll
        for (int k = 0; k < 8; ++k) {
            float g = __int_as_float(cc[k].y);
            accx = fmaf((float)hh[k][0], ww[k].x * g, accx);
            accy = fmaf((float)hh[k][1], ww[k].y * g, accy);
        }
    }
    for (; e + 3 < end; e += 4) {
        int2 cc[4];
        #pragma unroll
        for (int k = 0; k < 4; ++k) cc[k] = ecomb[e + k];
        #pragma unroll
        for (int k = 0; k < 4; ++k) {
            f16x2 h = *(const f16x2*)(vlin_h + (size_t)(cc[k].x & 0x01FFFFFF) * HD + 2 * lane);
            float2 w = *(const float2*)(lwt2 + (cc[k].x >> 25) * HD);
            float g = __int_as_float(cc[k].y);
            accx = fmaf((float)h[0], w.x * g, accx);
            accy = fmaf((float)h[1], w.y * g, accy);
        }
    }
    for (; e < end; ++e) {
        int2 c0 = ecomb[e];
        f16x2 h0 = *(const f16x2*)(vlin_h + (size_t)(c0.x & 0x01FFFFFF) * HD + 2 * lane);
        float2 w0 = *(const float2*)(lwt2 + (c0.x >> 25) * HD);
        float g0 = __int_as_float(c0.y);
        accx = fmaf((float)h0[0], w0.x * g0, accx);
        accy = fmaf((float)h0[1], w0.y * g0, accy);
    }
    f16x2 o; o[0] = (_Float16)accx; o[1] = (_Float16)accy;
    *(f16x2*)(agg_h + (size_t)node * HD + 2 * lane) = o;
}

// ---------------------------------------------------------------------------
// k_mid: 16 rows/block, 4 waves x 2 ct. tmp=ssp(agg@l1+b1);
// vnew = v(z) + tmp@l2 + b2 -> vres (acc layout); vlin_h = f16(vnew@lin1)
// ---------------------------------------------------------------------------
__global__ __launch_bounds__(256) void k_mid(const _Float16* __restrict__ agg_h,
                                             const _Float16* __restrict__ Bf1,
                                             const float* __restrict__ b1,
                                             const _Float16* __restrict__ Bf2,
                                             const float* __restrict__ b2,
                                             const _Float16* __restrict__ BfL,
                                             const float* __restrict__ z,
                                             const float* __restrict__ iw,
                                             const float* __restrict__ ib,
                                             f32x4* __restrict__ vres4,
                                             _Float16* __restrict__ vlin_h, int n) {
    __shared__ __attribute__((aligned(16))) _Float16 tile16[2048];
    int tid = threadIdx.x, lane = tid & 63, wid = tid >> 6;
    int rowbase = blockIdx.x * 16;
    int ctb = wid * 2;

    int arow = min(rowbase + (lane & 15), n - 1);
    int kg = (lane >> 4) * 8;
    f16x8 af[4];
    #pragma unroll
    for (int ks = 0; ks < 4; ++ks)
        af[ks] = *(const f16x8*)(agg_h + (size_t)arow * HD + ks * 32 + kg);

    f32x4 acc[2];
    acc[0] = (f32x4){0.f, 0.f, 0.f, 0.f};
    acc[1] = (f32x4){0.f, 0.f, 0.f, 0.f};
    mfma_ct(af, Bf1, lane, acc, ctb);
    acc_to_t16_ct<1>(acc, b1, lane, tile16, ctb);     // tmp cols
    __syncthreads();                                  // tmp complete
    t16_to_af(tile16, lane, af);
    __syncthreads();                                  // all reads done

    acc[0] = (f32x4){0.f, 0.f, 0.f, 0.f};
    acc[1] = (f32x4){0.f, 0.f, 0.f, 0.f};
    mfma_ct(af, Bf2, lane, acc, ctb);

    f32x4 vz[2];
    vz_ct(z, iw, ib, rowbase, lane, n, ctb, vz);
    int col0 = lane & 15;
    #pragma unroll
    for (int c = 0; c < 2; ++c) {
        float bs = b2[(ctb + c) * 16 + col0];
        #pragma unroll
        for (int r = 0; r < 4; ++r) acc[c][r] += bs + vz[c][r];
        vres4[((size_t)blockIdx.x * 8 + ctb + c) * 64 + lane] = acc[c];
    }

    acc_to_t16_ct<0>(acc, nullptr, lane, tile16, ctb);  // vnew cols
    __syncthreads();                                    // vnew complete
    t16_to_af(tile16, lane, af);
    __syncthreads();                                    // reads done

    acc[0] = (f32x4){0.f, 0.f, 0.f, 0.f};
    acc[1] = (f32x4){0.f, 0.f, 0.f, 0.f};
    mfma_ct(af, BfL, lane, acc, ctb);
    acc_to_t16_ct<0>(acc, nullptr, lane, tile16, ctb);
    __syncthreads();                                    // vlin tile complete
    int row = tid >> 4, g8 = tid & 15;
    if (rowbase + row < n)
        ((f16x8*)vlin_h)[(size_t)(rowbase + row) * 16 + g8] =
            *(const f16x8*)t16(tile16, row, g8 * 16);
}

// ---------------------------------------------------------------------------
// k_back: 16 rows/block. tmp=ssp(agg@l1+b1); vnew = vres + tmp@l2 + b2;
// u = ssp(vnew@u1+ub1); out = u @ u_l2[128,3] + ub2 (shfl + LDS reduce)
// ---------------------------------------------------------------------------
__global__ __launch_bounds__(256) void k_back(const _Float16* __restrict__ agg_h,
                                              const _Float16* __restrict__ Bf1,
                                              const float* __restrict__ b1,
                                              const _Float16* __restrict__ Bf2,
                                              const float* __restrict__ b2,
                                              const _Float16* __restrict__ BfU,
                                              const float* __restrict__ ub1,
                                              const float* __restrict__ w2,
                                              const float* __restrict__ ub2,
                                              const f32x4* __restrict__ vres4,
                                              float* __restrict__ out, int n) {
    __shared__ __attribute__((aligned(16))) _Float16 tile16[2048];
    __shared__ float red[4][16][3];
    int tid = threadIdx.x, lane = tid & 63, wid = tid >> 6;
    int rowbase = blockIdx.x * 16;
    int ctb = wid * 2;

    int arow = min(rowbase + (lane & 15), n - 1);
    int kg = (lane >> 4) * 8;
    f16x8 af[4];
    #pragma unroll
    for (int ks = 0; ks < 4; ++ks)
        af[ks] = *(const f16x8*)(agg_h + (size_t)arow * HD + ks * 32 + kg);

    f32x4 acc[2];
    acc[0] = (f32x4){0.f, 0.f, 0.f, 0.f};
    acc[1] = (f32x4){0.f, 0.f, 0.f, 0.f};
    mfma_ct(af, Bf1, lane, acc, ctb);
    acc_to_t16_ct<1>(acc, b1, lane, tile16, ctb);
    __syncthreads();
    t16_to_af(tile16, lane, af);
    __syncthreads();

    acc[0] = (f32x4){0.f, 0.f, 0.f, 0.f};
    acc[1] = (f32x4){0.f, 0.f, 0.f, 0.f};
    mfma_ct(af, Bf2, lane, acc, ctb);

    int col0 = lane & 15;
    #pragma unroll
    for (int c = 0; c < 2; ++c) {
        float bs = b2[(ctb + c) * 16 + col0];
        f32x4 rv = vres4[((size_t)blockIdx.x * 8 + ctb + c) * 64 + lane];
        #pragma unroll
        for (int r = 0; r < 4; ++r) acc[c][r] += bs + rv[r];
    }

    acc_to_t16_ct<0>(acc, nullptr, lane, tile16, ctb);
    __syncthreads();
    t16_to_af(tile16, lane, af);
    // tile is not written again — no further barrier needed before MFMA

    acc[0] = (f32x4){0.f, 0.f, 0.f, 0.f};
    acc[1] = (f32x4){0.f, 0.f, 0.f, 0.f};
    mfma_ct(af, BfU, lane, acc, ctb);

    // readout partials over this wave's 32 cols
    int r0 = (lane >> 4) * 4;
    float p0[4] = {0.f, 0.f, 0.f, 0.f};
    float p1[4] = {0.f, 0.f, 0.f, 0.f};
    float p2[4] = {0.f, 0.f, 0.f, 0.f};
    #pragma unroll
    for (int c = 0; c < 2; ++c) {
        int cc = (ctb + c) * 16 + col0;
        float bu = ub1[cc];
        float w20 = w2[cc * 3 + 0], w21 = w2[cc * 3 + 1], w22 = w2[cc * 3 + 2];
        #pragma unroll
        for (int r = 0; r < 4; ++r) {
            float u = ssp(acc[c][r] + bu);
            p0[r] = fmaf(u, w20, p0[r]);
            p1[r] = fmaf(u, w21, p1[r]);
            p2[r] = fmaf(u, w22, p2[r]);
        }
    }
    #pragma unroll
    for (int m = 1; m < 16; m <<= 1) {
        #pragma unroll
        for (int r = 0; r < 4; ++r) {
            p0[r] += __shfl_xor(p0[r], m, 64);
            p1[r] += __shfl_xor(p1[r], m, 64);
            p2[r] += __shfl_xor(p2[r], m, 64);
        }
    }
    if (col0 == 0) {
        #pragma unroll
        for (int r = 0; r < 4; ++r) {
            red[wid][r0 + r][0] = p0[r];
            red[wid][r0 + r][1] = p1[r];
            red[wid][r0 + r][2] = p2[r];
        }
    }
    __syncthreads();
    if (tid < 48) {
        int row = tid / 3, c = tid % 3;
        float s = red[0][row][c] + red[1][row][c] + red[2][row][c] + red[3][row][c];
        if (rowbase + row < n)
            out[(size_t)(rowbase + row) * 3 + c] = s + ub2[c];
    }
}

// ---------------------------------------------------------------------------
extern "C" void kernel_launch(void* const* d_in, const int* in_sizes, int n_in,
                              void* d_out, int out_size, void* d_ws, size_t ws_size,
                              hipStream_t stream) {
    const float* z      = (const float*)d_in[0];
    const float* dist   = (const float*)d_in[1];
    const int*   ei     = (const int*)d_in[2];
    const float* init_w = (const float*)d_in[3];
    const float* init_b = (const float*)d_in[4];

    const float* L[2][9];
    for (int l = 0; l < 2; ++l)
        for (int p = 0; p < 9; ++p)
            L[l][p] = (const float*)d_in[5 + l * 9 + p];

    const float* u_l1_w = (const float*)d_in[23];
    const float* u_l1_b = (const float*)d_in[24];
    const float* u_l2_w = (const float*)d_in[25];
    const float* u_l2_b = (const float*)d_in[26];
    float* out = (float*)d_out;

    const int N = in_sizes[0] / 3;
    const int E = in_sizes[1];

    const int nb16     = (N + 15) / 16;           // 16-row blocks
    const int e8Grid   = (E + 2047) / 2048;       // 8 edges/thread
    const int scanB    = (N + 1 + 1023) / 1024;
    const int aggGrid  = (N + 3) / 4;

    // workspace layout (float units)
    float* wtab   = (float*)d_ws;                     // 2048
    float* bf     = wtab + 2048;                      // 57344
    float* vres   = bf + 57344;                       // nb16*2048 (acc layout)
    float* vh     = vres + (size_t)nb16 * 2048;       // N*64
    float* aggh   = vh + (size_t)N * 64;              // N*64
    int2*  ecomb  = (int2*)(aggh + (size_t)N * 64);   // E int2
    int*   pos    = (int*)(ecomb + E);                // E
    int*   deg    = pos + E;                          // N
    int*   rowstart = deg + N;                        // N+1
    int*   blocksum = rowstart + N + 1;               // 64

    _Float16* vlin_h = (_Float16*)vh;
    _Float16* agg_h  = (_Float16*)aggh;
    f32x4*    vres4  = (f32x4*)vres;
    _Float16* Bf     = (_Float16*)bf;
    _Float16* BfW[7];
    for (int i = 0; i < 7; ++i) BfW[i] = Bf + (size_t)i * 16384;

    Ptr8 wt; wt.p[0] = L[0][1]; wt.p[1] = L[0][2]; wt.p[2] = L[0][3]; wt.p[3] = L[0][4];
             wt.p[4] = L[1][1]; wt.p[5] = L[1][2]; wt.p[6] = L[1][3]; wt.p[7] = L[1][4];
    Ptr8 pb; pb.p[0] = L[0][0]; pb.p[1] = L[0][5]; pb.p[2] = L[0][7];
             pb.p[3] = L[1][0]; pb.p[4] = L[1][5]; pb.p[5] = L[1][7];
             pb.p[6] = u_l1_w;  pb.p[7] = u_l1_w;

    // prep: pack 7 weights + zero deg + both layers' Wtab, one launch
    k_wtab_prep<<<dim3(8, 9), 256, 0, stream>>>(wt, pb, wtab, Bf, deg, N);

    // CSR build: ONE atomic pass (deg + local slot), scan
    k_degpos<<<e8Grid, 256, 0, stream>>>(ei, deg, pos, E);
    k_scan1<<<scanB, 1024, 0, stream>>>(deg, rowstart, blocksum, N);
    k_scan3e<<<scanB, 1024, 0, stream>>>(rowstart, blocksum, scanB, N);

    // placement write (NT stores) fused with layer-0 front
    k_ewf<<<e8Grid + nb16, 256, 0, stream>>>(ei, dist, pos, rowstart, ecomb, E, e8Grid,
                                             z, init_w, init_b, BfW[0], vlin_h, N);

    k_agg<<<aggGrid, 256, 0, stream>>>(rowstart, ecomb, vlin_h, wtab, agg_h, N);
    k_mid<<<nb16, 256, 0, stream>>>(agg_h, BfW[1], L[0][6], BfW[2], L[0][8],
                                    BfW[3], z, init_w, init_b, vres4, vlin_h, N);
    k_agg<<<aggGrid, 256, 0, stream>>>(rowstart, ecomb, vlin_h, wtab + 7 * HD, agg_h, N);
    k_back<<<nb16, 256, 0, stream>>>(agg_h, BfW[4], L[1][6], BfW[5], L[1][8],
                                     BfW[6], u_l1_b, u_l2_w, u_l2_b, vres4, out, N);
}